// Round 2
// baseline (4009.930 us; speedup 1.0000x reference)
//
#include <hip/hip_runtime.h>
#include <math.h>

#define HWp 16384
#define Wp 128
#define Hp 128
#define Bp 4
#define Cp 64
#define CKp 576

// ---------------- depthwise 7x7, pad 3 (ConvNeXt dw) ----------------
// grid (HW/256, nMaps); map index = blockIdx.y; channel = map & 63.
__global__ __launch_bounds__(256)
void dwconv7(const float* __restrict__ in, const float* __restrict__ w,
             float* __restrict__ out) {
  int bc = blockIdx.y;
  int p  = blockIdx.x * 256 + threadIdx.x;
  __shared__ float ws[49];
  if (threadIdx.x < 49) ws[threadIdx.x] = w[(bc & 63) * 49 + threadIdx.x];
  __syncthreads();
  int y = p >> 7, x = p & 127;
  const float* ip = in + (size_t)bc * HWp;
  float acc = 0.f;
  #pragma unroll
  for (int dy = 0; dy < 7; dy++) {
    int yy = y + dy - 3;
    bool vy = (yy >= 0 && yy < Hp);
    #pragma unroll
    for (int dx = 0; dx < 7; dx++) {
      int xx = x + dx - 3;
      if (vy && xx >= 0 && xx < Wp) acc += ip[yy * Wp + xx] * ws[dy * 7 + dx];
    }
  }
  out[(size_t)bc * HWp + p] = acc;
}

// ---------------- generic 1x1 conv (tiled fp32 GEMM) ----------------
// ACT: 0 none, 1 relu, 2 leaky(0.1).  Tile: 64 co x 128 px, micro 4x8.
// grid (HW/128, Cout/64, nBatch); in/out/resid pre-offset if nBatch==1.
template<int ACT, bool RESID, bool BIAS>
__global__ __launch_bounds__(256)
void conv1x1(const float* __restrict__ in, const float* __restrict__ wgt,
             const float* __restrict__ bias, const float* __restrict__ resid,
             float* __restrict__ out, int Cin, int Cout) {
  int b   = blockIdx.z;
  int p0  = blockIdx.x * 128;
  int co0 = blockIdx.y * 64;
  __shared__ float Wt[16][68];    // pad 68 (272B rows, 16B-aligned)
  __shared__ float It[16][128];
  float acc[4][8];
  #pragma unroll
  for (int i = 0; i < 4; i++)
    #pragma unroll
    for (int j = 0; j < 8; j++) acc[i][j] = 0.f;

  const float* ip = in + (size_t)b * Cin * HWp + p0;
  int t = threadIdx.x;
  int wco = t >> 4, wkk = t & 15;
  int ipx = t & 127, ikr = t >> 7;
  int ty4 = (t >> 4) * 4, txa = (t & 15) * 4;

  for (int k0 = 0; k0 < Cin; k0 += 16) {
    #pragma unroll
    for (int i = 0; i < 4; i++)
      Wt[wkk][wco + 16 * i] = wgt[(size_t)(co0 + wco + 16 * i) * Cin + k0 + wkk];
    #pragma unroll
    for (int i = 0; i < 8; i++)
      It[ikr + 2 * i][ipx] = ip[(size_t)(k0 + ikr + 2 * i) * HWp + ipx];
    __syncthreads();
    #pragma unroll
    for (int kk = 0; kk < 16; kk++) {
      float4 wv = *(const float4*)&Wt[kk][ty4];
      float4 ia = *(const float4*)&It[kk][txa];
      float4 ib = *(const float4*)&It[kk][txa + 64];
      float iv[8] = {ia.x, ia.y, ia.z, ia.w, ib.x, ib.y, ib.z, ib.w};
      #pragma unroll
      for (int j = 0; j < 8; j++) {
        acc[0][j] += wv.x * iv[j];
        acc[1][j] += wv.y * iv[j];
        acc[2][j] += wv.z * iv[j];
        acc[3][j] += wv.w * iv[j];
      }
    }
    __syncthreads();
  }

  #pragma unroll
  for (int i = 0; i < 4; i++) {
    int co = co0 + ty4 + i;
    float bv = BIAS ? bias[co] : 0.f;
    #pragma unroll
    for (int hh = 0; hh < 2; hh++) {
      size_t base = ((size_t)b * Cout + co) * HWp + p0 + txa + hh * 64;
      float4 r;
      r.x = acc[i][hh * 4 + 0] + bv;
      r.y = acc[i][hh * 4 + 1] + bv;
      r.z = acc[i][hh * 4 + 2] + bv;
      r.w = acc[i][hh * 4 + 3] + bv;
      if (ACT == 1) {
        r.x = fmaxf(r.x, 0.f); r.y = fmaxf(r.y, 0.f);
        r.z = fmaxf(r.z, 0.f); r.w = fmaxf(r.w, 0.f);
      } else if (ACT == 2) {
        r.x = r.x > 0.f ? r.x : 0.1f * r.x;
        r.y = r.y > 0.f ? r.y : 0.1f * r.y;
        r.z = r.z > 0.f ? r.z : 0.1f * r.z;
        r.w = r.w > 0.f ? r.w : 0.1f * r.w;
      }
      if (RESID) {
        float4 rr = *(const float4*)&resid[base];
        r.x += rr.x; r.y += rr.y; r.z += rr.z; r.w += rr.w;
      }
      *(float4*)&out[base] = r;
    }
  }
}

// ---------------- 3x3 conv 64->64, bias + leaky (offset CNN) ----------------
__global__ __launch_bounds__(256)
void conv3x3_64(const float* __restrict__ in, const float* __restrict__ wgt,
                const float* __restrict__ bias, float* __restrict__ out) {
  int b = blockIdx.z;
  int coh = blockIdx.y;
  int p = blockIdx.x * 256 + threadIdx.x;
  int y = p >> 7, x = p & 127;
  __shared__ float Wl[8 * 9 * 32];
  float acc[32];
  #pragma unroll
  for (int i = 0; i < 32; i++) acc[i] = 0.f;
  const float* ip = in + (size_t)b * 64 * HWp;

  for (int c0 = 0; c0 < 64; c0 += 8) {
    __syncthreads();
    for (int idx = threadIdx.x; idx < 8 * 9 * 32; idx += 256) {
      int co = idx & 31;
      int rest = idx >> 5;
      int k = rest % 9;
      int ci8 = rest / 9;
      Wl[idx] = wgt[(((size_t)(coh * 32 + co) * 64) + c0 + ci8) * 9 + k];
    }
    __syncthreads();
    for (int ci8 = 0; ci8 < 8; ci8++) {
      const float* pl = ip + (size_t)(c0 + ci8) * HWp;
      #pragma unroll
      for (int k = 0; k < 9; k++) {
        int yy = y + k / 3 - 1, xx = x + (k % 3) - 1;
        float v = (yy >= 0 && yy < Hp && xx >= 0 && xx < Wp) ? pl[yy * Wp + xx] : 0.f;
        const float* wr = &Wl[(ci8 * 9 + k) * 32];
        #pragma unroll
        for (int c4 = 0; c4 < 8; c4++) {
          float4 wv = *(const float4*)&wr[c4 * 4];
          acc[c4 * 4 + 0] += wv.x * v;
          acc[c4 * 4 + 1] += wv.y * v;
          acc[c4 * 4 + 2] += wv.z * v;
          acc[c4 * 4 + 3] += wv.w * v;
        }
      }
    }
  }
  #pragma unroll
  for (int co = 0; co < 32; co++) {
    float vv = acc[co] + bias[coh * 32 + co];
    vv = vv > 0.f ? vv : 0.1f * vv;
    out[((size_t)b * 64 + coh * 32 + co) * HWp + p] = vv;
  }
}

// ---------------- off_w6 (64->18) + bias + 8*tanh ----------------
__global__ __launch_bounds__(256)
void off6_tanh(const float* __restrict__ in, const float* __restrict__ wgt,
               const float* __restrict__ bias, float* __restrict__ out) {
  int b = blockIdx.y;
  int p = blockIdx.x * 256 + threadIdx.x;
  __shared__ float Wl[18 * 64];
  for (int i = threadIdx.x; i < 18 * 64; i += 256) {
    int j = i / 64, ci = i % 64;
    Wl[ci * 18 + j] = wgt[i];
  }
  __syncthreads();
  float acc[18];
  #pragma unroll
  for (int j = 0; j < 18; j++) acc[j] = 0.f;
  const float* ip = in + (size_t)b * 64 * HWp + p;
  for (int ci = 0; ci < 64; ci++) {
    float v = ip[(size_t)ci * HWp];
    #pragma unroll
    for (int j = 0; j < 18; j++) acc[j] += Wl[ci * 18 + j] * v;
  }
  #pragma unroll
  for (int j = 0; j < 18; j++)
    out[((size_t)b * 18 + j) * HWp + p] = 8.f * tanhf(acc[j] + bias[j]);
}

// ---------------- deformable neighbourhood gather (per batch) ----------------
// grid (HW/256, 9); x/offs/xb pre-offset to batch b.
__global__ __launch_bounds__(256)
void deform(const float* __restrict__ x, const float* __restrict__ offs,
            float* __restrict__ xb) {
  int k = blockIdx.y;
  int p = blockIdx.x * 256 + threadIdx.x;
  int yi = p >> 7, xi = p & 127;
  float dy = offs[(size_t)(2 * k) * HWp + p];
  float dx = offs[(size_t)(2 * k + 1) * HWp + p];
  float py = (float)yi + (float)(k / 3 - 1) + dy;
  float px = (float)xi + (float)(k % 3 - 1) + dx;
  float y0f = floorf(py), x0f = floorf(px);
  float wy1 = py - y0f, wy0 = 1.f - wy1;
  float wx1 = px - x0f, wx0 = 1.f - wx1;
  int y0 = (int)y0f, x0 = (int)x0f;
  bool vy0 = (y0 >= 0 && y0 < Hp), vy1 = (y0 + 1 >= 0 && y0 + 1 < Hp);
  bool vx0 = (x0 >= 0 && x0 < Wp), vx1 = (x0 + 1 >= 0 && x0 + 1 < Wp);
  int yc0 = min(max(y0, 0), Hp - 1), yc1 = min(max(y0 + 1, 0), Hp - 1);
  int xc0 = min(max(x0, 0), Wp - 1), xc1 = min(max(x0 + 1, 0), Wp - 1);
  int i00 = yc0 * Wp + xc0, i01 = yc0 * Wp + xc1;
  int i10 = yc1 * Wp + xc0, i11 = yc1 * Wp + xc1;
  float w00 = wy0 * wx0 * ((vy0 && vx0) ? 1.f : 0.f);
  float w01 = wy0 * wx1 * ((vy0 && vx1) ? 1.f : 0.f);
  float w10 = wy1 * wx0 * ((vy1 && vx0) ? 1.f : 0.f);
  float w11 = wy1 * wx1 * ((vy1 && vx1) ? 1.f : 0.f);
  for (int c = 0; c < 64; c++) {
    const float* pl = x + (size_t)c * HWp;
    float v = pl[i00] * w00 + pl[i01] * w01 + pl[i10] * w10 + pl[i11] * w11;
    xb[((size_t)c * 9 + k) * HWp + p] = v;
  }
}

// ---------------- per-group 9->9 1x1 (dct / inv1), optional fused mul ----------------
// grid (HW/256, 64, 1); buffers pre-offset to batch.
template<bool FUSE_MUL>
__global__ __launch_bounds__(256)
void group9(const float* __restrict__ in, const float* __restrict__ w9,
            const float* __restrict__ mul, float* __restrict__ out) {
  int c = blockIdx.y;
  int p = blockIdx.x * 256 + threadIdx.x;
  __shared__ float Wl[81];
  if (threadIdx.x < 81) Wl[threadIdx.x] = w9[(size_t)c * 81 + threadIdx.x];
  __syncthreads();
  size_t base = (size_t)(c * 9) * HWp + p;
  float v[9];
  #pragma unroll
  for (int k = 0; k < 9; k++) {
    float t = in[base + (size_t)k * HWp];
    if (FUSE_MUL) t *= mul[base + (size_t)k * HWp];
    v[k] = t;
  }
  #pragma unroll
  for (int j = 0; j < 9; j++) {
    float a = 0.f;
    #pragma unroll
    for (int k = 0; k < 9; k++) a += Wl[j * 9 + k] * v[k];
    out[base + (size_t)j * HWp] = a;
  }
}

// ---------------- depthwise 3x3 over 576 ch (per batch), ACT: 1 relu, 2 sigmoid ----------------
template<int ACT>
__global__ __launch_bounds__(256)
void dw3x3(const float* __restrict__ in, const float* __restrict__ w,
           float* __restrict__ out) {
  int ch = blockIdx.y;
  int p = blockIdx.x * 256 + threadIdx.x;
  int y = p >> 7, x = p & 127;
  __shared__ float ws[9];
  if (threadIdx.x < 9) ws[threadIdx.x] = w[(size_t)ch * 9 + threadIdx.x];
  __syncthreads();
  const float* ip = in + (size_t)ch * HWp;
  float acc = 0.f;
  #pragma unroll
  for (int k = 0; k < 9; k++) {
    int yy = y + k / 3 - 1, xx = x + k % 3 - 1;
    if (yy >= 0 && yy < Hp && xx >= 0 && xx < Wp) acc += ip[yy * Wp + xx] * ws[k];
  }
  float r = (ACT == 1) ? fmaxf(acc, 0.f) : 1.f / (1.f + expf(-acc));
  out[(size_t)ch * HWp + p] = r;
}

// ---------------- launch ----------------
extern "C" void kernel_launch(void* const* d_in, const int* in_sizes, int n_in,
                              void* d_out, int out_size, void* d_ws, size_t ws_size,
                              hipStream_t stream) {
  const float* x       = (const float*)d_in[0];
  const float* enc_dw  = (const float*)d_in[1];
  const float* enc_pw1 = (const float*)d_in[2];
  const float* enc_pw2 = (const float*)d_in[3];
  const float* dec_dw  = (const float*)d_in[4];
  const float* dec_pw1 = (const float*)d_in[5];
  const float* dec_pw2 = (const float*)d_in[6];
  const float* off_w1  = (const float*)d_in[7];
  const float* off_b1  = (const float*)d_in[8];
  const float* off_w2  = (const float*)d_in[9];
  const float* off_b2  = (const float*)d_in[10];
  const float* off_w3  = (const float*)d_in[11];
  const float* off_b3  = (const float*)d_in[12];
  const float* off_w4  = (const float*)d_in[13];
  const float* off_b4  = (const float*)d_in[14];
  const float* off_w5  = (const float*)d_in[15];
  const float* off_b5  = (const float*)d_in[16];
  const float* off_w6  = (const float*)d_in[17];
  const float* off_b6  = (const float*)d_in[18];
  const float* dct_w   = (const float*)d_in[19];
  const float* wie_w1  = (const float*)d_in[20];
  const float* wie_w2  = (const float*)d_in[21];
  const float* wie_w3  = (const float*)d_in[22];
  const float* wie_w4  = (const float*)d_in[23];
  const float* wie_w5  = (const float*)d_in[24];
  const float* wie_w6  = (const float*)d_in[25];
  const float* inv_w1  = (const float*)d_in[26];
  const float* inv_w2  = (const float*)d_in[27];
  float* outp = (float*)d_out;

  const size_t NP = (size_t)Bp * HWp;
  // Workspace layout (floats):
  //   x1   : NP*64    (enc out, full batch)
  //   t0   : NP*64    (dw7 tmp / offsets / dec dw7 tmp)
  //   t1   : NP*128   (pw1 tmp / offset ping-pong; later: dec-input "mid" in
  //                    first NP*64)
  //   bigA/bigB/bigC : HWp*576 each (per-batch middle)
  const size_t REQ_FLOATS = NP * 64 + NP * 64 + NP * 128 + 3 * (size_t)HWp * CKp;
  if (ws_size < REQ_FLOATS * sizeof(float)) return;  // diagnostic guard

  float* ws = (float*)d_ws;
  float* x1   = ws;
  float* t0   = x1 + NP * 64;
  float* t1   = t0 + NP * 64;
  float* bigA = t1 + NP * 128;
  float* bigB = bigA + (size_t)HWp * CKp;
  float* bigC = bigB + (size_t)HWp * CKp;
  float* off1 = t1;
  float* off2 = t1 + NP * 64;
  float* offs = t0;
  float* mid  = t1;   // dec-convnext input (64ch full batch), after offsets dead

  dim3 blk(256);

  // ---- enc ConvNeXt (full batch) ----
  dwconv7<<<dim3(HWp / 256, Bp * Cp), blk, 0, stream>>>(x, enc_dw, t0);
  conv1x1<1, false, false><<<dim3(HWp / 128, 2, Bp), blk, 0, stream>>>(
      t0, enc_pw1, nullptr, nullptr, t1, 64, 128);
  conv1x1<0, true, false><<<dim3(HWp / 128, 1, Bp), blk, 0, stream>>>(
      t1, enc_pw2, nullptr, x, x1, 128, 64);

  // ---- offset CNN (full batch) ----
  conv1x1<2, false, true><<<dim3(HWp / 128, 1, Bp), blk, 0, stream>>>(
      x1, off_w1, off_b1, nullptr, off1, 64, 64);
  conv3x3_64<<<dim3(HWp / 256, 2, Bp), blk, 0, stream>>>(off1, off_w2, off_b2, off2);
  conv3x3_64<<<dim3(HWp / 256, 2, Bp), blk, 0, stream>>>(off2, off_w3, off_b3, off1);
  conv3x3_64<<<dim3(HWp / 256, 2, Bp), blk, 0, stream>>>(off1, off_w4, off_b4, off2);
  conv3x3_64<<<dim3(HWp / 256, 2, Bp), blk, 0, stream>>>(off2, off_w5, off_b5, off1);
  off6_tanh<<<dim3(HWp / 256, Bp), blk, 0, stream>>>(off1, off_w6, off_b6, offs);
  // NOTE: offs lives in t0 channels [b*18, b*18+18); read per-batch below,
  // fully consumed before dec ConvNeXt reuses t0.

  // ---- 576-channel middle, one batch at a time ----
  for (int b = 0; b < Bp; b++) {
    const float* x1b  = x1 + (size_t)b * 64 * HWp;
    const float* offb = offs + (size_t)b * 18 * HWp;
    float* midb = mid + (size_t)b * 64 * HWp;

    deform<<<dim3(HWp / 256, 9), blk, 0, stream>>>(x1b, offb, bigA);
    group9<false><<<dim3(HWp / 256, Cp), blk, 0, stream>>>(bigA, dct_w, nullptr, bigB);
    conv1x1<0, false, false><<<dim3(HWp / 128, 9, 1), blk, 0, stream>>>(
        bigA, wie_w1, nullptr, nullptr, bigC, CKp, CKp);
    dw3x3<1><<<dim3(HWp / 256, CKp), blk, 0, stream>>>(bigC, wie_w2, bigA);
    conv1x1<0, false, false><<<dim3(HWp / 128, 9, 1), blk, 0, stream>>>(
        bigA, wie_w3, nullptr, nullptr, bigC, CKp, CKp);
    dw3x3<1><<<dim3(HWp / 256, CKp), blk, 0, stream>>>(bigC, wie_w4, bigA);
    conv1x1<0, false, false><<<dim3(HWp / 128, 9, 1), blk, 0, stream>>>(
        bigA, wie_w5, nullptr, nullptr, bigC, CKp, CKp);
    dw3x3<2><<<dim3(HWp / 256, CKp), blk, 0, stream>>>(bigC, wie_w6, bigA);
    group9<true><<<dim3(HWp / 256, Cp), blk, 0, stream>>>(bigA, inv_w1, bigB, bigC);
    conv1x1<0, false, false><<<dim3(HWp / 128, 1, 1), blk, 0, stream>>>(
        bigC, inv_w2, nullptr, nullptr, midb, CKp, 64);
  }

  // ---- dec ConvNeXt (full batch); pw1 scratch in big region ----
  dwconv7<<<dim3(HWp / 256, Bp * Cp), blk, 0, stream>>>(mid, dec_dw, t0);
  conv1x1<1, false, false><<<dim3(HWp / 128, 2, Bp), blk, 0, stream>>>(
      t0, dec_pw1, nullptr, nullptr, bigA, 64, 128);
  conv1x1<0, true, false><<<dim3(HWp / 128, 1, Bp), blk, 0, stream>>>(
      bigA, dec_pw2, nullptr, mid, outp, 128, 64);
}

// Round 3
// 2281.246 us; speedup vs baseline: 1.7578x; 1.7578x over previous
//
#include <hip/hip_runtime.h>
#include <math.h>

#define HWp 16384
#define Wp 128
#define Hp 128
#define Bp 4
#define Cp 64
#define CKp 576

typedef unsigned int u32;
typedef unsigned short ushortt;
typedef __attribute__((ext_vector_type(8))) short short8;
typedef __attribute__((ext_vector_type(4))) float float4v;

__device__ __forceinline__ ushortt f2b(float f) {
  union { float f; u32 u; } x; x.f = f;
  u32 r = x.u + 0x7fff + ((x.u >> 16) & 1);
  return (ushortt)(r >> 16);
}
__device__ __forceinline__ float b2f(ushortt h) {
  union { u32 u; float f; } x; x.u = ((u32)h) << 16; return x.f;
}
__device__ __forceinline__ void gll(const ushortt* g, ushortt* l) {
  __builtin_amdgcn_global_load_lds(
      (const __attribute__((address_space(1))) u32*)g,
      (__attribute__((address_space(3))) u32*)l, 16, 0, 0);
}

// ---------------- depthwise 7x7, pad 3 (ConvNeXt dw, NCHW) ----------------
__global__ __launch_bounds__(256)
void dwconv7(const float* __restrict__ in, const float* __restrict__ w,
             float* __restrict__ out) {
  int bc = blockIdx.y;
  int p  = blockIdx.x * 256 + threadIdx.x;
  __shared__ float ws[49];
  if (threadIdx.x < 49) ws[threadIdx.x] = w[(bc & 63) * 49 + threadIdx.x];
  __syncthreads();
  int y = p >> 7, x = p & 127;
  const float* ip = in + (size_t)bc * HWp;
  float acc = 0.f;
  #pragma unroll
  for (int dy = 0; dy < 7; dy++) {
    int yy = y + dy - 3;
    bool vy = (yy >= 0 && yy < Hp);
    #pragma unroll
    for (int dx = 0; dx < 7; dx++) {
      int xx = x + dx - 3;
      if (vy && xx >= 0 && xx < Wp) acc += ip[yy * Wp + xx] * ws[dy * 7 + dx];
    }
  }
  out[(size_t)bc * HWp + p] = acc;
}

// ---------------- fp32 1x1 conv (enc/dec/off1 only, NCHW) ----------------
template<int ACT, bool RESID, bool BIAS>
__global__ __launch_bounds__(256)
void conv1x1(const float* __restrict__ in, const float* __restrict__ wgt,
             const float* __restrict__ bias, const float* __restrict__ resid,
             float* __restrict__ out, int Cin, int Cout) {
  int b   = blockIdx.z;
  int p0  = blockIdx.x * 128;
  int co0 = blockIdx.y * 64;
  __shared__ float Wt[16][68];
  __shared__ float It[16][128];
  float acc[4][8];
  #pragma unroll
  for (int i = 0; i < 4; i++)
    #pragma unroll
    for (int j = 0; j < 8; j++) acc[i][j] = 0.f;

  const float* ip = in + (size_t)b * Cin * HWp + p0;
  int t = threadIdx.x;
  int wco = t >> 4, wkk = t & 15;
  int ipx = t & 127, ikr = t >> 7;
  int ty4 = (t >> 4) * 4, txa = (t & 15) * 4;

  for (int k0 = 0; k0 < Cin; k0 += 16) {
    #pragma unroll
    for (int i = 0; i < 4; i++)
      Wt[wkk][wco + 16 * i] = wgt[(size_t)(co0 + wco + 16 * i) * Cin + k0 + wkk];
    #pragma unroll
    for (int i = 0; i < 8; i++)
      It[ikr + 2 * i][ipx] = ip[(size_t)(k0 + ikr + 2 * i) * HWp + ipx];
    __syncthreads();
    #pragma unroll
    for (int kk = 0; kk < 16; kk++) {
      float4 wv = *(const float4*)&Wt[kk][ty4];
      float4 ia = *(const float4*)&It[kk][txa];
      float4 ib = *(const float4*)&It[kk][txa + 64];
      float iv[8] = {ia.x, ia.y, ia.z, ia.w, ib.x, ib.y, ib.z, ib.w};
      #pragma unroll
      for (int j = 0; j < 8; j++) {
        acc[0][j] += wv.x * iv[j];
        acc[1][j] += wv.y * iv[j];
        acc[2][j] += wv.z * iv[j];
        acc[3][j] += wv.w * iv[j];
      }
    }
    __syncthreads();
  }

  #pragma unroll
  for (int i = 0; i < 4; i++) {
    int co = co0 + ty4 + i;
    float bv = BIAS ? bias[co] : 0.f;
    #pragma unroll
    for (int hh = 0; hh < 2; hh++) {
      size_t base = ((size_t)b * Cout + co) * HWp + p0 + txa + hh * 64;
      float4 r;
      r.x = acc[i][hh * 4 + 0] + bv;
      r.y = acc[i][hh * 4 + 1] + bv;
      r.z = acc[i][hh * 4 + 2] + bv;
      r.w = acc[i][hh * 4 + 3] + bv;
      if (ACT == 1) {
        r.x = fmaxf(r.x, 0.f); r.y = fmaxf(r.y, 0.f);
        r.z = fmaxf(r.z, 0.f); r.w = fmaxf(r.w, 0.f);
      } else if (ACT == 2) {
        r.x = r.x > 0.f ? r.x : 0.1f * r.x;
        r.y = r.y > 0.f ? r.y : 0.1f * r.y;
        r.z = r.z > 0.f ? r.z : 0.1f * r.z;
        r.w = r.w > 0.f ? r.w : 0.1f * r.w;
      }
      if (RESID) {
        float4 rr = *(const float4*)&resid[base];
        r.x += rr.x; r.y += rr.y; r.z += rr.z; r.w += rr.w;
      }
      *(float4*)&out[base] = r;
    }
  }
}

// ---------------- 3x3 conv 64->64, bias + leaky (offset CNN, NCHW) ----------------
__global__ __launch_bounds__(256)
void conv3x3_64(const float* __restrict__ in, const float* __restrict__ wgt,
                const float* __restrict__ bias, float* __restrict__ out) {
  int b = blockIdx.z;
  int coh = blockIdx.y;
  int p = blockIdx.x * 256 + threadIdx.x;
  int y = p >> 7, x = p & 127;
  __shared__ float Wl[8 * 9 * 32];
  float acc[32];
  #pragma unroll
  for (int i = 0; i < 32; i++) acc[i] = 0.f;
  const float* ip = in + (size_t)b * 64 * HWp;

  for (int c0 = 0; c0 < 64; c0 += 8) {
    __syncthreads();
    for (int idx = threadIdx.x; idx < 8 * 9 * 32; idx += 256) {
      int co = idx & 31;
      int rest = idx >> 5;
      int k = rest % 9;
      int ci8 = rest / 9;
      Wl[idx] = wgt[(((size_t)(coh * 32 + co) * 64) + c0 + ci8) * 9 + k];
    }
    __syncthreads();
    for (int ci8 = 0; ci8 < 8; ci8++) {
      const float* pl = ip + (size_t)(c0 + ci8) * HWp;
      #pragma unroll
      for (int k = 0; k < 9; k++) {
        int yy = y + k / 3 - 1, xx = x + (k % 3) - 1;
        float v = (yy >= 0 && yy < Hp && xx >= 0 && xx < Wp) ? pl[yy * Wp + xx] : 0.f;
        const float* wr = &Wl[(ci8 * 9 + k) * 32];
        #pragma unroll
        for (int c4 = 0; c4 < 8; c4++) {
          float4 wv = *(const float4*)&wr[c4 * 4];
          acc[c4 * 4 + 0] += wv.x * v;
          acc[c4 * 4 + 1] += wv.y * v;
          acc[c4 * 4 + 2] += wv.z * v;
          acc[c4 * 4 + 3] += wv.w * v;
        }
      }
    }
  }
  #pragma unroll
  for (int co = 0; co < 32; co++) {
    float vv = acc[co] + bias[coh * 32 + co];
    vv = vv > 0.f ? vv : 0.1f * vv;
    out[((size_t)b * 64 + coh * 32 + co) * HWp + p] = vv;
  }
}

// ---------------- off_w6 (64->18) + bias + 8*tanh (NCHW) ----------------
__global__ __launch_bounds__(256)
void off6_tanh(const float* __restrict__ in, const float* __restrict__ wgt,
               const float* __restrict__ bias, float* __restrict__ out) {
  int b = blockIdx.y;
  int p = blockIdx.x * 256 + threadIdx.x;
  __shared__ float Wl[18 * 64];
  for (int i = threadIdx.x; i < 18 * 64; i += 256) {
    int j = i / 64, ci = i % 64;
    Wl[ci * 18 + j] = wgt[i];
  }
  __syncthreads();
  float acc[18];
  #pragma unroll
  for (int j = 0; j < 18; j++) acc[j] = 0.f;
  const float* ip = in + (size_t)b * 64 * HWp + p;
  for (int ci = 0; ci < 64; ci++) {
    float v = ip[(size_t)ci * HWp];
    #pragma unroll
    for (int j = 0; j < 18; j++) acc[j] += Wl[ci * 18 + j] * v;
  }
  #pragma unroll
  for (int j = 0; j < 18; j++)
    out[((size_t)b * 18 + j) * HWp + p] = 8.f * tanhf(acc[j] + bias[j]);
}

// ---------------- weight repacks (permuted channel order pi(c*9+k)=64k+c) ----------------
__global__ __launch_bounds__(256)
void rep576(const float* __restrict__ in, ushortt* __restrict__ out) {
  int idx = blockIdx.x * 256 + threadIdx.x;   // over 640*576
  if (idx >= 640 * 576) return;
  int cop = idx / 576, cip = idx % 576;
  ushortt v = 0;
  if (cop < 576) {
    int co = (cop & 63) * 9 + (cop >> 6);
    int ci = (cip & 63) * 9 + (cip >> 6);
    v = f2b(in[(size_t)co * 576 + ci]);
  }
  out[idx] = v;
}
__global__ __launch_bounds__(256)
void repinv2(const float* __restrict__ in, ushortt* __restrict__ out) {
  int idx = blockIdx.x * 256 + threadIdx.x;   // over 128*576
  if (idx >= 128 * 576) return;
  int co = idx / 576, cip = idx % 576;
  ushortt v = 0;
  if (co < 64) {
    int ci = (cip & 63) * 9 + (cip >> 6);
    v = f2b(in[(size_t)co * 576 + ci]);
  }
  out[idx] = v;
}
__global__ __launch_bounds__(256)
void repdw(const float* __restrict__ in, float* __restrict__ out) {
  int idx = blockIdx.x * 256 + threadIdx.x;   // over 5184
  if (idx >= 5184) return;
  int chp = idx / 9, k = idx % 9;
  int ch = (chp & 63) * 9 + (chp >> 6);
  out[idx] = in[ch * 9 + k];
}

// ---------------- deform -> NHWC bf16 (per batch) ----------------
// grid (HW/256, 9); x NCHW fp32, offs NCHW fp32 (18ch), xb NHWC bf16 [px][576]
__global__ __launch_bounds__(256)
void deform_nhwc(const float* __restrict__ x, const float* __restrict__ offs,
                 ushortt* __restrict__ xb) {
  __shared__ ushortt tile[256 * 66];
  int k = blockIdx.y;
  int tid = threadIdx.x;
  int p = blockIdx.x * 256 + tid;
  int yi = p >> 7, xi = p & 127;
  float dy = offs[(size_t)(2 * k) * HWp + p];
  float dx = offs[(size_t)(2 * k + 1) * HWp + p];
  float py = (float)yi + (float)(k / 3 - 1) + dy;
  float px = (float)xi + (float)(k % 3 - 1) + dx;
  float y0f = floorf(py), x0f = floorf(px);
  float wy1 = py - y0f, wy0 = 1.f - wy1;
  float wx1 = px - x0f, wx0 = 1.f - wx1;
  int y0 = (int)y0f, x0 = (int)x0f;
  bool vy0 = (y0 >= 0 && y0 < Hp), vy1 = (y0 + 1 >= 0 && y0 + 1 < Hp);
  bool vx0 = (x0 >= 0 && x0 < Wp), vx1 = (x0 + 1 >= 0 && x0 + 1 < Wp);
  int yc0 = min(max(y0, 0), Hp - 1), yc1 = min(max(y0 + 1, 0), Hp - 1);
  int xc0 = min(max(x0, 0), Wp - 1), xc1 = min(max(x0 + 1, 0), Wp - 1);
  int i00 = yc0 * Wp + xc0, i01 = yc0 * Wp + xc1;
  int i10 = yc1 * Wp + xc0, i11 = yc1 * Wp + xc1;
  float w00 = wy0 * wx0 * ((vy0 && vx0) ? 1.f : 0.f);
  float w01 = wy0 * wx1 * ((vy0 && vx1) ? 1.f : 0.f);
  float w10 = wy1 * wx0 * ((vy1 && vx0) ? 1.f : 0.f);
  float w11 = wy1 * wx1 * ((vy1 && vx1) ? 1.f : 0.f);
  u32 pair = 0;
  for (int c = 0; c < 64; c++) {
    const float* pl = x + (size_t)c * HWp;
    float v = pl[i00] * w00 + pl[i01] * w01 + pl[i10] * w10 + pl[i11] * w11;
    ushortt h = f2b(v);
    if (c & 1) {
      pair |= ((u32)h) << 16;
      *(u32*)&tile[tid * 66 + (c & ~1)] = pair;
    } else pair = h;
  }
  __syncthreads();
  const u32* tu = (const u32*)tile;
  u32* xo = (u32*)xb;
  int cpair = tid & 31, pxl0 = tid >> 5;
  for (int i = 0; i < 32; i++) {
    int pxl = pxl0 + 8 * i;
    u32 v = tu[pxl * 33 + cpair];
    xo[(size_t)(blockIdx.x * 256 + pxl) * 288 + 32 * k + cpair] = v;
  }
}

// ---------------- MFMA bf16 GEMM (NHWC): out[px][co] = sum_k X[px][k]*Wb[co][k]
// X [16384][576] bf16, Wb [Npad][576] bf16, out fp32 stride outStride.
// grid (128 pxTiles, coTiles); block 256 (4 waves); tile 128px x 128co, BK=32.
__global__ __launch_bounds__(256)
void gemm_bf16(const ushortt* __restrict__ X, const ushortt* __restrict__ Wb,
               float* __restrict__ out, int outStride, int coMax) {
  __shared__ ushortt Xs[128 * 32];
  __shared__ ushortt Wsh[128 * 32];
  int tid = threadIdx.x;
  int px0 = blockIdx.x * 128, co0 = blockIdx.y * 128;
  int row = tid >> 2, ch4 = tid & 3;
  const ushortt* gx = X + (size_t)(px0 + row) * 576 + ch4 * 8;
  const ushortt* gw = Wb + (size_t)(co0 + row) * 576 + ch4 * 8;
  int wid = tid >> 6, lane = tid & 63;
  int q = lane >> 4, m = lane & 15;
  int pxw = (wid & 1) * 64, cow = (wid >> 1) * 64;
  float4v acc[4][4];
  #pragma unroll
  for (int i = 0; i < 4; i++)
    #pragma unroll
    for (int j = 0; j < 4; j++) acc[i][j] = (float4v){0.f, 0.f, 0.f, 0.f};

  for (int k0 = 0; k0 < 576; k0 += 32) {
    __syncthreads();
    gll(gx + k0,             &Xs[tid * 8]);
    gll(gx + k0 + 64 * 576,  &Xs[2048 + tid * 8]);
    gll(gw + k0,             &Wsh[tid * 8]);
    gll(gw + k0 + 64 * 576,  &Wsh[2048 + tid * 8]);
    __syncthreads();
    short8 a[4], b[4];
    #pragma unroll
    for (int i = 0; i < 4; i++)
      a[i] = *(const short8*)&Xs[(pxw + i * 16 + m) * 32 + q * 8];
    #pragma unroll
    for (int j = 0; j < 4; j++)
      b[j] = *(const short8*)&Wsh[(cow + j * 16 + m) * 32 + q * 8];
    #pragma unroll
    for (int i = 0; i < 4; i++)
      #pragma unroll
      for (int j = 0; j < 4; j++)
        acc[i][j] = __builtin_amdgcn_mfma_f32_16x16x32_bf16(a[i], b[j], acc[i][j], 0, 0, 0);
  }

  #pragma unroll
  for (int j = 0; j < 4; j++) {
    int co = co0 + cow + j * 16 + m;
    if (co >= coMax) continue;
    #pragma unroll
    for (int i = 0; i < 4; i++) {
      int pxb = px0 + pxw + i * 16 + q * 4;
      #pragma unroll
      for (int r = 0; r < 4; r++)
        out[(size_t)(pxb + r) * outStride + co] = acc[i][j][r];
    }
  }
}

// ---------------- depthwise 3x3 NHWC (per batch), ACT 1 relu / 2 sigmoid ----------------
// in fp32 NHWC [px][576], wdw fp32 [576(perm)][9], out bf16 NHWC
template<int ACT>
__global__ __launch_bounds__(256)
void dw3x3_nhwc(const float* __restrict__ in, const float* __restrict__ wdw,
                ushortt* __restrict__ out) {
  int c0 = threadIdx.x & 63, pxl = threadIdx.x >> 6;
  int ch = blockIdx.y * 64 + c0;
  int px = blockIdx.x * 4 + pxl;
  int y = px >> 7, xx = px & 127;
  float w[9];
  #pragma unroll
  for (int k = 0; k < 9; k++) w[k] = wdw[ch * 9 + k];
  float acc = 0.f;
  #pragma unroll
  for (int k = 0; k < 9; k++) {
    int yy = y + k / 3 - 1, xw = xx + k % 3 - 1;
    if (yy >= 0 && yy < Hp && xw >= 0 && xw < Wp)
      acc += in[(size_t)(yy * Wp + xw) * 576 + ch] * w[k];
  }
  float r = (ACT == 1) ? fmaxf(acc, 0.f) : 1.f / (1.f + __expf(-acc));
  out[(size_t)px * 576 + ch] = f2b(r);
}

// ---------------- group 9->9 dct (NHWC): in bf16, out fp32 ----------------
__global__ __launch_bounds__(256)
void g9dct(const ushortt* __restrict__ xb, const float* __restrict__ w9,
           float* __restrict__ dct) {
  __shared__ float Wl[5184];
  for (int i = threadIdx.x; i < 5184; i += 256) Wl[i] = w9[i];
  __syncthreads();
  int c = threadIdx.x & 63, pxl = threadIdx.x >> 6;
  size_t px = (size_t)blockIdx.x * 4 + pxl;
  float v[9];
  #pragma unroll
  for (int kk = 0; kk < 9; kk++) v[kk] = b2f(xb[px * 576 + 64 * kk + c]);
  const float* wc = &Wl[c * 81];
  #pragma unroll
  for (int j = 0; j < 9; j++) {
    float a = 0.f;
    #pragma unroll
    for (int kk = 0; kk < 9; kk++) a += wc[j * 9 + kk] * v[kk];
    dct[px * 576 + 64 * j + c] = a;
  }
}

// ---------------- group 9->9 inv1 with fused wiener*dct (NHWC) ----------------
__global__ __launch_bounds__(256)
void g9inv(const ushortt* __restrict__ wien, const float* __restrict__ dct,
           const float* __restrict__ w9, ushortt* __restrict__ outb) {
  __shared__ float Wl[5184];
  for (int i = threadIdx.x; i < 5184; i += 256) Wl[i] = w9[i];
  __syncthreads();
  int c = threadIdx.x & 63, pxl = threadIdx.x >> 6;
  size_t px = (size_t)blockIdx.x * 4 + pxl;
  float v[9];
  #pragma unroll
  for (int kk = 0; kk < 9; kk++)
    v[kk] = b2f(wien[px * 576 + 64 * kk + c]) * dct[px * 576 + 64 * kk + c];
  const float* wc = &Wl[c * 81];
  #pragma unroll
  for (int j = 0; j < 9; j++) {
    float a = 0.f;
    #pragma unroll
    for (int kk = 0; kk < 9; kk++) a += wc[j * 9 + kk] * v[kk];
    outb[px * 576 + 64 * j + c] = f2b(a);
  }
}

// ---------------- transpose NHWC[16384][64] fp32 -> NCHW[64][16384] ----------------
__global__ __launch_bounds__(256)
void t64(const float* __restrict__ in, float* __restrict__ out) {
  __shared__ float tl[64 * 65];
  int tid = threadIdx.x;
  int px0 = blockIdx.x * 64;
  int c = tid & 63, r0 = tid >> 6;
  #pragma unroll
  for (int i = 0; i < 16; i++) {
    int r = r0 + 4 * i;
    tl[r * 65 + c] = in[(size_t)(px0 + r) * 64 + c];
  }
  __syncthreads();
  #pragma unroll
  for (int i = 0; i < 16; i++) {
    int cr = r0 + 4 * i;
    out[(size_t)cr * HWp + px0 + c] = tl[c * 65 + cr];
  }
}

// ---------------- launch ----------------
extern "C" void kernel_launch(void* const* d_in, const int* in_sizes, int n_in,
                              void* d_out, int out_size, void* d_ws, size_t ws_size,
                              hipStream_t stream) {
  const float* x       = (const float*)d_in[0];
  const float* enc_dw  = (const float*)d_in[1];
  const float* enc_pw1 = (const float*)d_in[2];
  const float* enc_pw2 = (const float*)d_in[3];
  const float* dec_dw  = (const float*)d_in[4];
  const float* dec_pw1 = (const float*)d_in[5];
  const float* dec_pw2 = (const float*)d_in[6];
  const float* off_w1  = (const float*)d_in[7];
  const float* off_b1  = (const float*)d_in[8];
  const float* off_w2  = (const float*)d_in[9];
  const float* off_b2  = (const float*)d_in[10];
  const float* off_w3  = (const float*)d_in[11];
  const float* off_b3  = (const float*)d_in[12];
  const float* off_w4  = (const float*)d_in[13];
  const float* off_b4  = (const float*)d_in[14];
  const float* off_w5  = (const float*)d_in[15];
  const float* off_b5  = (const float*)d_in[16];
  const float* off_w6  = (const float*)d_in[17];
  const float* off_b6  = (const float*)d_in[18];
  const float* dct_w   = (const float*)d_in[19];
  const float* wie_w1  = (const float*)d_in[20];
  const float* wie_w2  = (const float*)d_in[21];
  const float* wie_w3  = (const float*)d_in[22];
  const float* wie_w4  = (const float*)d_in[23];
  const float* wie_w5  = (const float*)d_in[24];
  const float* wie_w6  = (const float*)d_in[25];
  const float* inv_w1  = (const float*)d_in[26];
  const float* inv_w2  = (const float*)d_in[27];
  float* outp = (float*)d_out;

  const size_t NP = (size_t)Bp * HWp;
  // floats: x1(NP*64) t0(NP*64) t1(NP*128) bigA(HW*576) bigB(HW*576)
  //         xb(HW*576/2) actb(HW*576/2)  == 45,088,768 floats (180.4 MB)
  const size_t REQ_FLOATS = NP * 64 + NP * 64 + NP * 128 +
                            2 * (size_t)HWp * CKp + (size_t)HWp * CKp;
  if (ws_size < REQ_FLOATS * sizeof(float)) return;

  float* ws  = (float*)d_ws;
  float* x1  = ws;
  float* t0  = x1 + NP * 64;
  float* t1  = t0 + NP * 64;
  float* bigA = t1 + NP * 128;
  float* bigB = bigA + (size_t)HWp * CKp;
  ushortt* xbB   = (ushortt*)(bigB + (size_t)HWp * CKp);
  ushortt* actB  = xbB + (size_t)HWp * CKp;

  // weights live in t0 after the offset maps (t0[NP*18 ...])
  float* wreg = t0 + NP * 18;
  ushortt* wb1  = (ushortt*)wreg;
  ushortt* wb3  = wb1 + 640 * 576;
  ushortt* wb5  = wb3 + 640 * 576;
  ushortt* wbi2 = wb5 + 640 * 576;
  float* wdw2 = (float*)(wbi2 + 128 * 576);
  float* wdw4 = wdw2 + 5184;
  float* wdw6 = wdw4 + 5184;

  float* off1 = t1;
  float* off2 = t1 + NP * 64;
  float* offs = t0;
  float* mid  = t1;                    // dec input NCHW (full batch)
  float* midNHWC = t1 + NP * 64;       // per-batch inv2 output NHWC

  dim3 blk(256);

  // ---- enc ConvNeXt (full batch); pw1 tmp in bigA ----
  dwconv7<<<dim3(HWp / 256, Bp * Cp), blk, 0, stream>>>(x, enc_dw, t0);
  conv1x1<1, false, false><<<dim3(HWp / 128, 2, Bp), blk, 0, stream>>>(
      t0, enc_pw1, nullptr, nullptr, bigA, 64, 128);
  conv1x1<0, true, false><<<dim3(HWp / 128, 1, Bp), blk, 0, stream>>>(
      bigA, enc_pw2, nullptr, x, x1, 128, 64);

  // ---- weight repacks (after t0's dw7-tmp use) ----
  rep576<<<dim3((640 * 576 + 255) / 256), blk, 0, stream>>>(wie_w1, wb1);
  rep576<<<dim3((640 * 576 + 255) / 256), blk, 0, stream>>>(wie_w3, wb3);
  rep576<<<dim3((640 * 576 + 255) / 256), blk, 0, stream>>>(wie_w5, wb5);
  repinv2<<<dim3((128 * 576 + 255) / 256), blk, 0, stream>>>(inv_w2, wbi2);
  repdw<<<dim3((5184 + 255) / 256), blk, 0, stream>>>(wie_w2, wdw2);
  repdw<<<dim3((5184 + 255) / 256), blk, 0, stream>>>(wie_w4, wdw4);
  repdw<<<dim3((5184 + 255) / 256), blk, 0, stream>>>(wie_w6, wdw6);

  // ---- offset CNN (full batch) ----
  conv1x1<2, false, true><<<dim3(HWp / 128, 1, Bp), blk, 0, stream>>>(
      x1, off_w1, off_b1, nullptr, off1, 64, 64);
  conv3x3_64<<<dim3(HWp / 256, 2, Bp), blk, 0, stream>>>(off1, off_w2, off_b2, off2);
  conv3x3_64<<<dim3(HWp / 256, 2, Bp), blk, 0, stream>>>(off2, off_w3, off_b3, off1);
  conv3x3_64<<<dim3(HWp / 256, 2, Bp), blk, 0, stream>>>(off1, off_w4, off_b4, off2);
  conv3x3_64<<<dim3(HWp / 256, 2, Bp), blk, 0, stream>>>(off2, off_w5, off_b5, off1);
  off6_tanh<<<dim3(HWp / 256, Bp), blk, 0, stream>>>(off1, off_w6, off_b6, offs);

  // ---- 576-channel middle (NHWC, per batch) ----
  for (int b = 0; b < Bp; b++) {
    const float* x1b  = x1 + (size_t)b * 64 * HWp;
    const float* offb = offs + (size_t)b * 18 * HWp;

    deform_nhwc<<<dim3(HWp / 256, 9), blk, 0, stream>>>(x1b, offb, xbB);
    g9dct<<<dim3(HWp / 4), blk, 0, stream>>>(xbB, dct_w, bigB);
    gemm_bf16<<<dim3(128, 5), blk, 0, stream>>>(xbB, wb1, bigA, CKp, CKp);
    dw3x3_nhwc<1><<<dim3(HWp / 4, 9), blk, 0, stream>>>(bigA, wdw2, actB);
    gemm_bf16<<<dim3(128, 5), blk, 0, stream>>>(actB, wb3, bigA, CKp, CKp);
    dw3x3_nhwc<1><<<dim3(HWp / 4, 9), blk, 0, stream>>>(bigA, wdw4, actB);
    gemm_bf16<<<dim3(128, 5), blk, 0, stream>>>(actB, wb5, bigA, CKp, CKp);
    dw3x3_nhwc<2><<<dim3(HWp / 4, 9), blk, 0, stream>>>(bigA, wdw6, xbB);  // wiener
    g9inv<<<dim3(HWp / 4), blk, 0, stream>>>(xbB, bigB, inv_w1, actB);
    gemm_bf16<<<dim3(128, 1), blk, 0, stream>>>(actB, wbi2, midNHWC, 64, 64);
    t64<<<dim3(HWp / 64), blk, 0, stream>>>(midNHWC, mid + (size_t)b * 64 * HWp);
  }

  // ---- dec ConvNeXt (full batch); pw1 tmp in bigA ----
  dwconv7<<<dim3(HWp / 256, Bp * Cp), blk, 0, stream>>>(mid, dec_dw, t0);
  conv1x1<1, false, false><<<dim3(HWp / 128, 2, Bp), blk, 0, stream>>>(
      t0, dec_pw1, nullptr, nullptr, bigA, 64, 128);
  conv1x1<0, true, false><<<dim3(HWp / 128, 1, Bp), blk, 0, stream>>>(
      bigA, dec_pw2, nullptr, mid, outp, 128, 64);
}

// Round 4
// 1915.776 us; speedup vs baseline: 2.0931x; 1.1908x over previous
//
#include <hip/hip_runtime.h>
#include <math.h>

#define HWp 16384
#define Wp 128
#define Hp 128
#define Bp 4
#define Cp 64
#define CKp 576

typedef unsigned int u32;
typedef unsigned short ushortt;
typedef __attribute__((ext_vector_type(8))) short short8;
typedef __attribute__((ext_vector_type(4))) float float4v;

__device__ __forceinline__ ushortt f2b(float f) {
  union { float f; u32 u; } x; x.f = f;
  u32 r = x.u + 0x7fff + ((x.u >> 16) & 1);
  return (ushortt)(r >> 16);
}
__device__ __forceinline__ float b2f(ushortt h) {
  union { u32 u; float f; } x; x.u = ((u32)h) << 16; return x.f;
}
__device__ __forceinline__ void gll(const ushortt* g, ushortt* l) {
  __builtin_amdgcn_global_load_lds(
      (const __attribute__((address_space(1))) u32*)g,
      (__attribute__((address_space(3))) u32*)l, 16, 0, 0);
}

// ---------------- depthwise 7x7, pad 3 (ConvNeXt dw, NCHW) ----------------
__global__ __launch_bounds__(256)
void dwconv7(const float* __restrict__ in, const float* __restrict__ w,
             float* __restrict__ out) {
  int bc = blockIdx.y;
  int p  = blockIdx.x * 256 + threadIdx.x;
  __shared__ float ws[49];
  if (threadIdx.x < 49) ws[threadIdx.x] = w[(bc & 63) * 49 + threadIdx.x];
  __syncthreads();
  int y = p >> 7, x = p & 127;
  const float* ip = in + (size_t)bc * HWp;
  float acc = 0.f;
  #pragma unroll
  for (int dy = 0; dy < 7; dy++) {
    int yy = y + dy - 3;
    bool vy = (yy >= 0 && yy < Hp);
    #pragma unroll
    for (int dx = 0; dx < 7; dx++) {
      int xx = x + dx - 3;
      if (vy && xx >= 0 && xx < Wp) acc += ip[yy * Wp + xx] * ws[dy * 7 + dx];
    }
  }
  out[(size_t)bc * HWp + p] = acc;
}

// ---------------- fp32 1x1 conv (enc/dec, NCHW) ----------------
template<int ACT, bool RESID, bool BIAS>
__global__ __launch_bounds__(256)
void conv1x1(const float* __restrict__ in, const float* __restrict__ wgt,
             const float* __restrict__ bias, const float* __restrict__ resid,
             float* __restrict__ out, int Cin, int Cout) {
  int b   = blockIdx.z;
  int p0  = blockIdx.x * 128;
  int co0 = blockIdx.y * 64;
  __shared__ float Wt[16][68];
  __shared__ float It[16][128];
  float acc[4][8];
  #pragma unroll
  for (int i = 0; i < 4; i++)
    #pragma unroll
    for (int j = 0; j < 8; j++) acc[i][j] = 0.f;

  const float* ip = in + (size_t)b * Cin * HWp + p0;
  int t = threadIdx.x;
  int wco = t >> 4, wkk = t & 15;
  int ipx = t & 127, ikr = t >> 7;
  int ty4 = (t >> 4) * 4, txa = (t & 15) * 4;

  for (int k0 = 0; k0 < Cin; k0 += 16) {
    #pragma unroll
    for (int i = 0; i < 4; i++)
      Wt[wkk][wco + 16 * i] = wgt[(size_t)(co0 + wco + 16 * i) * Cin + k0 + wkk];
    #pragma unroll
    for (int i = 0; i < 8; i++)
      It[ikr + 2 * i][ipx] = ip[(size_t)(k0 + ikr + 2 * i) * HWp + ipx];
    __syncthreads();
    #pragma unroll
    for (int kk = 0; kk < 16; kk++) {
      float4 wv = *(const float4*)&Wt[kk][ty4];
      float4 ia = *(const float4*)&It[kk][txa];
      float4 ib = *(const float4*)&It[kk][txa + 64];
      float iv[8] = {ia.x, ia.y, ia.z, ia.w, ib.x, ib.y, ib.z, ib.w};
      #pragma unroll
      for (int j = 0; j < 8; j++) {
        acc[0][j] += wv.x * iv[j];
        acc[1][j] += wv.y * iv[j];
        acc[2][j] += wv.z * iv[j];
        acc[3][j] += wv.w * iv[j];
      }
    }
    __syncthreads();
  }

  #pragma unroll
  for (int i = 0; i < 4; i++) {
    int co = co0 + ty4 + i;
    float bv = BIAS ? bias[co] : 0.f;
    #pragma unroll
    for (int hh = 0; hh < 2; hh++) {
      size_t base = ((size_t)b * Cout + co) * HWp + p0 + txa + hh * 64;
      float4 r;
      r.x = acc[i][hh * 4 + 0] + bv;
      r.y = acc[i][hh * 4 + 1] + bv;
      r.z = acc[i][hh * 4 + 2] + bv;
      r.w = acc[i][hh * 4 + 3] + bv;
      if (ACT == 1) {
        r.x = fmaxf(r.x, 0.f); r.y = fmaxf(r.y, 0.f);
        r.z = fmaxf(r.z, 0.f); r.w = fmaxf(r.w, 0.f);
      } else if (ACT == 2) {
        r.x = r.x > 0.f ? r.x : 0.1f * r.x;
        r.y = r.y > 0.f ? r.y : 0.1f * r.y;
        r.z = r.z > 0.f ? r.z : 0.1f * r.z;
        r.w = r.w > 0.f ? r.w : 0.1f * r.w;
      }
      if (RESID) {
        float4 rr = *(const float4*)&resid[base];
        r.x += rr.x; r.y += rr.y; r.z += rr.z; r.w += rr.w;
      }
      *(float4*)&out[base] = r;
    }
  }
}

// ---------------- split-bf16 MFMA conv (1x1 or 3x3 pad1), NHWC hi/lo ----------------
// in/out: NHWC bf16 hi & lo, [NP px][64 ch]. w: [TAPS][64 co][64 ci] hi then lo.
// bias[64]; leaky 0.1 epilogue. grid (HWp/64, Bp), block 256 (4 waves).
// wave tile: 32 px x 32 co; block tile: 64 px (half row) x 64 co.
template<int TAPS>
__global__ __launch_bounds__(256)
void conv_mfma(const ushortt* __restrict__ inHi, const ushortt* __restrict__ inLo,
               const ushortt* __restrict__ wt, const float* __restrict__ bias,
               ushortt* __restrict__ outHi, ushortt* __restrict__ outLo) {
  int tid = threadIdx.x;
  int wid = tid >> 6, lane = tid & 63;
  int q = lane >> 4, m = lane & 15;
  int bx = blockIdx.x, b = blockIdx.y;
  int y = bx >> 1;
  int c0 = ((bx & 1) << 6) + ((wid & 1) << 5);
  int coW = (wid >> 1) << 5;
  const ushortt* wlo = wt + TAPS * 4096;
  size_t ibase = (size_t)b * HWp;

  float4v acc[2][2];
  #pragma unroll
  for (int i = 0; i < 2; i++)
    #pragma unroll
    for (int j = 0; j < 2; j++) acc[i][j] = (float4v){0.f, 0.f, 0.f, 0.f};
  short8 zz = {0, 0, 0, 0, 0, 0, 0, 0};

  #pragma unroll
  for (int k = 0; k < TAPS; k++) {
    int dy = (TAPS == 9) ? (k / 3 - 1) : 0;
    int dx = (TAPS == 9) ? (k % 3 - 1) : 0;
    int yy = y + dy;
    if (TAPS == 9 && (yy < 0 || yy >= Hp)) continue;
    #pragma unroll
    for (int ch = 0; ch < 2; ch++) {
      int ci0 = ch * 32 + q * 8;
      short8 bh[2], bl[2], ah[2], al[2];
      #pragma unroll
      for (int j = 0; j < 2; j++) {
        const ushortt* wp = &wt[(size_t)(k * 64 + coW + j * 16 + m) * 64 + ci0];
        bh[j] = *(const short8*)wp;
        bl[j] = *(const short8*)(wp + TAPS * 4096);
      }
      #pragma unroll
      for (int i = 0; i < 2; i++) {
        int col = c0 + i * 16 + m + dx;
        bool vld = (TAPS == 1) || ((unsigned)col < (unsigned)Wp);
        int colc = min(max(col, 0), Wp - 1);
        size_t a = (ibase + (size_t)yy * Wp + colc) * 64 + ci0;
        short8 h = *(const short8*)&inHi[a];
        short8 l = *(const short8*)&inLo[a];
        ah[i] = vld ? h : zz;
        al[i] = vld ? l : zz;
      }
      #pragma unroll
      for (int i = 0; i < 2; i++)
        #pragma unroll
        for (int j = 0; j < 2; j++) {
          acc[i][j] = __builtin_amdgcn_mfma_f32_16x16x32_bf16(ah[i], bh[j], acc[i][j], 0, 0, 0);
          acc[i][j] = __builtin_amdgcn_mfma_f32_16x16x32_bf16(ah[i], bl[j], acc[i][j], 0, 0, 0);
          acc[i][j] = __builtin_amdgcn_mfma_f32_16x16x32_bf16(al[i], bh[j], acc[i][j], 0, 0, 0);
        }
    }
  }

  #pragma unroll
  for (int j = 0; j < 2; j++) {
    int co = coW + j * 16 + m;
    float bv = bias[co];
    #pragma unroll
    for (int i = 0; i < 2; i++) {
      #pragma unroll
      for (int r = 0; r < 4; r++) {
        size_t px = ibase + (size_t)y * Wp + c0 + i * 16 + q * 4 + r;
        float v = acc[i][j][r] + bv;
        v = v > 0.f ? v : 0.1f * v;
        ushortt h = f2b(v);
        outHi[px * 64 + co] = h;
        outLo[px * 64 + co] = f2b(v - b2f(h));
      }
    }
  }
}

// ---------------- x1 NCHW fp32 -> NHWC bf16 hi/lo (per 64-px block) ----------------
__global__ __launch_bounds__(256)
void t64split(const float* __restrict__ in, ushortt* __restrict__ outHi,
              ushortt* __restrict__ outLo) {
  __shared__ float tl[64 * 65];
  int tid = threadIdx.x;
  int b = blockIdx.y;
  int px0 = blockIdx.x * 64;
  int lpx = tid & 63, c4 = tid >> 6;
  const float* ip = in + (size_t)b * 64 * HWp;
  #pragma unroll
  for (int i = 0; i < 16; i++) {
    int c = c4 + 4 * i;
    tl[lpx * 65 + c] = ip[(size_t)c * HWp + px0 + lpx];
  }
  __syncthreads();
  int ci = tid & 63, pr = tid >> 6;
  #pragma unroll
  for (int i = 0; i < 16; i++) {
    int r = pr + 4 * i;
    float v = tl[r * 65 + ci];
    ushortt h = f2b(v);
    size_t o = ((size_t)b * HWp + px0 + r) * 64 + ci;
    outHi[o] = h;
    outLo[o] = f2b(v - b2f(h));
  }
}

// ---------------- weight split-repack: (co,ci,taps) -> [k][co][ci] hi, then lo ----------------
__global__ __launch_bounds__(256)
void repsplit(const float* __restrict__ in, ushortt* __restrict__ out, int taps) {
  int idx = blockIdx.x * 256 + threadIdx.x;
  int tot = taps * 4096;
  if (idx >= tot) return;
  int k = idx >> 12, r = idx & 4095;
  int co = r >> 6, ci = r & 63;
  float v = in[(size_t)(co * 64 + ci) * taps + k];
  ushortt h = f2b(v);
  out[idx] = h;
  out[tot + idx] = f2b(v - b2f(h));
}

// ---------------- off_w6 (NHWC hi/lo in) -> NCHW offsets, 8*tanh ----------------
__global__ __launch_bounds__(256)
void off6_nhwc(const ushortt* __restrict__ hi, const ushortt* __restrict__ lo,
               const float* __restrict__ wgt, const float* __restrict__ bias,
               float* __restrict__ out) {
  __shared__ float Wl[18 * 64];
  for (int i = threadIdx.x; i < 18 * 64; i += 256) Wl[i] = wgt[i];
  __syncthreads();
  int px = blockIdx.x * 256 + threadIdx.x;
  int b = px >> 14, pim = px & 16383;
  float acc[18];
  #pragma unroll
  for (int j = 0; j < 18; j++) acc[j] = 0.f;
  const uint4* ph = (const uint4*)(hi + (size_t)px * 64);
  const uint4* pl = (const uint4*)(lo + (size_t)px * 64);
  for (int g = 0; g < 8; g++) {
    uint4 H = ph[g], L = pl[g];
    u32 hw[4] = {H.x, H.y, H.z, H.w};
    u32 lw[4] = {L.x, L.y, L.z, L.w};
    #pragma unroll
    for (int t = 0; t < 4; t++) {
      float v0 = b2f((ushortt)(hw[t] & 0xffff)) + b2f((ushortt)(lw[t] & 0xffff));
      float v1 = b2f((ushortt)(hw[t] >> 16)) + b2f((ushortt)(lw[t] >> 16));
      int ci = g * 8 + t * 2;
      #pragma unroll
      for (int j = 0; j < 18; j++)
        acc[j] += Wl[j * 64 + ci] * v0 + Wl[j * 64 + ci + 1] * v1;
    }
  }
  #pragma unroll
  for (int j = 0; j < 18; j++)
    out[((size_t)b * 18 + j) * HWp + pim] = 8.f * tanhf(acc[j] + bias[j]);
}

// ---------------- weight repacks (permuted channel order pi(c*9+k)=64k+c) ----------------
__global__ __launch_bounds__(256)
void rep576(const float* __restrict__ in, ushortt* __restrict__ out) {
  int idx = blockIdx.x * 256 + threadIdx.x;
  if (idx >= 640 * 576) return;
  int cop = idx / 576, cip = idx % 576;
  ushortt v = 0;
  if (cop < 576) {
    int co = (cop & 63) * 9 + (cop >> 6);
    int ci = (cip & 63) * 9 + (cip >> 6);
    v = f2b(in[(size_t)co * 576 + ci]);
  }
  out[idx] = v;
}
__global__ __launch_bounds__(256)
void repinv2(const float* __restrict__ in, ushortt* __restrict__ out) {
  int idx = blockIdx.x * 256 + threadIdx.x;
  if (idx >= 128 * 576) return;
  int co = idx / 576, cip = idx % 576;
  ushortt v = 0;
  if (co < 64) {
    int ci = (cip & 63) * 9 + (cip >> 6);
    v = f2b(in[(size_t)co * 576 + ci]);
  }
  out[idx] = v;
}
__global__ __launch_bounds__(256)
void repdw(const float* __restrict__ in, float* __restrict__ out) {
  int idx = blockIdx.x * 256 + threadIdx.x;
  if (idx >= 5184) return;
  int chp = idx / 9, k = idx % 9;
  int ch = (chp & 63) * 9 + (chp >> 6);
  out[idx] = in[ch * 9 + k];
}

// ---------------- deform -> NHWC bf16 (per batch) ----------------
__global__ __launch_bounds__(256)
void deform_nhwc(const float* __restrict__ x, const float* __restrict__ offs,
                 ushortt* __restrict__ xb) {
  __shared__ ushortt tile[256 * 66];
  int k = blockIdx.y;
  int tid = threadIdx.x;
  int p = blockIdx.x * 256 + tid;
  int yi = p >> 7, xi = p & 127;
  float dy = offs[(size_t)(2 * k) * HWp + p];
  float dx = offs[(size_t)(2 * k + 1) * HWp + p];
  float py = (float)yi + (float)(k / 3 - 1) + dy;
  float px = (float)xi + (float)(k % 3 - 1) + dx;
  float y0f = floorf(py), x0f = floorf(px);
  float wy1 = py - y0f, wy0 = 1.f - wy1;
  float wx1 = px - x0f, wx0 = 1.f - wx1;
  int y0 = (int)y0f, x0 = (int)x0f;
  bool vy0 = (y0 >= 0 && y0 < Hp), vy1 = (y0 + 1 >= 0 && y0 + 1 < Hp);
  bool vx0 = (x0 >= 0 && x0 < Wp), vx1 = (x0 + 1 >= 0 && x0 + 1 < Wp);
  int yc0 = min(max(y0, 0), Hp - 1), yc1 = min(max(y0 + 1, 0), Hp - 1);
  int xc0 = min(max(x0, 0), Wp - 1), xc1 = min(max(x0 + 1, 0), Wp - 1);
  int i00 = yc0 * Wp + xc0, i01 = yc0 * Wp + xc1;
  int i10 = yc1 * Wp + xc0, i11 = yc1 * Wp + xc1;
  float w00 = wy0 * wx0 * ((vy0 && vx0) ? 1.f : 0.f);
  float w01 = wy0 * wx1 * ((vy0 && vx1) ? 1.f : 0.f);
  float w10 = wy1 * wx0 * ((vy1 && vx0) ? 1.f : 0.f);
  float w11 = wy1 * wx1 * ((vy1 && vx1) ? 1.f : 0.f);
  u32 pair = 0;
  for (int c = 0; c < 64; c++) {
    const float* pl = x + (size_t)c * HWp;
    float v = pl[i00] * w00 + pl[i01] * w01 + pl[i10] * w10 + pl[i11] * w11;
    ushortt h = f2b(v);
    if (c & 1) {
      pair |= ((u32)h) << 16;
      *(u32*)&tile[tid * 66 + (c & ~1)] = pair;
    } else pair = h;
  }
  __syncthreads();
  const u32* tu = (const u32*)tile;
  u32* xo = (u32*)xb;
  int cpair = tid & 31, pxl0 = tid >> 5;
  for (int i = 0; i < 32; i++) {
    int pxl = pxl0 + 8 * i;
    u32 v = tu[pxl * 33 + cpair];
    xo[(size_t)(blockIdx.x * 256 + pxl) * 288 + 32 * k + cpair] = v;
  }
}

// ---------------- MFMA bf16 GEMM (NHWC middle) ----------------
__global__ __launch_bounds__(256)
void gemm_bf16(const ushortt* __restrict__ X, const ushortt* __restrict__ Wb,
               float* __restrict__ out, int outStride, int coMax) {
  __shared__ ushortt Xs[128 * 32];
  __shared__ ushortt Wsh[128 * 32];
  int tid = threadIdx.x;
  int px0 = blockIdx.x * 128, co0 = blockIdx.y * 128;
  int row = tid >> 2, ch4 = tid & 3;
  const ushortt* gx = X + (size_t)(px0 + row) * 576 + ch4 * 8;
  const ushortt* gw = Wb + (size_t)(co0 + row) * 576 + ch4 * 8;
  int wid = tid >> 6, lane = tid & 63;
  int q = lane >> 4, m = lane & 15;
  int pxw = (wid & 1) * 64, cow = (wid >> 1) * 64;
  float4v acc[4][4];
  #pragma unroll
  for (int i = 0; i < 4; i++)
    #pragma unroll
    for (int j = 0; j < 4; j++) acc[i][j] = (float4v){0.f, 0.f, 0.f, 0.f};

  for (int k0 = 0; k0 < 576; k0 += 32) {
    __syncthreads();
    gll(gx + k0,             &Xs[tid * 8]);
    gll(gx + k0 + 64 * 576,  &Xs[2048 + tid * 8]);
    gll(gw + k0,             &Wsh[tid * 8]);
    gll(gw + k0 + 64 * 576,  &Wsh[2048 + tid * 8]);
    __syncthreads();
    short8 a[4], b[4];
    #pragma unroll
    for (int i = 0; i < 4; i++)
      a[i] = *(const short8*)&Xs[(pxw + i * 16 + m) * 32 + q * 8];
    #pragma unroll
    for (int j = 0; j < 4; j++)
      b[j] = *(const short8*)&Wsh[(cow + j * 16 + m) * 32 + q * 8];
    #pragma unroll
    for (int i = 0; i < 4; i++)
      #pragma unroll
      for (int j = 0; j < 4; j++)
        acc[i][j] = __builtin_amdgcn_mfma_f32_16x16x32_bf16(a[i], b[j], acc[i][j], 0, 0, 0);
  }

  #pragma unroll
  for (int j = 0; j < 4; j++) {
    int co = co0 + cow + j * 16 + m;
    if (co >= coMax) continue;
    #pragma unroll
    for (int i = 0; i < 4; i++) {
      int pxb = px0 + pxw + i * 16 + q * 4;
      #pragma unroll
      for (int r = 0; r < 4; r++)
        out[(size_t)(pxb + r) * outStride + co] = acc[i][j][r];
    }
  }
}

// ---------------- depthwise 3x3 NHWC (per batch), ACT 1 relu / 2 sigmoid ----------------
template<int ACT>
__global__ __launch_bounds__(256)
void dw3x3_nhwc(const float* __restrict__ in, const float* __restrict__ wdw,
                ushortt* __restrict__ out) {
  int c0 = threadIdx.x & 63, pxl = threadIdx.x >> 6;
  int ch = blockIdx.y * 64 + c0;
  int px = blockIdx.x * 4 + pxl;
  int y = px >> 7, xx = px & 127;
  float w[9];
  #pragma unroll
  for (int k = 0; k < 9; k++) w[k] = wdw[ch * 9 + k];
  float acc = 0.f;
  #pragma unroll
  for (int k = 0; k < 9; k++) {
    int yy = y + k / 3 - 1, xw = xx + k % 3 - 1;
    if (yy >= 0 && yy < Hp && xw >= 0 && xw < Wp)
      acc += in[(size_t)(yy * Wp + xw) * 576 + ch] * w[k];
  }
  float r = (ACT == 1) ? fmaxf(acc, 0.f) : 1.f / (1.f + __expf(-acc));
  out[(size_t)px * 576 + ch] = f2b(r);
}

// ---------------- group 9->9 dct (NHWC): in bf16, out fp32 ----------------
__global__ __launch_bounds__(256)
void g9dct(const ushortt* __restrict__ xb, const float* __restrict__ w9,
           float* __restrict__ dct) {
  __shared__ float Wl[5184];
  for (int i = threadIdx.x; i < 5184; i += 256) Wl[i] = w9[i];
  __syncthreads();
  int c = threadIdx.x & 63, pxl = threadIdx.x >> 6;
  size_t px = (size_t)blockIdx.x * 4 + pxl;
  float v[9];
  #pragma unroll
  for (int kk = 0; kk < 9; kk++) v[kk] = b2f(xb[px * 576 + 64 * kk + c]);
  const float* wc = &Wl[c * 81];
  #pragma unroll
  for (int j = 0; j < 9; j++) {
    float a = 0.f;
    #pragma unroll
    for (int kk = 0; kk < 9; kk++) a += wc[j * 9 + kk] * v[kk];
    dct[px * 576 + 64 * j + c] = a;
  }
}

// ---------------- group 9->9 inv1 with fused wiener*dct (NHWC) ----------------
__global__ __launch_bounds__(256)
void g9inv(const ushortt* __restrict__ wien, const float* __restrict__ dct,
           const float* __restrict__ w9, ushortt* __restrict__ outb) {
  __shared__ float Wl[5184];
  for (int i = threadIdx.x; i < 5184; i += 256) Wl[i] = w9[i];
  __syncthreads();
  int c = threadIdx.x & 63, pxl = threadIdx.x >> 6;
  size_t px = (size_t)blockIdx.x * 4 + pxl;
  float v[9];
  #pragma unroll
  for (int kk = 0; kk < 9; kk++)
    v[kk] = b2f(wien[px * 576 + 64 * kk + c]) * dct[px * 576 + 64 * kk + c];
  const float* wc = &Wl[c * 81];
  #pragma unroll
  for (int j = 0; j < 9; j++) {
    float a = 0.f;
    #pragma unroll
    for (int kk = 0; kk < 9; kk++) a += wc[j * 9 + kk] * v[kk];
    outb[px * 576 + 64 * j + c] = f2b(a);
  }
}

// ---------------- transpose NHWC[16384][64] fp32 -> NCHW[64][16384] ----------------
__global__ __launch_bounds__(256)
void t64(const float* __restrict__ in, float* __restrict__ out) {
  __shared__ float tl[64 * 65];
  int tid = threadIdx.x;
  int px0 = blockIdx.x * 64;
  int c = tid & 63, r0 = tid >> 6;
  #pragma unroll
  for (int i = 0; i < 16; i++) {
    int r = r0 + 4 * i;
    tl[r * 65 + c] = in[(size_t)(px0 + r) * 64 + c];
  }
  __syncthreads();
  #pragma unroll
  for (int i = 0; i < 16; i++) {
    int cr = r0 + 4 * i;
    out[(size_t)cr * HWp + px0 + c] = tl[c * 65 + cr];
  }
}

// ---------------- launch ----------------
extern "C" void kernel_launch(void* const* d_in, const int* in_sizes, int n_in,
                              void* d_out, int out_size, void* d_ws, size_t ws_size,
                              hipStream_t stream) {
  const float* x       = (const float*)d_in[0];
  const float* enc_dw  = (const float*)d_in[1];
  const float* enc_pw1 = (const float*)d_in[2];
  const float* enc_pw2 = (const float*)d_in[3];
  const float* dec_dw  = (const float*)d_in[4];
  const float* dec_pw1 = (const float*)d_in[5];
  const float* dec_pw2 = (const float*)d_in[6];
  const float* off_w1  = (const float*)d_in[7];
  const float* off_b1  = (const float*)d_in[8];
  const float* off_w2  = (const float*)d_in[9];
  const float* off_b2  = (const float*)d_in[10];
  const float* off_w3  = (const float*)d_in[11];
  const float* off_b3  = (const float*)d_in[12];
  const float* off_w4  = (const float*)d_in[13];
  const float* off_b4  = (const float*)d_in[14];
  const float* off_w5  = (const float*)d_in[15];
  const float* off_b5  = (const float*)d_in[16];
  const float* off_w6  = (const float*)d_in[17];
  const float* off_b6  = (const float*)d_in[18];
  const float* dct_w   = (const float*)d_in[19];
  const float* wie_w1  = (const float*)d_in[20];
  const float* wie_w2  = (const float*)d_in[21];
  const float* wie_w3  = (const float*)d_in[22];
  const float* wie_w4  = (const float*)d_in[23];
  const float* wie_w5  = (const float*)d_in[24];
  const float* wie_w6  = (const float*)d_in[25];
  const float* inv_w1  = (const float*)d_in[26];
  const float* inv_w2  = (const float*)d_in[27];
  float* outp = (float*)d_out;

  const size_t NP = (size_t)Bp * HWp;
  const size_t REQ_FLOATS = NP * 64 + NP * 64 + NP * 128 +
                            2 * (size_t)HWp * CKp + (size_t)HWp * CKp;
  if (ws_size < REQ_FLOATS * sizeof(float)) return;

  float* ws  = (float*)d_ws;
  float* x1  = ws;
  float* t0  = x1 + NP * 64;
  float* t1  = t0 + NP * 64;
  float* bigA = t1 + NP * 128;
  float* bigB = bigA + (size_t)HWp * CKp;
  ushortt* xbB   = (ushortt*)(bigB + (size_t)HWp * CKp);
  ushortt* actB  = xbB + (size_t)HWp * CKp;

  // weight region in t0 after the offset maps
  float* wreg = t0 + NP * 18;
  ushortt* wb1  = (ushortt*)wreg;
  ushortt* wb3  = wb1 + 640 * 576;
  ushortt* wb5  = wb3 + 640 * 576;
  ushortt* wbi2 = wb5 + 640 * 576;
  float* wdw2 = (float*)(wbi2 + 128 * 576);
  float* wdw4 = wdw2 + 5184;
  float* wdw6 = wdw4 + 5184;
  ushortt* wc1 = (ushortt*)(wdw6 + 5184);   // [1][64][64] hi+lo
  ushortt* wc2 = wc1 + 2 * 4096;            // [9][64][64] hi+lo each
  ushortt* wc3 = wc2 + 2 * 36864;
  ushortt* wc4 = wc3 + 2 * 36864;
  ushortt* wc5 = wc4 + 2 * 36864;

  // offset-CNN NHWC bf16 hi/lo ping-pong in t1 (dead until "mid" use)
  ushortt* oAhi = (ushortt*)t1;
  ushortt* oAlo = oAhi + NP * 64;
  ushortt* oBhi = oAlo + NP * 64;
  ushortt* oBlo = oBhi + NP * 64;

  float* offs = t0;
  float* mid  = t1;                    // dec input NCHW (full batch)
  float* midNHWC = t1 + NP * 64;       // per-batch inv2 output NHWC

  dim3 blk(256);

  // ---- enc ConvNeXt (full batch); pw1 tmp in bigA ----
  dwconv7<<<dim3(HWp / 256, Bp * Cp), blk, 0, stream>>>(x, enc_dw, t0);
  conv1x1<1, false, false><<<dim3(HWp / 128, 2, Bp), blk, 0, stream>>>(
      t0, enc_pw1, nullptr, nullptr, bigA, 64, 128);
  conv1x1<0, true, false><<<dim3(HWp / 128, 1, Bp), blk, 0, stream>>>(
      bigA, enc_pw2, nullptr, x, x1, 128, 64);

  // ---- weight repacks (t0's dw7-tmp is dead now) ----
  rep576<<<dim3((640 * 576 + 255) / 256), blk, 0, stream>>>(wie_w1, wb1);
  rep576<<<dim3((640 * 576 + 255) / 256), blk, 0, stream>>>(wie_w3, wb3);
  rep576<<<dim3((640 * 576 + 255) / 256), blk, 0, stream>>>(wie_w5, wb5);
  repinv2<<<dim3((128 * 576 + 255) / 256), blk, 0, stream>>>(inv_w2, wbi2);
  repdw<<<dim3((5184 + 255) / 256), blk, 0, stream>>>(wie_w2, wdw2);
  repdw<<<dim3((5184 + 255) / 256), blk, 0, stream>>>(wie_w4, wdw4);
  repdw<<<dim3((5184 + 255) / 256), blk, 0, stream>>>(wie_w6, wdw6);
  repsplit<<<dim3((4096 + 255) / 256), blk, 0, stream>>>(off_w1, wc1, 1);
  repsplit<<<dim3((36864 + 255) / 256), blk, 0, stream>>>(off_w2, wc2, 9);
  repsplit<<<dim3((36864 + 255) / 256), blk, 0, stream>>>(off_w3, wc3, 9);
  repsplit<<<dim3((36864 + 255) / 256), blk, 0, stream>>>(off_w4, wc4, 9);
  repsplit<<<dim3((36864 + 255) / 256), blk, 0, stream>>>(off_w5, wc5, 9);

  // ---- offset CNN (full batch, split-bf16 MFMA, NHWC) ----
  t64split<<<dim3(HWp / 64, Bp), blk, 0, stream>>>(x1, oAhi, oAlo);
  conv_mfma<1><<<dim3(HWp / 64, Bp), blk, 0, stream>>>(oAhi, oAlo, wc1, off_b1, oBhi, oBlo);
  conv_mfma<9><<<dim3(HWp / 64, Bp), blk, 0, stream>>>(oBhi, oBlo, wc2, off_b2, oAhi, oAlo);
  conv_mfma<9><<<dim3(HWp / 64, Bp), blk, 0, stream>>>(oAhi, oAlo, wc3, off_b3, oBhi, oBlo);
  conv_mfma<9><<<dim3(HWp / 64, Bp), blk, 0, stream>>>(oBhi, oBlo, wc4, off_b4, oAhi, oAlo);
  conv_mfma<9><<<dim3(HWp / 64, Bp), blk, 0, stream>>>(oAhi, oAlo, wc5, off_b5, oBhi, oBlo);
  off6_nhwc<<<dim3(NP / 256), blk, 0, stream>>>(oBhi, oBlo, off_w6, off_b6, offs);

  // ---- 576-channel middle (NHWC, per batch) ----
  for (int b = 0; b < Bp; b++) {
    const float* x1b  = x1 + (size_t)b * 64 * HWp;
    const float* offb = offs + (size_t)b * 18 * HWp;

    deform_nhwc<<<dim3(HWp / 256, 9), blk, 0, stream>>>(x1b, offb, xbB);
    g9dct<<<dim3(HWp / 4), blk, 0, stream>>>(xbB, dct_w, bigB);
    gemm_bf16<<<dim3(128, 5), blk, 0, stream>>>(xbB, wb1, bigA, CKp, CKp);
    dw3x3_nhwc<1><<<dim3(HWp / 4, 9), blk, 0, stream>>>(bigA, wdw2, actB);
    gemm_bf16<<<dim3(128, 5), blk, 0, stream>>>(actB, wb3, bigA, CKp, CKp);
    dw3x3_nhwc<1><<<dim3(HWp / 4, 9), blk, 0, stream>>>(bigA, wdw4, actB);
    gemm_bf16<<<dim3(128, 5), blk, 0, stream>>>(actB, wb5, bigA, CKp, CKp);
    dw3x3_nhwc<2><<<dim3(HWp / 4, 9), blk, 0, stream>>>(bigA, wdw6, xbB);  // wiener
    g9inv<<<dim3(HWp / 4), blk, 0, stream>>>(xbB, bigB, inv_w1, actB);
    gemm_bf16<<<dim3(128, 1), blk, 0, stream>>>(actB, wbi2, midNHWC, 64, 64);
    t64<<<dim3(HWp / 64), blk, 0, stream>>>(midNHWC, mid + (size_t)b * 64 * HWp);
  }

  // ---- dec ConvNeXt (full batch); pw1 tmp in bigA ----
  dwconv7<<<dim3(HWp / 256, Bp * Cp), blk, 0, stream>>>(mid, dec_dw, t0);
  conv1x1<1, false, false><<<dim3(HWp / 128, 2, Bp), blk, 0, stream>>>(
      t0, dec_pw1, nullptr, nullptr, bigA, 64, 128);
  conv1x1<0, true, false><<<dim3(HWp / 128, 1, Bp), blk, 0, stream>>>(
      bigA, dec_pw2, nullptr, mid, outp, 128, 64);
}

// Round 5
// 1751.426 us; speedup vs baseline: 2.2895x; 1.0938x over previous
//
#include <hip/hip_runtime.h>
#include <math.h>

#define HWp 16384
#define Wp 128
#define Hp 128
#define Bp 4
#define Cp 64
#define CKp 576

typedef unsigned int u32;
typedef unsigned short ushortt;
typedef __attribute__((ext_vector_type(8))) short short8;
typedef __attribute__((ext_vector_type(4))) float float4v;

__device__ __forceinline__ ushortt f2b(float f) {
  union { float f; u32 u; } x; x.f = f;
  u32 r = x.u + 0x7fff + ((x.u >> 16) & 1);
  return (ushortt)(r >> 16);
}
__device__ __forceinline__ float b2f(ushortt h) {
  union { u32 u; float f; } x; x.u = ((u32)h) << 16; return x.f;
}
__device__ __forceinline__ void gll(const ushortt* g, ushortt* l) {
  __builtin_amdgcn_global_load_lds(
      (const __attribute__((address_space(1))) u32*)g,
      (__attribute__((address_space(3))) u32*)l, 16, 0, 0);
}

// ---------------- depthwise 7x7, pad 3, LDS-tiled (ConvNeXt dw, NCHW) ----------------
// grid (Hp/2, nMaps); block 256 = 2 output rows. LDS tile 8 rows x 136 (halo 3).
__global__ __launch_bounds__(256)
void dwconv7_lds(const float* __restrict__ in, const float* __restrict__ w,
                 float* __restrict__ out) {
  int bc = blockIdx.y;
  int tid = threadIdx.x;
  int y0 = blockIdx.x * 2;
  __shared__ float ws[49];
  __shared__ float tile[8][136];
  if (tid < 49) ws[tid] = w[(bc & 63) * 49 + tid];
  if (tid < 48) {                       // zero horizontal halo
    int r = tid / 6, cc = tid % 6;
    tile[r][cc < 3 ? cc : 128 + cc] = 0.f;
  }
  const float* ip = in + (size_t)bc * HWp;
  #pragma unroll
  for (int i = 0; i < 4; i++) {
    int idx = tid + 256 * i;
    int r = idx >> 7, xx = idx & 127;
    int yy = y0 - 3 + r;
    tile[r][xx + 3] = (yy >= 0 && yy < Hp) ? ip[yy * Wp + xx] : 0.f;
  }
  __syncthreads();
  int ty = tid >> 7, x = tid & 127;
  float acc = 0.f;
  #pragma unroll
  for (int dy = 0; dy < 7; dy++)
    #pragma unroll
    for (int dx = 0; dx < 7; dx++)
      acc += tile[ty + dy][x + dx] * ws[dy * 7 + dx];
  out[(size_t)bc * HWp + (y0 + ty) * Wp + x] = acc;
}

// ---------------- fp32 1x1 conv (enc/dec, NCHW) ----------------
template<int ACT, bool RESID, bool BIAS>
__global__ __launch_bounds__(256)
void conv1x1(const float* __restrict__ in, const float* __restrict__ wgt,
             const float* __restrict__ bias, const float* __restrict__ resid,
             float* __restrict__ out, int Cin, int Cout) {
  int b   = blockIdx.z;
  int p0  = blockIdx.x * 128;
  int co0 = blockIdx.y * 64;
  __shared__ float Wt[16][68];
  __shared__ float It[16][128];
  float acc[4][8];
  #pragma unroll
  for (int i = 0; i < 4; i++)
    #pragma unroll
    for (int j = 0; j < 8; j++) acc[i][j] = 0.f;

  const float* ip = in + (size_t)b * Cin * HWp + p0;
  int t = threadIdx.x;
  int wco = t >> 4, wkk = t & 15;
  int ipx = t & 127, ikr = t >> 7;
  int ty4 = (t >> 4) * 4, txa = (t & 15) * 4;

  for (int k0 = 0; k0 < Cin; k0 += 16) {
    #pragma unroll
    for (int i = 0; i < 4; i++)
      Wt[wkk][wco + 16 * i] = wgt[(size_t)(co0 + wco + 16 * i) * Cin + k0 + wkk];
    #pragma unroll
    for (int i = 0; i < 8; i++)
      It[ikr + 2 * i][ipx] = ip[(size_t)(k0 + ikr + 2 * i) * HWp + ipx];
    __syncthreads();
    #pragma unroll
    for (int kk = 0; kk < 16; kk++) {
      float4 wv = *(const float4*)&Wt[kk][ty4];
      float4 ia = *(const float4*)&It[kk][txa];
      float4 ib = *(const float4*)&It[kk][txa + 64];
      float iv[8] = {ia.x, ia.y, ia.z, ia.w, ib.x, ib.y, ib.z, ib.w};
      #pragma unroll
      for (int j = 0; j < 8; j++) {
        acc[0][j] += wv.x * iv[j];
        acc[1][j] += wv.y * iv[j];
        acc[2][j] += wv.z * iv[j];
        acc[3][j] += wv.w * iv[j];
      }
    }
    __syncthreads();
  }

  #pragma unroll
  for (int i = 0; i < 4; i++) {
    int co = co0 + ty4 + i;
    float bv = BIAS ? bias[co] : 0.f;
    #pragma unroll
    for (int hh = 0; hh < 2; hh++) {
      size_t base = ((size_t)b * Cout + co) * HWp + p0 + txa + hh * 64;
      float4 r;
      r.x = acc[i][hh * 4 + 0] + bv;
      r.y = acc[i][hh * 4 + 1] + bv;
      r.z = acc[i][hh * 4 + 2] + bv;
      r.w = acc[i][hh * 4 + 3] + bv;
      if (ACT == 1) {
        r.x = fmaxf(r.x, 0.f); r.y = fmaxf(r.y, 0.f);
        r.z = fmaxf(r.z, 0.f); r.w = fmaxf(r.w, 0.f);
      } else if (ACT == 2) {
        r.x = r.x > 0.f ? r.x : 0.1f * r.x;
        r.y = r.y > 0.f ? r.y : 0.1f * r.y;
        r.z = r.z > 0.f ? r.z : 0.1f * r.z;
        r.w = r.w > 0.f ? r.w : 0.1f * r.w;
      }
      if (RESID) {
        float4 rr = *(const float4*)&resid[base];
        r.x += rr.x; r.y += rr.y; r.z += rr.z; r.w += rr.w;
      }
      *(float4*)&out[base] = r;
    }
  }
}

// ---------------- split-bf16 MFMA conv (1x1 or 3x3 pad1), NHWC hi/lo ----------------
template<int TAPS>
__global__ __launch_bounds__(256)
void conv_mfma(const ushortt* __restrict__ inHi, const ushortt* __restrict__ inLo,
               const ushortt* __restrict__ wt, const float* __restrict__ bias,
               ushortt* __restrict__ outHi, ushortt* __restrict__ outLo) {
  int tid = threadIdx.x;
  int wid = tid >> 6, lane = tid & 63;
  int q = lane >> 4, m = lane & 15;
  int bx = blockIdx.x, b = blockIdx.y;
  int y = bx >> 1;
  int c0 = ((bx & 1) << 6) + ((wid & 1) << 5);
  int coW = (wid >> 1) << 5;
  size_t ibase = (size_t)b * HWp;

  float4v acc[2][2];
  #pragma unroll
  for (int i = 0; i < 2; i++)
    #pragma unroll
    for (int j = 0; j < 2; j++) acc[i][j] = (float4v){0.f, 0.f, 0.f, 0.f};
  short8 zz = {0, 0, 0, 0, 0, 0, 0, 0};

  #pragma unroll
  for (int k = 0; k < TAPS; k++) {
    int dy = (TAPS == 9) ? (k / 3 - 1) : 0;
    int dx = (TAPS == 9) ? (k % 3 - 1) : 0;
    int yy = y + dy;
    if (TAPS == 9 && (yy < 0 || yy >= Hp)) continue;
    #pragma unroll
    for (int ch = 0; ch < 2; ch++) {
      int ci0 = ch * 32 + q * 8;
      short8 bh[2], bl[2], ah[2], al[2];
      #pragma unroll
      for (int j = 0; j < 2; j++) {
        const ushortt* wp = &wt[(size_t)(k * 64 + coW + j * 16 + m) * 64 + ci0];
        bh[j] = *(const short8*)wp;
        bl[j] = *(const short8*)(wp + TAPS * 4096);
      }
      #pragma unroll
      for (int i = 0; i < 2; i++) {
        int col = c0 + i * 16 + m + dx;
        bool vld = (TAPS == 1) || ((unsigned)col < (unsigned)Wp);
        int colc = min(max(col, 0), Wp - 1);
        size_t a = (ibase + (size_t)yy * Wp + colc) * 64 + ci0;
        short8 h = *(const short8*)&inHi[a];
        short8 l = *(const short8*)&inLo[a];
        ah[i] = vld ? h : zz;
        al[i] = vld ? l : zz;
      }
      #pragma unroll
      for (int i = 0; i < 2; i++)
        #pragma unroll
        for (int j = 0; j < 2; j++) {
          acc[i][j] = __builtin_amdgcn_mfma_f32_16x16x32_bf16(ah[i], bh[j], acc[i][j], 0, 0, 0);
          acc[i][j] = __builtin_amdgcn_mfma_f32_16x16x32_bf16(ah[i], bl[j], acc[i][j], 0, 0, 0);
          acc[i][j] = __builtin_amdgcn_mfma_f32_16x16x32_bf16(al[i], bh[j], acc[i][j], 0, 0, 0);
        }
    }
  }

  #pragma unroll
  for (int j = 0; j < 2; j++) {
    int co = coW + j * 16 + m;
    float bv = bias[co];
    #pragma unroll
    for (int i = 0; i < 2; i++) {
      #pragma unroll
      for (int r = 0; r < 4; r++) {
        size_t px = ibase + (size_t)y * Wp + c0 + i * 16 + q * 4 + r;
        float v = acc[i][j][r] + bv;
        v = v > 0.f ? v : 0.1f * v;
        ushortt h = f2b(v);
        outHi[px * 64 + co] = h;
        outLo[px * 64 + co] = f2b(v - b2f(h));
      }
    }
  }
}

// ---------------- x1 NCHW fp32 -> NHWC bf16 hi/lo ----------------
__global__ __launch_bounds__(256)
void t64split(const float* __restrict__ in, ushortt* __restrict__ outHi,
              ushortt* __restrict__ outLo) {
  __shared__ float tl[64 * 65];
  int tid = threadIdx.x;
  int b = blockIdx.y;
  int px0 = blockIdx.x * 64;
  int lpx = tid & 63, c4 = tid >> 6;
  const float* ip = in + (size_t)b * 64 * HWp;
  #pragma unroll
  for (int i = 0; i < 16; i++) {
    int c = c4 + 4 * i;
    tl[lpx * 65 + c] = ip[(size_t)c * HWp + px0 + lpx];
  }
  __syncthreads();
  int ci = tid & 63, pr = tid >> 6;
  #pragma unroll
  for (int i = 0; i < 16; i++) {
    int r = pr + 4 * i;
    float v = tl[r * 65 + ci];
    ushortt h = f2b(v);
    size_t o = ((size_t)b * HWp + px0 + r) * 64 + ci;
    outHi[o] = h;
    outLo[o] = f2b(v - b2f(h));
  }
}

// ---------------- x1b NCHW fp32 -> NHWC bf16 (per batch, hi only) ----------------
__global__ __launch_bounds__(256)
void tx64b(const float* __restrict__ in, ushortt* __restrict__ out) {
  __shared__ float tl[64 * 65];
  int tid = threadIdx.x;
  int px0 = blockIdx.x * 64;
  int lpx = tid & 63, c4 = tid >> 6;
  #pragma unroll
  for (int i = 0; i < 16; i++) {
    int c = c4 + 4 * i;
    tl[lpx * 65 + c] = in[(size_t)c * HWp + px0 + lpx];
  }
  __syncthreads();
  int ci = tid & 63, pr = tid >> 6;
  #pragma unroll
  for (int i = 0; i < 16; i++) {
    int r = pr + 4 * i;
    out[(size_t)(px0 + r) * 64 + ci] = f2b(tl[r * 65 + ci]);
  }
}

// ---------------- weight split-repack ----------------
__global__ __launch_bounds__(256)
void repsplit(const float* __restrict__ in, ushortt* __restrict__ out, int taps) {
  int idx = blockIdx.x * 256 + threadIdx.x;
  int tot = taps * 4096;
  if (idx >= tot) return;
  int k = idx >> 12, r = idx & 4095;
  int co = r >> 6, ci = r & 63;
  float v = in[(size_t)(co * 64 + ci) * taps + k];
  ushortt h = f2b(v);
  out[idx] = h;
  out[tot + idx] = f2b(v - b2f(h));
}

// ---------------- off_w6 (NHWC hi/lo in) -> NCHW offsets, 8*tanh ----------------
__global__ __launch_bounds__(256)
void off6_nhwc(const ushortt* __restrict__ hi, const ushortt* __restrict__ lo,
               const float* __restrict__ wgt, const float* __restrict__ bias,
               float* __restrict__ out) {
  __shared__ float Wl[18 * 64];
  for (int i = threadIdx.x; i < 18 * 64; i += 256) Wl[i] = wgt[i];
  __syncthreads();
  int px = blockIdx.x * 256 + threadIdx.x;
  int b = px >> 14, pim = px & 16383;
  float acc[18];
  #pragma unroll
  for (int j = 0; j < 18; j++) acc[j] = 0.f;
  const uint4* ph = (const uint4*)(hi + (size_t)px * 64);
  const uint4* pl = (const uint4*)(lo + (size_t)px * 64);
  for (int g = 0; g < 8; g++) {
    uint4 H = ph[g], L = pl[g];
    u32 hw[4] = {H.x, H.y, H.z, H.w};
    u32 lw[4] = {L.x, L.y, L.z, L.w};
    #pragma unroll
    for (int t = 0; t < 4; t++) {
      float v0 = b2f((ushortt)(hw[t] & 0xffff)) + b2f((ushortt)(lw[t] & 0xffff));
      float v1 = b2f((ushortt)(hw[t] >> 16)) + b2f((ushortt)(lw[t] >> 16));
      int ci = g * 8 + t * 2;
      #pragma unroll
      for (int j = 0; j < 18; j++)
        acc[j] += Wl[j * 64 + ci] * v0 + Wl[j * 64 + ci + 1] * v1;
    }
  }
  #pragma unroll
  for (int j = 0; j < 18; j++)
    out[((size_t)b * 18 + j) * HWp + pim] = 8.f * tanhf(acc[j] + bias[j]);
}

// ---------------- weight repacks (permuted channel order pi(c*9+k)=64k+c) ----------------
__global__ __launch_bounds__(256)
void rep576(const float* __restrict__ in, ushortt* __restrict__ out) {
  int idx = blockIdx.x * 256 + threadIdx.x;
  if (idx >= 640 * 576) return;
  int cop = idx / 576, cip = idx % 576;
  ushortt v = 0;
  if (cop < 576) {
    int co = (cop & 63) * 9 + (cop >> 6);
    int ci = (cip & 63) * 9 + (cip >> 6);
    v = f2b(in[(size_t)co * 576 + ci]);
  }
  out[idx] = v;
}
__global__ __launch_bounds__(256)
void repinv2(const float* __restrict__ in, ushortt* __restrict__ out) {
  int idx = blockIdx.x * 256 + threadIdx.x;
  if (idx >= 128 * 576) return;
  int co = idx / 576, cip = idx % 576;
  ushortt v = 0;
  if (co < 64) {
    int ci = (cip & 63) * 9 + (cip >> 6);
    v = f2b(in[(size_t)co * 576 + ci]);
  }
  out[idx] = v;
}
__global__ __launch_bounds__(256)
void repdw(const float* __restrict__ in, float* __restrict__ out) {
  int idx = blockIdx.x * 256 + threadIdx.x;
  if (idx >= 5184) return;
  int chp = idx / 9, k = idx % 9;
  int ch = (chp & 63) * 9 + (chp >> 6);
  out[idx] = in[ch * 9 + k];
}

// ---------------- deform: wave-per-(px,k), NHWC bf16 in/out ----------------
// grid (HWp/4, 9); xn NHWC bf16 [px][64], offs NCHW fp32 (18ch), xb NHWC bf16 [px][576]
__global__ __launch_bounds__(256)
void deform_wave(const ushortt* __restrict__ xn, const float* __restrict__ offs,
                 ushortt* __restrict__ xb) {
  int tid = threadIdx.x;
  int wid = tid >> 6, lane = tid & 63;
  int k = blockIdx.y;
  int p = blockIdx.x * 4 + wid;
  int yi = p >> 7, xi = p & 127;
  float dy = offs[(size_t)(2 * k) * HWp + p];
  float dx = offs[(size_t)(2 * k + 1) * HWp + p];
  float py = (float)yi + (float)(k / 3 - 1) + dy;
  float px = (float)xi + (float)(k % 3 - 1) + dx;
  float y0f = floorf(py), x0f = floorf(px);
  float wy1 = py - y0f, wy0 = 1.f - wy1;
  float wx1 = px - x0f, wx0 = 1.f - wx1;
  int y0 = (int)y0f, x0 = (int)x0f;
  bool vy0 = (y0 >= 0 && y0 < Hp), vy1 = (y0 + 1 >= 0 && y0 + 1 < Hp);
  bool vx0 = (x0 >= 0 && x0 < Wp), vx1 = (x0 + 1 >= 0 && x0 + 1 < Wp);
  int yc0 = min(max(y0, 0), Hp - 1), yc1 = min(max(y0 + 1, 0), Hp - 1);
  int xc0 = min(max(x0, 0), Wp - 1), xc1 = min(max(x0 + 1, 0), Wp - 1);
  float w00 = wy0 * wx0 * ((vy0 && vx0) ? 1.f : 0.f);
  float w01 = wy0 * wx1 * ((vy0 && vx1) ? 1.f : 0.f);
  float w10 = wy1 * wx0 * ((vy1 && vx0) ? 1.f : 0.f);
  float w11 = wy1 * wx1 * ((vy1 && vx1) ? 1.f : 0.f);
  float v00 = b2f(xn[(size_t)(yc0 * Wp + xc0) * 64 + lane]);
  float v01 = b2f(xn[(size_t)(yc0 * Wp + xc1) * 64 + lane]);
  float v10 = b2f(xn[(size_t)(yc1 * Wp + xc0) * 64 + lane]);
  float v11 = b2f(xn[(size_t)(yc1 * Wp + xc1) * 64 + lane]);
  float v = v00 * w00 + v01 * w01 + v10 * w10 + v11 * w11;
  xb[(size_t)p * 576 + 64 * k + lane] = f2b(v);
}

// ---------------- MFMA bf16 GEMM (NHWC middle); OUT: 0 fp32, 1 bf16 ----------------
template<int OUT>
__global__ __launch_bounds__(256)
void gemm_bf16(const ushortt* __restrict__ X, const ushortt* __restrict__ Wb,
               void* __restrict__ outv, int outStride, int coMax) {
  __shared__ ushortt Xs[128 * 32];
  __shared__ ushortt Wsh[128 * 32];
  int tid = threadIdx.x;
  int px0 = blockIdx.x * 128, co0 = blockIdx.y * 128;
  int row = tid >> 2, ch4 = tid & 3;
  const ushortt* gx = X + (size_t)(px0 + row) * 576 + ch4 * 8;
  const ushortt* gw = Wb + (size_t)(co0 + row) * 576 + ch4 * 8;
  int wid = tid >> 6, lane = tid & 63;
  int q = lane >> 4, m = lane & 15;
  int pxw = (wid & 1) * 64, cow = (wid >> 1) * 64;
  float4v acc[4][4];
  #pragma unroll
  for (int i = 0; i < 4; i++)
    #pragma unroll
    for (int j = 0; j < 4; j++) acc[i][j] = (float4v){0.f, 0.f, 0.f, 0.f};

  for (int k0 = 0; k0 < 576; k0 += 32) {
    __syncthreads();
    gll(gx + k0,             &Xs[tid * 8]);
    gll(gx + k0 + 64 * 576,  &Xs[2048 + tid * 8]);
    gll(gw + k0,             &Wsh[tid * 8]);
    gll(gw + k0 + 64 * 576,  &Wsh[2048 + tid * 8]);
    __syncthreads();
    short8 a[4], b[4];
    #pragma unroll
    for (int i = 0; i < 4; i++)
      a[i] = *(const short8*)&Xs[(pxw + i * 16 + m) * 32 + q * 8];
    #pragma unroll
    for (int j = 0; j < 4; j++)
      b[j] = *(const short8*)&Wsh[(cow + j * 16 + m) * 32 + q * 8];
    #pragma unroll
    for (int i = 0; i < 4; i++)
      #pragma unroll
      for (int j = 0; j < 4; j++)
        acc[i][j] = __builtin_amdgcn_mfma_f32_16x16x32_bf16(a[i], b[j], acc[i][j], 0, 0, 0);
  }

  #pragma unroll
  for (int j = 0; j < 4; j++) {
    int co = co0 + cow + j * 16 + m;
    if (co >= coMax) continue;
    #pragma unroll
    for (int i = 0; i < 4; i++) {
      int pxb = px0 + pxw + i * 16 + q * 4;
      #pragma unroll
      for (int r = 0; r < 4; r++) {
        if (OUT == 0)
          ((float*)outv)[(size_t)(pxb + r) * outStride + co] = acc[i][j][r];
        else
          ((ushortt*)outv)[(size_t)(pxb + r) * outStride + co] = f2b(acc[i][j][r]);
      }
    }
  }
}

// ---------------- depthwise 3x3 NHWC bf16 (per batch), ACT 1 relu / 2 sigmoid ----------------
template<int ACT>
__global__ __launch_bounds__(256)
void dw3x3_nhwc(const ushortt* __restrict__ in, const float* __restrict__ wdw,
                ushortt* __restrict__ out) {
  int c0 = threadIdx.x & 63, pxl = threadIdx.x >> 6;
  int ch = blockIdx.y * 64 + c0;
  int px = blockIdx.x * 4 + pxl;
  int y = px >> 7, xx = px & 127;
  float w[9];
  #pragma unroll
  for (int k = 0; k < 9; k++) w[k] = wdw[ch * 9 + k];
  float acc = 0.f;
  #pragma unroll
  for (int k = 0; k < 9; k++) {
    int yy = y + k / 3 - 1, xw = xx + k % 3 - 1;
    if (yy >= 0 && yy < Hp && xw >= 0 && xw < Wp)
      acc += b2f(in[(size_t)(yy * Wp + xw) * 576 + ch]) * w[k];
  }
  float r = (ACT == 1) ? fmaxf(acc, 0.f) : 1.f / (1.f + __expf(-acc));
  out[(size_t)px * 576 + ch] = f2b(r);
}

// ---------------- group 9->9 dct (NHWC): in bf16, out fp32 ----------------
__global__ __launch_bounds__(256)
void g9dct(const ushortt* __restrict__ xb, const float* __restrict__ w9,
           float* __restrict__ dct) {
  __shared__ float Wl[5184];
  for (int i = threadIdx.x; i < 5184; i += 256) Wl[i] = w9[i];
  __syncthreads();
  int c = threadIdx.x & 63, pxl = threadIdx.x >> 6;
  size_t px = (size_t)blockIdx.x * 4 + pxl;
  float v[9];
  #pragma unroll
  for (int kk = 0; kk < 9; kk++) v[kk] = b2f(xb[px * 576 + 64 * kk + c]);
  const float* wc = &Wl[c * 81];
  #pragma unroll
  for (int j = 0; j < 9; j++) {
    float a = 0.f;
    #pragma unroll
    for (int kk = 0; kk < 9; kk++) a += wc[j * 9 + kk] * v[kk];
    dct[px * 576 + 64 * j + c] = a;
  }
}

// ---------------- group 9->9 inv1 with fused wiener*dct (NHWC) ----------------
__global__ __launch_bounds__(256)
void g9inv(const ushortt* __restrict__ wien, const float* __restrict__ dct,
           const float* __restrict__ w9, ushortt* __restrict__ outb) {
  __shared__ float Wl[5184];
  for (int i = threadIdx.x; i < 5184; i += 256) Wl[i] = w9[i];
  __syncthreads();
  int c = threadIdx.x & 63, pxl = threadIdx.x >> 6;
  size_t px = (size_t)blockIdx.x * 4 + pxl;
  float v[9];
  #pragma unroll
  for (int kk = 0; kk < 9; kk++)
    v[kk] = b2f(wien[px * 576 + 64 * kk + c]) * dct[px * 576 + 64 * kk + c];
  const float* wc = &Wl[c * 81];
  #pragma unroll
  for (int j = 0; j < 9; j++) {
    float a = 0.f;
    #pragma unroll
    for (int kk = 0; kk < 9; kk++) a += wc[j * 9 + kk] * v[kk];
    outb[px * 576 + 64 * j + c] = f2b(a);
  }
}

// ---------------- transpose NHWC[16384][64] fp32 -> NCHW[64][16384] ----------------
__global__ __launch_bounds__(256)
void t64(const float* __restrict__ in, float* __restrict__ out) {
  __shared__ float tl[64 * 65];
  int tid = threadIdx.x;
  int px0 = blockIdx.x * 64;
  int c = tid & 63, r0 = tid >> 6;
  #pragma unroll
  for (int i = 0; i < 16; i++) {
    int r = r0 + 4 * i;
    tl[r * 65 + c] = in[(size_t)(px0 + r) * 64 + c];
  }
  __syncthreads();
  #pragma unroll
  for (int i = 0; i < 16; i++) {
    int cr = r0 + 4 * i;
    out[(size_t)cr * HWp + px0 + c] = tl[c * 65 + cr];
  }
}

// ---------------- launch ----------------
extern "C" void kernel_launch(void* const* d_in, const int* in_sizes, int n_in,
                              void* d_out, int out_size, void* d_ws, size_t ws_size,
                              hipStream_t stream) {
  const float* x       = (const float*)d_in[0];
  const float* enc_dw  = (const float*)d_in[1];
  const float* enc_pw1 = (const float*)d_in[2];
  const float* enc_pw2 = (const float*)d_in[3];
  const float* dec_dw  = (const float*)d_in[4];
  const float* dec_pw1 = (const float*)d_in[5];
  const float* dec_pw2 = (const float*)d_in[6];
  const float* off_w1  = (const float*)d_in[7];
  const float* off_b1  = (const float*)d_in[8];
  const float* off_w2  = (const float*)d_in[9];
  const float* off_b2  = (const float*)d_in[10];
  const float* off_w3  = (const float*)d_in[11];
  const float* off_b3  = (const float*)d_in[12];
  const float* off_w4  = (const float*)d_in[13];
  const float* off_b4  = (const float*)d_in[14];
  const float* off_w5  = (const float*)d_in[15];
  const float* off_b5  = (const float*)d_in[16];
  const float* off_w6  = (const float*)d_in[17];
  const float* off_b6  = (const float*)d_in[18];
  const float* dct_w   = (const float*)d_in[19];
  const float* wie_w1  = (const float*)d_in[20];
  const float* wie_w2  = (const float*)d_in[21];
  const float* wie_w3  = (const float*)d_in[22];
  const float* wie_w4  = (const float*)d_in[23];
  const float* wie_w5  = (const float*)d_in[24];
  const float* wie_w6  = (const float*)d_in[25];
  const float* inv_w1  = (const float*)d_in[26];
  const float* inv_w2  = (const float*)d_in[27];
  float* outp = (float*)d_out;

  const size_t NP = (size_t)Bp * HWp;
  const size_t REQ_FLOATS = NP * 64 + NP * 64 + NP * 128 +
                            2 * (size_t)HWp * CKp + (size_t)HWp * CKp;
  if (ws_size < REQ_FLOATS * sizeof(float)) return;

  float* ws  = (float*)d_ws;
  float* x1  = ws;
  float* t0  = x1 + NP * 64;
  float* t1  = t0 + NP * 64;
  float* bigA = t1 + NP * 128;
  float* bigB = bigA + (size_t)HWp * CKp;
  ushortt* xbB   = (ushortt*)(bigB + (size_t)HWp * CKp);
  ushortt* actB  = xbB + (size_t)HWp * CKp;
  // bigA reinterpreted: first half = gB (bf16 gemm out), second half = xn
  ushortt* gB = (ushortt*)bigA;
  ushortt* xn = (ushortt*)(bigA + (size_t)HWp * CKp / 2);

  // weight region in t0 after the offset maps
  float* wreg = t0 + NP * 18;
  ushortt* wb1  = (ushortt*)wreg;
  ushortt* wb3  = wb1 + 640 * 576;
  ushortt* wb5  = wb3 + 640 * 576;
  ushortt* wbi2 = wb5 + 640 * 576;
  float* wdw2 = (float*)(wbi2 + 128 * 576);
  float* wdw4 = wdw2 + 5184;
  float* wdw6 = wdw4 + 5184;
  ushortt* wc1 = (ushortt*)(wdw6 + 5184);
  ushortt* wc2 = wc1 + 2 * 4096;
  ushortt* wc3 = wc2 + 2 * 36864;
  ushortt* wc4 = wc3 + 2 * 36864;
  ushortt* wc5 = wc4 + 2 * 36864;

  // offset-CNN NHWC bf16 hi/lo ping-pong in t1
  ushortt* oAhi = (ushortt*)t1;
  ushortt* oAlo = oAhi + NP * 64;
  ushortt* oBhi = oAlo + NP * 64;
  ushortt* oBlo = oBhi + NP * 64;

  float* offs = t0;
  float* mid  = t1;
  float* midNHWC = t1 + NP * 64;

  dim3 blk(256);

  // ---- enc ConvNeXt (full batch); pw1 tmp in bigA ----
  dwconv7_lds<<<dim3(Hp / 2, Bp * Cp), blk, 0, stream>>>(x, enc_dw, t0);
  conv1x1<1, false, false><<<dim3(HWp / 128, 2, Bp), blk, 0, stream>>>(
      t0, enc_pw1, nullptr, nullptr, bigA, 64, 128);
  conv1x1<0, true, false><<<dim3(HWp / 128, 1, Bp), blk, 0, stream>>>(
      bigA, enc_pw2, nullptr, x, x1, 128, 64);

  // ---- weight repacks ----
  rep576<<<dim3((640 * 576 + 255) / 256), blk, 0, stream>>>(wie_w1, wb1);
  rep576<<<dim3((640 * 576 + 255) / 256), blk, 0, stream>>>(wie_w3, wb3);
  rep576<<<dim3((640 * 576 + 255) / 256), blk, 0, stream>>>(wie_w5, wb5);
  repinv2<<<dim3((128 * 576 + 255) / 256), blk, 0, stream>>>(inv_w2, wbi2);
  repdw<<<dim3((5184 + 255) / 256), blk, 0, stream>>>(wie_w2, wdw2);
  repdw<<<dim3((5184 + 255) / 256), blk, 0, stream>>>(wie_w4, wdw4);
  repdw<<<dim3((5184 + 255) / 256), blk, 0, stream>>>(wie_w6, wdw6);
  repsplit<<<dim3((4096 + 255) / 256), blk, 0, stream>>>(off_w1, wc1, 1);
  repsplit<<<dim3((36864 + 255) / 256), blk, 0, stream>>>(off_w2, wc2, 9);
  repsplit<<<dim3((36864 + 255) / 256), blk, 0, stream>>>(off_w3, wc3, 9);
  repsplit<<<dim3((36864 + 255) / 256), blk, 0, stream>>>(off_w4, wc4, 9);
  repsplit<<<dim3((36864 + 255) / 256), blk, 0, stream>>>(off_w5, wc5, 9);

  // ---- offset CNN (full batch, split-bf16 MFMA, NHWC) ----
  t64split<<<dim3(HWp / 64, Bp), blk, 0, stream>>>(x1, oAhi, oAlo);
  conv_mfma<1><<<dim3(HWp / 64, Bp), blk, 0, stream>>>(oAhi, oAlo, wc1, off_b1, oBhi, oBlo);
  conv_mfma<9><<<dim3(HWp / 64, Bp), blk, 0, stream>>>(oBhi, oBlo, wc2, off_b2, oAhi, oAlo);
  conv_mfma<9><<<dim3(HWp / 64, Bp), blk, 0, stream>>>(oAhi, oAlo, wc3, off_b3, oBhi, oBlo);
  conv_mfma<9><<<dim3(HWp / 64, Bp), blk, 0, stream>>>(oBhi, oBlo, wc4, off_b4, oAhi, oAlo);
  conv_mfma<9><<<dim3(HWp / 64, Bp), blk, 0, stream>>>(oAhi, oAlo, wc5, off_b5, oBhi, oBlo);
  off6_nhwc<<<dim3(NP / 256), blk, 0, stream>>>(oBhi, oBlo, off_w6, off_b6, offs);

  // ---- 576-channel middle (NHWC, per batch, bf16 chain) ----
  for (int b = 0; b < Bp; b++) {
    const float* x1b  = x1 + (size_t)b * 64 * HWp;
    const float* offb = offs + (size_t)b * 18 * HWp;

    tx64b<<<dim3(HWp / 64), blk, 0, stream>>>(x1b, xn);
    deform_wave<<<dim3(HWp / 4, 9), blk, 0, stream>>>(xn, offb, xbB);
    g9dct<<<dim3(HWp / 4), blk, 0, stream>>>(xbB, dct_w, bigB);
    gemm_bf16<1><<<dim3(128, 5), blk, 0, stream>>>(xbB, wb1, gB, CKp, CKp);
    dw3x3_nhwc<1><<<dim3(HWp / 4, 9), blk, 0, stream>>>(gB, wdw2, actB);
    gemm_bf16<1><<<dim3(128, 5), blk, 0, stream>>>(actB, wb3, gB, CKp, CKp);
    dw3x3_nhwc<1><<<dim3(HWp / 4, 9), blk, 0, stream>>>(gB, wdw4, actB);
    gemm_bf16<1><<<dim3(128, 5), blk, 0, stream>>>(actB, wb5, gB, CKp, CKp);
    dw3x3_nhwc<2><<<dim3(HWp / 4, 9), blk, 0, stream>>>(gB, wdw6, xbB);  // wiener
    g9inv<<<dim3(HWp / 4), blk, 0, stream>>>(xbB, bigB, inv_w1, actB);
    gemm_bf16<0><<<dim3(128, 1), blk, 0, stream>>>(actB, wbi2, midNHWC, 64, 64);
    t64<<<dim3(HWp / 64), blk, 0, stream>>>(midNHWC, mid + (size_t)b * 64 * HWp);
  }

  // ---- dec ConvNeXt (full batch); pw1 tmp in bigA ----
  dwconv7_lds<<<dim3(Hp / 2, Bp * Cp), blk, 0, stream>>>(mid, dec_dw, t0);
  conv1x1<1, false, false><<<dim3(HWp / 128, 2, Bp), blk, 0, stream>>>(
      t0, dec_pw1, nullptr, nullptr, bigA, 64, 128);
  conv1x1<0, true, false><<<dim3(HWp / 128, 1, Bp), blk, 0, stream>>>(
      bigA, dec_pw2, nullptr, mid, outp, 128, 64);
}

// Round 6
// 1323.094 us; speedup vs baseline: 3.0307x; 1.3237x over previous
//
#include <hip/hip_runtime.h>
#include <math.h>

#define HWp 16384
#define Wp 128
#define Hp 128
#define Bp 4
#define Cp 64
#define CKp 576

typedef unsigned int u32;
typedef unsigned short ushortt;
typedef __attribute__((ext_vector_type(8))) short short8;
typedef __attribute__((ext_vector_type(4))) float float4v;

__device__ __forceinline__ ushortt f2b(float f) {
  union { float f; u32 u; } x; x.f = f;
  u32 r = x.u + 0x7fff + ((x.u >> 16) & 1);
  return (ushortt)(r >> 16);
}
__device__ __forceinline__ float b2f(ushortt h) {
  union { u32 u; float f; } x; x.u = ((u32)h) << 16; return x.f;
}
__device__ __forceinline__ void gll(const ushortt* g, ushortt* l) {
  __builtin_amdgcn_global_load_lds(
      (const __attribute__((address_space(1))) u32*)g,
      (__attribute__((address_space(3))) u32*)l, 16, 0, 0);
}

// ---------------- depthwise 7x7, pad 3, LDS-tiled (ConvNeXt dw, NCHW) ----------------
__global__ __launch_bounds__(256)
void dwconv7_lds(const float* __restrict__ in, const float* __restrict__ w,
                 float* __restrict__ out) {
  int bc = blockIdx.y;
  int tid = threadIdx.x;
  int y0 = blockIdx.x * 2;
  __shared__ float ws[49];
  __shared__ float tile[8][136];
  if (tid < 49) ws[tid] = w[(bc & 63) * 49 + tid];
  if (tid < 48) {
    int r = tid / 6, cc = tid % 6;
    tile[r][cc < 3 ? cc : 128 + cc] = 0.f;
  }
  const float* ip = in + (size_t)bc * HWp;
  #pragma unroll
  for (int i = 0; i < 4; i++) {
    int idx = tid + 256 * i;
    int r = idx >> 7, xx = idx & 127;
    int yy = y0 - 3 + r;
    tile[r][xx + 3] = (yy >= 0 && yy < Hp) ? ip[yy * Wp + xx] : 0.f;
  }
  __syncthreads();
  int ty = tid >> 7, x = tid & 127;
  float acc = 0.f;
  #pragma unroll
  for (int dy = 0; dy < 7; dy++)
    #pragma unroll
    for (int dx = 0; dx < 7; dx++)
      acc += tile[ty + dy][x + dx] * ws[dy * 7 + dx];
  out[(size_t)bc * HWp + (y0 + ty) * Wp + x] = acc;
}

// ---------------- fp32 1x1 conv (enc/dec, NCHW) ----------------
template<int ACT, bool RESID, bool BIAS>
__global__ __launch_bounds__(256)
void conv1x1(const float* __restrict__ in, const float* __restrict__ wgt,
             const float* __restrict__ bias, const float* __restrict__ resid,
             float* __restrict__ out, int Cin, int Cout) {
  int b   = blockIdx.z;
  int p0  = blockIdx.x * 128;
  int co0 = blockIdx.y * 64;
  __shared__ float Wt[16][68];
  __shared__ float It[16][128];
  float acc[4][8];
  #pragma unroll
  for (int i = 0; i < 4; i++)
    #pragma unroll
    for (int j = 0; j < 8; j++) acc[i][j] = 0.f;

  const float* ip = in + (size_t)b * Cin * HWp + p0;
  int t = threadIdx.x;
  int wco = t >> 4, wkk = t & 15;
  int ipx = t & 127, ikr = t >> 7;
  int ty4 = (t >> 4) * 4, txa = (t & 15) * 4;

  for (int k0 = 0; k0 < Cin; k0 += 16) {
    #pragma unroll
    for (int i = 0; i < 4; i++)
      Wt[wkk][wco + 16 * i] = wgt[(size_t)(co0 + wco + 16 * i) * Cin + k0 + wkk];
    #pragma unroll
    for (int i = 0; i < 8; i++)
      It[ikr + 2 * i][ipx] = ip[(size_t)(k0 + ikr + 2 * i) * HWp + ipx];
    __syncthreads();
    #pragma unroll
    for (int kk = 0; kk < 16; kk++) {
      float4 wv = *(const float4*)&Wt[kk][ty4];
      float4 ia = *(const float4*)&It[kk][txa];
      float4 ib = *(const float4*)&It[kk][txa + 64];
      float iv[8] = {ia.x, ia.y, ia.z, ia.w, ib.x, ib.y, ib.z, ib.w};
      #pragma unroll
      for (int j = 0; j < 8; j++) {
        acc[0][j] += wv.x * iv[j];
        acc[1][j] += wv.y * iv[j];
        acc[2][j] += wv.z * iv[j];
        acc[3][j] += wv.w * iv[j];
      }
    }
    __syncthreads();
  }

  #pragma unroll
  for (int i = 0; i < 4; i++) {
    int co = co0 + ty4 + i;
    float bv = BIAS ? bias[co] : 0.f;
    #pragma unroll
    for (int hh = 0; hh < 2; hh++) {
      size_t base = ((size_t)b * Cout + co) * HWp + p0 + txa + hh * 64;
      float4 r;
      r.x = acc[i][hh * 4 + 0] + bv;
      r.y = acc[i][hh * 4 + 1] + bv;
      r.z = acc[i][hh * 4 + 2] + bv;
      r.w = acc[i][hh * 4 + 3] + bv;
      if (ACT == 1) {
        r.x = fmaxf(r.x, 0.f); r.y = fmaxf(r.y, 0.f);
        r.z = fmaxf(r.z, 0.f); r.w = fmaxf(r.w, 0.f);
      } else if (ACT == 2) {
        r.x = r.x > 0.f ? r.x : 0.1f * r.x;
        r.y = r.y > 0.f ? r.y : 0.1f * r.y;
        r.z = r.z > 0.f ? r.z : 0.1f * r.z;
        r.w = r.w > 0.f ? r.w : 0.1f * r.w;
      }
      if (RESID) {
        float4 rr = *(const float4*)&resid[base];
        r.x += rr.x; r.y += rr.y; r.z += rr.z; r.w += rr.w;
      }
      *(float4*)&out[base] = r;
    }
  }
}

// ---------------- plain-bf16 MFMA conv (1x1 or 3x3 pad1), NHWC ----------------
// in/out NHWC bf16 [px][64]. w: [TAPS][64 co][64 ci] bf16. bias + leaky 0.1.
// grid (HWp/64, Bp); block 256 (4 waves); wave 32px x 32co.
template<int TAPS>
__global__ __launch_bounds__(256)
void conv_bf(const ushortt* __restrict__ in, const ushortt* __restrict__ wt,
             const float* __restrict__ bias, ushortt* __restrict__ out) {
  int tid = threadIdx.x;
  int wid = tid >> 6, lane = tid & 63;
  int q = lane >> 4, m = lane & 15;
  int bx = blockIdx.x, b = blockIdx.y;
  int y = bx >> 1;
  int c0 = ((bx & 1) << 6) + ((wid & 1) << 5);
  int coW = (wid >> 1) << 5;
  size_t ibase = (size_t)b * HWp;

  float4v acc[2][2];
  #pragma unroll
  for (int i = 0; i < 2; i++)
    #pragma unroll
    for (int j = 0; j < 2; j++) acc[i][j] = (float4v){0.f, 0.f, 0.f, 0.f};
  short8 zz = {0, 0, 0, 0, 0, 0, 0, 0};

  #pragma unroll
  for (int k = 0; k < TAPS; k++) {
    int dy = (TAPS == 9) ? (k / 3 - 1) : 0;
    int dx = (TAPS == 9) ? (k % 3 - 1) : 0;
    int yy = y + dy;
    if (TAPS == 9 && (yy < 0 || yy >= Hp)) continue;
    #pragma unroll
    for (int ch = 0; ch < 2; ch++) {
      int ci0 = ch * 32 + q * 8;
      short8 bfr[2], afr[2];
      #pragma unroll
      for (int j = 0; j < 2; j++)
        bfr[j] = *(const short8*)&wt[(size_t)(k * 64 + coW + j * 16 + m) * 64 + ci0];
      #pragma unroll
      for (int i = 0; i < 2; i++) {
        int col = c0 + i * 16 + m + dx;
        bool vld = (TAPS == 1) || ((unsigned)col < (unsigned)Wp);
        int colc = min(max(col, 0), Wp - 1);
        short8 h = *(const short8*)&in[(ibase + (size_t)yy * Wp + colc) * 64 + ci0];
        afr[i] = vld ? h : zz;
      }
      #pragma unroll
      for (int i = 0; i < 2; i++)
        #pragma unroll
        for (int j = 0; j < 2; j++)
          acc[i][j] = __builtin_amdgcn_mfma_f32_16x16x32_bf16(afr[i], bfr[j], acc[i][j], 0, 0, 0);
    }
  }

  #pragma unroll
  for (int j = 0; j < 2; j++) {
    int co = coW + j * 16 + m;
    float bv = bias[co];
    #pragma unroll
    for (int i = 0; i < 2; i++) {
      #pragma unroll
      for (int r = 0; r < 4; r++) {
        size_t px = ibase + (size_t)y * Wp + c0 + i * 16 + q * 4 + r;
        float v = acc[i][j][r] + bv;
        v = v > 0.f ? v : 0.1f * v;
        out[px * 64 + co] = f2b(v);
      }
    }
  }
}

// ---------------- NCHW fp32 -> NHWC bf16 (full batch) ----------------
__global__ __launch_bounds__(256)
void t64b(const float* __restrict__ in, ushortt* __restrict__ out) {
  __shared__ float tl[64 * 65];
  int tid = threadIdx.x;
  int b = blockIdx.y;
  int px0 = blockIdx.x * 64;
  int lpx = tid & 63, c4 = tid >> 6;
  const float* ip = in + (size_t)b * 64 * HWp;
  #pragma unroll
  for (int i = 0; i < 16; i++) {
    int c = c4 + 4 * i;
    tl[lpx * 65 + c] = ip[(size_t)c * HWp + px0 + lpx];
  }
  __syncthreads();
  int ci = tid & 63, pr = tid >> 6;
  #pragma unroll
  for (int i = 0; i < 16; i++) {
    int r = pr + 4 * i;
    out[((size_t)b * HWp + px0 + r) * 64 + ci] = f2b(tl[r * 65 + ci]);
  }
}

// ---------------- conv weight repack: (co,ci,taps) -> [k][co][ci] bf16 ----------------
__global__ __launch_bounds__(256)
void repw(const float* __restrict__ in, ushortt* __restrict__ out, int taps) {
  int idx = blockIdx.x * 256 + threadIdx.x;
  if (idx >= taps * 4096) return;
  int k = idx >> 12, r = idx & 4095;
  int co = r >> 6, ci = r & 63;
  out[idx] = f2b(in[(size_t)(co * 64 + ci) * taps + k]);
}

// ---------------- off_w6 (NHWC bf16 in) -> NCHW offsets, 8*tanh ----------------
__global__ __launch_bounds__(256)
void off6_nhwc(const ushortt* __restrict__ hi, const float* __restrict__ wgt,
               const float* __restrict__ bias, float* __restrict__ out) {
  __shared__ float Wl[18 * 64];
  for (int i = threadIdx.x; i < 18 * 64; i += 256) Wl[i] = wgt[i];
  __syncthreads();
  int px = blockIdx.x * 256 + threadIdx.x;
  int b = px >> 14, pim = px & 16383;
  float acc[18];
  #pragma unroll
  for (int j = 0; j < 18; j++) acc[j] = 0.f;
  const uint4* ph = (const uint4*)(hi + (size_t)px * 64);
  for (int g = 0; g < 8; g++) {
    uint4 H = ph[g];
    u32 hw[4] = {H.x, H.y, H.z, H.w};
    #pragma unroll
    for (int t = 0; t < 4; t++) {
      float v0 = b2f((ushortt)(hw[t] & 0xffff));
      float v1 = b2f((ushortt)(hw[t] >> 16));
      int ci = g * 8 + t * 2;
      #pragma unroll
      for (int j = 0; j < 18; j++)
        acc[j] += Wl[j * 64 + ci] * v0 + Wl[j * 64 + ci + 1] * v1;
    }
  }
  #pragma unroll
  for (int j = 0; j < 18; j++)
    out[((size_t)b * 18 + j) * HWp + pim] = 8.f * tanhf(acc[j] + bias[j]);
}

// ---------------- weight repacks (permuted channel order pi(c*9+k)=64k+c) ----------------
__global__ __launch_bounds__(256)
void rep576(const float* __restrict__ in, ushortt* __restrict__ out) {
  int idx = blockIdx.x * 256 + threadIdx.x;
  if (idx >= 640 * 576) return;
  int cop = idx / 576, cip = idx % 576;
  ushortt v = 0;
  if (cop < 576) {
    int co = (cop & 63) * 9 + (cop >> 6);
    int ci = (cip & 63) * 9 + (cip >> 6);
    v = f2b(in[(size_t)co * 576 + ci]);
  }
  out[idx] = v;
}
__global__ __launch_bounds__(256)
void repinv2(const float* __restrict__ in, ushortt* __restrict__ out) {
  int idx = blockIdx.x * 256 + threadIdx.x;
  if (idx >= 128 * 576) return;
  int co = idx / 576, cip = idx % 576;
  ushortt v = 0;
  if (co < 64) {
    int ci = (cip & 63) * 9 + (cip >> 6);
    v = f2b(in[(size_t)co * 576 + ci]);
  }
  out[idx] = v;
}
__global__ __launch_bounds__(256)
void repdw(const float* __restrict__ in, float* __restrict__ out) {
  int idx = blockIdx.x * 256 + threadIdx.x;
  if (idx >= 5184) return;
  int chp = idx / 9, k = idx % 9;
  int ch = (chp & 63) * 9 + (chp >> 6);
  out[idx] = in[ch * 9 + k];
}

// ---------------- fused deform + dct (per batch) ----------------
// wave = 64 ch of one px; block = 4 px. xn NHWC bf16; offs NCHW fp32 (18ch);
// xb NHWC bf16 [px][576]; dctb NHWC bf16 [px][576].
__global__ __launch_bounds__(256)
void deform_dct(const ushortt* __restrict__ xn, const float* __restrict__ offs,
                const float* __restrict__ w9, ushortt* __restrict__ xb,
                ushortt* __restrict__ dctb) {
  __shared__ float Wl[5184];
  for (int i = threadIdx.x; i < 5184; i += 256) Wl[i] = w9[i];
  __syncthreads();
  int wid = threadIdx.x >> 6, lane = threadIdx.x & 63;
  int p = blockIdx.x * 4 + wid;
  int yi = p >> 7, xi = p & 127;
  float v[9];
  #pragma unroll
  for (int k = 0; k < 9; k++) {
    float dy = offs[(size_t)(2 * k) * HWp + p];
    float dx = offs[(size_t)(2 * k + 1) * HWp + p];
    float py = (float)yi + (float)(k / 3 - 1) + dy;
    float px = (float)xi + (float)(k % 3 - 1) + dx;
    float y0f = floorf(py), x0f = floorf(px);
    float wy1 = py - y0f, wy0 = 1.f - wy1;
    float wx1 = px - x0f, wx0 = 1.f - wx1;
    int y0 = (int)y0f, x0 = (int)x0f;
    bool vy0 = (y0 >= 0 && y0 < Hp), vy1 = (y0 + 1 >= 0 && y0 + 1 < Hp);
    bool vx0 = (x0 >= 0 && x0 < Wp), vx1 = (x0 + 1 >= 0 && x0 + 1 < Wp);
    int yc0 = min(max(y0, 0), Hp - 1), yc1 = min(max(y0 + 1, 0), Hp - 1);
    int xc0 = min(max(x0, 0), Wp - 1), xc1 = min(max(x0 + 1, 0), Wp - 1);
    float w00 = wy0 * wx0 * ((vy0 && vx0) ? 1.f : 0.f);
    float w01 = wy0 * wx1 * ((vy0 && vx1) ? 1.f : 0.f);
    float w10 = wy1 * wx0 * ((vy1 && vx0) ? 1.f : 0.f);
    float w11 = wy1 * wx1 * ((vy1 && vx1) ? 1.f : 0.f);
    float v00 = b2f(xn[(size_t)(yc0 * Wp + xc0) * 64 + lane]);
    float v01 = b2f(xn[(size_t)(yc0 * Wp + xc1) * 64 + lane]);
    float v10 = b2f(xn[(size_t)(yc1 * Wp + xc0) * 64 + lane]);
    float v11 = b2f(xn[(size_t)(yc1 * Wp + xc1) * 64 + lane]);
    v[k] = v00 * w00 + v01 * w01 + v10 * w10 + v11 * w11;
    xb[(size_t)p * 576 + 64 * k + lane] = f2b(v[k]);
  }
  const float* wc = &Wl[lane * 81];
  #pragma unroll
  for (int j = 0; j < 9; j++) {
    float a = 0.f;
    #pragma unroll
    for (int kk = 0; kk < 9; kk++) a += wc[j * 9 + kk] * v[kk];
    dctb[(size_t)p * 576 + 64 * j + lane] = f2b(a);
  }
}

// ---------------- MFMA bf16 GEMM; OUT: 0 fp32 NHWC, 1 bf16 NHWC, 2 fp32 NCHW ----------------
template<int OUT>
__global__ __launch_bounds__(256)
void gemm_bf16(const ushortt* __restrict__ X, const ushortt* __restrict__ Wb,
               void* __restrict__ outv, int outStride, int coMax) {
  __shared__ ushortt Xs[128 * 32];
  __shared__ ushortt Wsh[128 * 32];
  int tid = threadIdx.x;
  int px0 = blockIdx.x * 128, co0 = blockIdx.y * 128;
  int row = tid >> 2, ch4 = tid & 3;
  const ushortt* gx = X + (size_t)(px0 + row) * 576 + ch4 * 8;
  const ushortt* gw = Wb + (size_t)(co0 + row) * 576 + ch4 * 8;
  int wid = tid >> 6, lane = tid & 63;
  int q = lane >> 4, m = lane & 15;
  int pxw = (wid & 1) * 64, cow = (wid >> 1) * 64;
  float4v acc[4][4];
  #pragma unroll
  for (int i = 0; i < 4; i++)
    #pragma unroll
    for (int j = 0; j < 4; j++) acc[i][j] = (float4v){0.f, 0.f, 0.f, 0.f};

  for (int k0 = 0; k0 < 576; k0 += 32) {
    __syncthreads();
    gll(gx + k0,             &Xs[tid * 8]);
    gll(gx + k0 + 64 * 576,  &Xs[2048 + tid * 8]);
    gll(gw + k0,             &Wsh[tid * 8]);
    gll(gw + k0 + 64 * 576,  &Wsh[2048 + tid * 8]);
    __syncthreads();
    short8 a[4], b[4];
    #pragma unroll
    for (int i = 0; i < 4; i++)
      a[i] = *(const short8*)&Xs[(pxw + i * 16 + m) * 32 + q * 8];
    #pragma unroll
    for (int j = 0; j < 4; j++)
      b[j] = *(const short8*)&Wsh[(cow + j * 16 + m) * 32 + q * 8];
    #pragma unroll
    for (int i = 0; i < 4; i++)
      #pragma unroll
      for (int j = 0; j < 4; j++)
        acc[i][j] = __builtin_amdgcn_mfma_f32_16x16x32_bf16(a[i], b[j], acc[i][j], 0, 0, 0);
  }

  #pragma unroll
  for (int j = 0; j < 4; j++) {
    int co = co0 + cow + j * 16 + m;
    if (co >= coMax) continue;
    #pragma unroll
    for (int i = 0; i < 4; i++) {
      int pxb = px0 + pxw + i * 16 + q * 4;
      if (OUT == 2) {
        float4 r;
        r.x = acc[i][j][0]; r.y = acc[i][j][1];
        r.z = acc[i][j][2]; r.w = acc[i][j][3];
        *(float4*)&((float*)outv)[(size_t)co * HWp + pxb] = r;
      } else {
        #pragma unroll
        for (int r = 0; r < 4; r++) {
          if (OUT == 0)
            ((float*)outv)[(size_t)(pxb + r) * outStride + co] = acc[i][j][r];
          else
            ((ushortt*)outv)[(size_t)(pxb + r) * outStride + co] = f2b(acc[i][j][r]);
        }
      }
    }
  }
}

// ---------------- depthwise 3x3 NHWC bf16, 2 ch/thread; ACT 1 relu / 2 sigmoid ----------------
template<int ACT>
__global__ __launch_bounds__(256)
void dw3x3_nhwc(const ushortt* __restrict__ in, const float* __restrict__ wdw,
                ushortt* __restrict__ out) {
  int l = threadIdx.x & 31, pxl = threadIdx.x >> 5;
  int ch = blockIdx.y * 64 + l * 2;
  int px = blockIdx.x * 8 + pxl;
  int y = px >> 7, xx = px & 127;
  float w0[9], w1[9];
  #pragma unroll
  for (int k = 0; k < 9; k++) {
    w0[k] = wdw[ch * 9 + k];
    w1[k] = wdw[(ch + 1) * 9 + k];
  }
  float a0 = 0.f, a1 = 0.f;
  #pragma unroll
  for (int k = 0; k < 9; k++) {
    int yy = y + k / 3 - 1, xw = xx + k % 3 - 1;
    if (yy >= 0 && yy < Hp && xw >= 0 && xw < Wp) {
      u32 t = *(const u32*)&in[(size_t)(yy * Wp + xw) * 576 + ch];
      a0 += b2f((ushortt)(t & 0xffff)) * w0[k];
      a1 += b2f((ushortt)(t >> 16)) * w1[k];
    }
  }
  float r0, r1;
  if (ACT == 1) { r0 = fmaxf(a0, 0.f); r1 = fmaxf(a1, 0.f); }
  else { r0 = 1.f / (1.f + __expf(-a0)); r1 = 1.f / (1.f + __expf(-a1)); }
  u32 o = (u32)f2b(r0) | (((u32)f2b(r1)) << 16);
  *(u32*)&out[(size_t)px * 576 + ch] = o;
}

// ---------------- group 9->9 inv1 with fused wiener*dct (NHWC, all bf16 in) ----------------
__global__ __launch_bounds__(256)
void g9inv(const ushortt* __restrict__ wien, const ushortt* __restrict__ dct,
           const float* __restrict__ w9, ushortt* __restrict__ outb) {
  __shared__ float Wl[5184];
  for (int i = threadIdx.x; i < 5184; i += 256) Wl[i] = w9[i];
  __syncthreads();
  int c = threadIdx.x & 63, pxl = threadIdx.x >> 6;
  size_t px = (size_t)blockIdx.x * 4 + pxl;
  float v[9];
  #pragma unroll
  for (int kk = 0; kk < 9; kk++)
    v[kk] = b2f(wien[px * 576 + 64 * kk + c]) * b2f(dct[px * 576 + 64 * kk + c]);
  const float* wc = &Wl[c * 81];
  #pragma unroll
  for (int j = 0; j < 9; j++) {
    float a = 0.f;
    #pragma unroll
    for (int kk = 0; kk < 9; kk++) a += wc[j * 9 + kk] * v[kk];
    outb[px * 576 + 64 * j + c] = f2b(a);
  }
}

// ---------------- launch ----------------
extern "C" void kernel_launch(void* const* d_in, const int* in_sizes, int n_in,
                              void* d_out, int out_size, void* d_ws, size_t ws_size,
                              hipStream_t stream) {
  const float* x       = (const float*)d_in[0];
  const float* enc_dw  = (const float*)d_in[1];
  const float* enc_pw1 = (const float*)d_in[2];
  const float* enc_pw2 = (const float*)d_in[3];
  const float* dec_dw  = (const float*)d_in[4];
  const float* dec_pw1 = (const float*)d_in[5];
  const float* dec_pw2 = (const float*)d_in[6];
  const float* off_w1  = (const float*)d_in[7];
  const float* off_b1  = (const float*)d_in[8];
  const float* off_w2  = (const float*)d_in[9];
  const float* off_b2  = (const float*)d_in[10];
  const float* off_w3  = (const float*)d_in[11];
  const float* off_b3  = (const float*)d_in[12];
  const float* off_w4  = (const float*)d_in[13];
  const float* off_b4  = (const float*)d_in[14];
  const float* off_w5  = (const float*)d_in[15];
  const float* off_b5  = (const float*)d_in[16];
  const float* off_w6  = (const float*)d_in[17];
  const float* off_b6  = (const float*)d_in[18];
  const float* dct_w   = (const float*)d_in[19];
  const float* wie_w1  = (const float*)d_in[20];
  const float* wie_w2  = (const float*)d_in[21];
  const float* wie_w3  = (const float*)d_in[22];
  const float* wie_w4  = (const float*)d_in[23];
  const float* wie_w5  = (const float*)d_in[24];
  const float* wie_w6  = (const float*)d_in[25];
  const float* inv_w1  = (const float*)d_in[26];
  const float* inv_w2  = (const float*)d_in[27];
  float* outp = (float*)d_out;

  const size_t NP = (size_t)Bp * HWp;
  const size_t REQ_FLOATS = NP * 64 + NP * 64 + NP * 128 +
                            2 * (size_t)HWp * CKp + (size_t)HWp * CKp;
  if (ws_size < REQ_FLOATS * sizeof(float)) return;

  float* ws  = (float*)d_ws;
  float* x1  = ws;                       // enc out; later: mid (dec input NCHW)
  float* t0  = x1 + NP * 64;             // dw7 tmp / offs + weights / dec dw7 tmp
  float* t1  = t0 + NP * 64;             // xnAll + offset ping-pong
  float* bigA = t1 + NP * 128;
  float* bigB = bigA + (size_t)HWp * CKp;
  ushortt* xbB   = (ushortt*)(bigB + (size_t)HWp * CKp);
  ushortt* actB  = xbB + (size_t)HWp * CKp;
  ushortt* gB    = (ushortt*)bigA;       // bf16 gemm out (per batch)
  ushortt* dctB  = (ushortt*)bigB;       // bf16 dct (per batch)

  // weight region in t0 after the offset maps
  float* wreg = t0 + NP * 18;
  ushortt* wb1  = (ushortt*)wreg;
  ushortt* wb3  = wb1 + 640 * 576;
  ushortt* wb5  = wb3 + 640 * 576;
  ushortt* wbi2 = wb5 + 640 * 576;
  float* wdw2 = (float*)(wbi2 + 128 * 576);
  float* wdw4 = wdw2 + 5184;
  float* wdw6 = wdw4 + 5184;
  ushortt* wc1 = (ushortt*)(wdw6 + 5184);   // [1][64][64]
  ushortt* wc2 = wc1 + 4096;                // [9][64][64]
  ushortt* wc3 = wc2 + 36864;
  ushortt* wc4 = wc3 + 36864;
  ushortt* wc5 = wc4 + 36864;

  // t1 region: xnAll (NP*64 ush) persists through middle; oA/oB ping-pong
  ushortt* xnAll = (ushortt*)t1;
  ushortt* oA = xnAll + NP * 64;
  ushortt* oB = oA + NP * 64;

  float* offs = t0;
  float* mid  = x1;   // dec-convnext input NCHW (x1 dead after t64b)

  dim3 blk(256);

  // ---- enc ConvNeXt (full batch); pw1 tmp in bigA ----
  dwconv7_lds<<<dim3(Hp / 2, Bp * Cp), blk, 0, stream>>>(x, enc_dw, t0);
  conv1x1<1, false, false><<<dim3(HWp / 128, 2, Bp), blk, 0, stream>>>(
      t0, enc_pw1, nullptr, nullptr, bigA, 64, 128);
  conv1x1<0, true, false><<<dim3(HWp / 128, 1, Bp), blk, 0, stream>>>(
      bigA, enc_pw2, nullptr, x, x1, 128, 64);

  // ---- weight repacks ----
  rep576<<<dim3((640 * 576 + 255) / 256), blk, 0, stream>>>(wie_w1, wb1);
  rep576<<<dim3((640 * 576 + 255) / 256), blk, 0, stream>>>(wie_w3, wb3);
  rep576<<<dim3((640 * 576 + 255) / 256), blk, 0, stream>>>(wie_w5, wb5);
  repinv2<<<dim3((128 * 576 + 255) / 256), blk, 0, stream>>>(inv_w2, wbi2);
  repdw<<<dim3((5184 + 255) / 256), blk, 0, stream>>>(wie_w2, wdw2);
  repdw<<<dim3((5184 + 255) / 256), blk, 0, stream>>>(wie_w4, wdw4);
  repdw<<<dim3((5184 + 255) / 256), blk, 0, stream>>>(wie_w6, wdw6);
  repw<<<dim3((4096 + 255) / 256), blk, 0, stream>>>(off_w1, wc1, 1);
  repw<<<dim3((36864 + 255) / 256), blk, 0, stream>>>(off_w2, wc2, 9);
  repw<<<dim3((36864 + 255) / 256), blk, 0, stream>>>(off_w3, wc3, 9);
  repw<<<dim3((36864 + 255) / 256), blk, 0, stream>>>(off_w4, wc4, 9);
  repw<<<dim3((36864 + 255) / 256), blk, 0, stream>>>(off_w5, wc5, 9);

  // ---- offset CNN (full batch, plain bf16 MFMA, NHWC) ----
  t64b<<<dim3(HWp / 64, Bp), blk, 0, stream>>>(x1, xnAll);
  conv_bf<1><<<dim3(HWp / 64, Bp), blk, 0, stream>>>(xnAll, wc1, off_b1, oA);
  conv_bf<9><<<dim3(HWp / 64, Bp), blk, 0, stream>>>(oA, wc2, off_b2, oB);
  conv_bf<9><<<dim3(HWp / 64, Bp), blk, 0, stream>>>(oB, wc3, off_b3, oA);
  conv_bf<9><<<dim3(HWp / 64, Bp), blk, 0, stream>>>(oA, wc4, off_b4, oB);
  conv_bf<9><<<dim3(HWp / 64, Bp), blk, 0, stream>>>(oB, wc5, off_b5, oA);
  off6_nhwc<<<dim3(NP / 256), blk, 0, stream>>>(oA, off_w6, off_b6, offs);

  // ---- 576-channel middle (NHWC bf16, per batch) ----
  for (int b = 0; b < Bp; b++) {
    const ushortt* xnb = xnAll + (size_t)b * HWp * 64;
    const float* offb = offs + (size_t)b * 18 * HWp;

    deform_dct<<<dim3(HWp / 4), blk, 0, stream>>>(xnb, offb, dct_w, xbB, dctB);
    gemm_bf16<1><<<dim3(128, 5), blk, 0, stream>>>(xbB, wb1, gB, CKp, CKp);
    dw3x3_nhwc<1><<<dim3(HWp / 8, 9), blk, 0, stream>>>(gB, wdw2, actB);
    gemm_bf16<1><<<dim3(128, 5), blk, 0, stream>>>(actB, wb3, gB, CKp, CKp);
    dw3x3_nhwc<1><<<dim3(HWp / 8, 9), blk, 0, stream>>>(gB, wdw4, actB);
    gemm_bf16<1><<<dim3(128, 5), blk, 0, stream>>>(actB, wb5, gB, CKp, CKp);
    dw3x3_nhwc<2><<<dim3(HWp / 8, 9), blk, 0, stream>>>(gB, wdw6, xbB);  // wiener
    g9inv<<<dim3(HWp / 4), blk, 0, stream>>>(xbB, dctB, inv_w1, actB);
    gemm_bf16<2><<<dim3(128, 1), blk, 0, stream>>>(
        actB, wbi2, mid + (size_t)b * 64 * HWp, 64, 64);
  }

  // ---- dec ConvNeXt (full batch); pw1 tmp in bigA ----
  dwconv7_lds<<<dim3(Hp / 2, Bp * Cp), blk, 0, stream>>>(mid, dec_dw, t0);
  conv1x1<1, false, false><<<dim3(HWp / 128, 2, Bp), blk, 0, stream>>>(
      t0, dec_pw1, nullptr, nullptr, bigA, 64, 128);
  conv1x1<0, true, false><<<dim3(HWp / 128, 1, Bp), blk, 0, stream>>>(
      bigA, dec_pw2, nullptr, mid, outp, 128, 64);
}

// Round 7
// 1311.617 us; speedup vs baseline: 3.0572x; 1.0088x over previous
//
#include <hip/hip_runtime.h>
#include <math.h>

#define HWp 16384
#define Wp 128
#define Hp 128
#define Bp 4
#define Cp 64
#define CKp 576

typedef unsigned int u32;
typedef unsigned short ushortt;
typedef __attribute__((ext_vector_type(8))) short short8;
typedef __attribute__((ext_vector_type(4))) float float4v;

__device__ __forceinline__ ushortt f2b(float f) {
  union { float f; u32 u; } x; x.f = f;
  u32 r = x.u + 0x7fff + ((x.u >> 16) & 1);
  return (ushortt)(r >> 16);
}
__device__ __forceinline__ float b2f(ushortt h) {
  union { u32 u; float f; } x; x.u = ((u32)h) << 16; return x.f;
}
__device__ __forceinline__ void gll(const ushortt* g, ushortt* l) {
  __builtin_amdgcn_global_load_lds(
      (const __attribute__((address_space(1))) u32*)g,
      (__attribute__((address_space(3))) u32*)l, 16, 0, 0);
}

// ---------------- depthwise 7x7, pad 3, LDS-tiled (ConvNeXt dw, NCHW) ----------------
__global__ __launch_bounds__(256)
void dwconv7_lds(const float* __restrict__ in, const float* __restrict__ w,
                 float* __restrict__ out) {
  int bc = blockIdx.y;
  int tid = threadIdx.x;
  int y0 = blockIdx.x * 2;
  __shared__ float ws[49];
  __shared__ float tile[8][136];
  if (tid < 49) ws[tid] = w[(bc & 63) * 49 + tid];
  if (tid < 48) {
    int r = tid / 6, cc = tid % 6;
    tile[r][cc < 3 ? cc : 128 + cc] = 0.f;
  }
  const float* ip = in + (size_t)bc * HWp;
  #pragma unroll
  for (int i = 0; i < 4; i++) {
    int idx = tid + 256 * i;
    int r = idx >> 7, xx = idx & 127;
    int yy = y0 - 3 + r;
    tile[r][xx + 3] = (yy >= 0 && yy < Hp) ? ip[yy * Wp + xx] : 0.f;
  }
  __syncthreads();
  int ty = tid >> 7, x = tid & 127;
  float acc = 0.f;
  #pragma unroll
  for (int dy = 0; dy < 7; dy++)
    #pragma unroll
    for (int dx = 0; dx < 7; dx++)
      acc += tile[ty + dy][x + dx] * ws[dy * 7 + dx];
  out[(size_t)bc * HWp + (y0 + ty) * Wp + x] = acc;
}

// ---------------- fp32 1x1 conv (enc/dec, NCHW) ----------------
template<int ACT, bool RESID, bool BIAS>
__global__ __launch_bounds__(256)
void conv1x1(const float* __restrict__ in, const float* __restrict__ wgt,
             const float* __restrict__ bias, const float* __restrict__ resid,
             float* __restrict__ out, int Cin, int Cout) {
  int b   = blockIdx.z;
  int p0  = blockIdx.x * 128;
  int co0 = blockIdx.y * 64;
  __shared__ float Wt[16][68];
  __shared__ float It[16][128];
  float acc[4][8];
  #pragma unroll
  for (int i = 0; i < 4; i++)
    #pragma unroll
    for (int j = 0; j < 8; j++) acc[i][j] = 0.f;

  const float* ip = in + (size_t)b * Cin * HWp + p0;
  int t = threadIdx.x;
  int wco = t >> 4, wkk = t & 15;
  int ipx = t & 127, ikr = t >> 7;
  int ty4 = (t >> 4) * 4, txa = (t & 15) * 4;

  for (int k0 = 0; k0 < Cin; k0 += 16) {
    #pragma unroll
    for (int i = 0; i < 4; i++)
      Wt[wkk][wco + 16 * i] = wgt[(size_t)(co0 + wco + 16 * i) * Cin + k0 + wkk];
    #pragma unroll
    for (int i = 0; i < 8; i++)
      It[ikr + 2 * i][ipx] = ip[(size_t)(k0 + ikr + 2 * i) * HWp + ipx];
    __syncthreads();
    #pragma unroll
    for (int kk = 0; kk < 16; kk++) {
      float4 wv = *(const float4*)&Wt[kk][ty4];
      float4 ia = *(const float4*)&It[kk][txa];
      float4 ib = *(const float4*)&It[kk][txa + 64];
      float iv[8] = {ia.x, ia.y, ia.z, ia.w, ib.x, ib.y, ib.z, ib.w};
      #pragma unroll
      for (int j = 0; j < 8; j++) {
        acc[0][j] += wv.x * iv[j];
        acc[1][j] += wv.y * iv[j];
        acc[2][j] += wv.z * iv[j];
        acc[3][j] += wv.w * iv[j];
      }
    }
    __syncthreads();
  }

  #pragma unroll
  for (int i = 0; i < 4; i++) {
    int co = co0 + ty4 + i;
    float bv = BIAS ? bias[co] : 0.f;
    #pragma unroll
    for (int hh = 0; hh < 2; hh++) {
      size_t base = ((size_t)b * Cout + co) * HWp + p0 + txa + hh * 64;
      float4 r;
      r.x = acc[i][hh * 4 + 0] + bv;
      r.y = acc[i][hh * 4 + 1] + bv;
      r.z = acc[i][hh * 4 + 2] + bv;
      r.w = acc[i][hh * 4 + 3] + bv;
      if (ACT == 1) {
        r.x = fmaxf(r.x, 0.f); r.y = fmaxf(r.y, 0.f);
        r.z = fmaxf(r.z, 0.f); r.w = fmaxf(r.w, 0.f);
      } else if (ACT == 2) {
        r.x = r.x > 0.f ? r.x : 0.1f * r.x;
        r.y = r.y > 0.f ? r.y : 0.1f * r.y;
        r.z = r.z > 0.f ? r.z : 0.1f * r.z;
        r.w = r.w > 0.f ? r.w : 0.1f * r.w;
      }
      if (RESID) {
        float4 rr = *(const float4*)&resid[base];
        r.x += rr.x; r.y += rr.y; r.z += rr.z; r.w += rr.w;
      }
      *(float4*)&out[base] = r;
    }
  }
}

// ---------------- plain-bf16 MFMA conv (1x1 or 3x3 pad1), NHWC ----------------
template<int TAPS>
__global__ __launch_bounds__(256)
void conv_bf(const ushortt* __restrict__ in, const ushortt* __restrict__ wt,
             const float* __restrict__ bias, ushortt* __restrict__ out) {
  int tid = threadIdx.x;
  int wid = tid >> 6, lane = tid & 63;
  int q = lane >> 4, m = lane & 15;
  int bx = blockIdx.x, b = blockIdx.y;
  int y = bx >> 1;
  int c0 = ((bx & 1) << 6) + ((wid & 1) << 5);
  int coW = (wid >> 1) << 5;
  size_t ibase = (size_t)b * HWp;

  float4v acc[2][2];
  #pragma unroll
  for (int i = 0; i < 2; i++)
    #pragma unroll
    for (int j = 0; j < 2; j++) acc[i][j] = (float4v){0.f, 0.f, 0.f, 0.f};
  short8 zz = {0, 0, 0, 0, 0, 0, 0, 0};

  #pragma unroll
  for (int k = 0; k < TAPS; k++) {
    int dy = (TAPS == 9) ? (k / 3 - 1) : 0;
    int dx = (TAPS == 9) ? (k % 3 - 1) : 0;
    int yy = y + dy;
    if (TAPS == 9 && (yy < 0 || yy >= Hp)) continue;
    #pragma unroll
    for (int ch = 0; ch < 2; ch++) {
      int ci0 = ch * 32 + q * 8;
      short8 bfr[2], afr[2];
      #pragma unroll
      for (int j = 0; j < 2; j++)
        bfr[j] = *(const short8*)&wt[(size_t)(k * 64 + coW + j * 16 + m) * 64 + ci0];
      #pragma unroll
      for (int i = 0; i < 2; i++) {
        int col = c0 + i * 16 + m + dx;
        bool vld = (TAPS == 1) || ((unsigned)col < (unsigned)Wp);
        int colc = min(max(col, 0), Wp - 1);
        short8 h = *(const short8*)&in[(ibase + (size_t)yy * Wp + colc) * 64 + ci0];
        afr[i] = vld ? h : zz;
      }
      #pragma unroll
      for (int i = 0; i < 2; i++)
        #pragma unroll
        for (int j = 0; j < 2; j++)
          acc[i][j] = __builtin_amdgcn_mfma_f32_16x16x32_bf16(afr[i], bfr[j], acc[i][j], 0, 0, 0);
    }
  }

  #pragma unroll
  for (int j = 0; j < 2; j++) {
    int co = coW + j * 16 + m;
    float bv = bias[co];
    #pragma unroll
    for (int i = 0; i < 2; i++) {
      #pragma unroll
      for (int r = 0; r < 4; r++) {
        size_t px = ibase + (size_t)y * Wp + c0 + i * 16 + q * 4 + r;
        float v = acc[i][j][r] + bv;
        v = v > 0.f ? v : 0.1f * v;
        out[px * 64 + co] = f2b(v);
      }
    }
  }
}

// ---------------- NCHW fp32 -> NHWC bf16 (full batch) ----------------
__global__ __launch_bounds__(256)
void t64b(const float* __restrict__ in, ushortt* __restrict__ out) {
  __shared__ float tl[64 * 65];
  int tid = threadIdx.x;
  int b = blockIdx.y;
  int px0 = blockIdx.x * 64;
  int lpx = tid & 63, c4 = tid >> 6;
  const float* ip = in + (size_t)b * 64 * HWp;
  #pragma unroll
  for (int i = 0; i < 16; i++) {
    int c = c4 + 4 * i;
    tl[lpx * 65 + c] = ip[(size_t)c * HWp + px0 + lpx];
  }
  __syncthreads();
  int ci = tid & 63, pr = tid >> 6;
  #pragma unroll
  for (int i = 0; i < 16; i++) {
    int r = pr + 4 * i;
    out[((size_t)b * HWp + px0 + r) * 64 + ci] = f2b(tl[r * 65 + ci]);
  }
}

// ---------------- merged weight repacks ----------------
// conv weight repack: (co,ci,taps) -> [k][co][ci] bf16 (single, taps=1)
__global__ __launch_bounds__(256)
void repw1(const float* __restrict__ in, ushortt* __restrict__ out) {
  int idx = blockIdx.x * 256 + threadIdx.x;
  if (idx >= 4096) return;
  int co = idx >> 6, ci = idx & 63;
  out[idx] = f2b(in[co * 64 + ci]);
}
// 4x 3x3 conv weights (off_w2..5) -> contiguous dst
__global__ __launch_bounds__(256)
void repw9x4(const float* __restrict__ s0, const float* __restrict__ s1,
             const float* __restrict__ s2, const float* __restrict__ s3,
             ushortt* __restrict__ dst) {
  int which = blockIdx.y;
  const float* in = which == 0 ? s0 : which == 1 ? s1 : which == 2 ? s2 : s3;
  int idx = blockIdx.x * 256 + threadIdx.x;
  if (idx >= 36864) return;
  int k = idx >> 12, r = idx & 4095;
  int co = r >> 6, ci = r & 63;
  dst[which * 36864 + idx] = f2b(in[(size_t)(co * 64 + ci) * 9 + k]);
}
// 3x 576x576 (wie_w1/3/5), permuted pi(c*9+k)=64k+c, padded to 640 rows
__global__ __launch_bounds__(256)
void rep576x3(const float* __restrict__ s0, const float* __restrict__ s1,
              const float* __restrict__ s2, ushortt* __restrict__ dst) {
  int which = blockIdx.y;
  const float* in = which == 0 ? s0 : which == 1 ? s1 : s2;
  int idx = blockIdx.x * 256 + threadIdx.x;
  if (idx >= 640 * 576) return;
  int cop = idx / 576, cip = idx % 576;
  ushortt v = 0;
  if (cop < 576) {
    int co = (cop & 63) * 9 + (cop >> 6);
    int ci = (cip & 63) * 9 + (cip >> 6);
    v = f2b(in[(size_t)co * 576 + ci]);
  }
  dst[(size_t)which * 640 * 576 + idx] = v;
}
__global__ __launch_bounds__(256)
void repinv2(const float* __restrict__ in, ushortt* __restrict__ out) {
  int idx = blockIdx.x * 256 + threadIdx.x;
  if (idx >= 64 * 576) return;
  int co = idx / 576, cip = idx % 576;
  int ci = (cip & 63) * 9 + (cip >> 6);
  out[idx] = f2b(in[(size_t)co * 576 + ci]);
}
// 3x depthwise weights -> contiguous dst, permuted channels
__global__ __launch_bounds__(256)
void repdw3(const float* __restrict__ s0, const float* __restrict__ s1,
            const float* __restrict__ s2, float* __restrict__ dst) {
  int idx = blockIdx.x * 256 + threadIdx.x;
  if (idx >= 3 * 5184) return;
  int which = idx / 5184, r = idx % 5184;
  const float* in = which == 0 ? s0 : which == 1 ? s1 : s2;
  int chp = r / 9, k = r % 9;
  int ch = (chp & 63) * 9 + (chp >> 6);
  dst[idx] = in[ch * 9 + k];
}

// ---------------- off_w6 (NHWC bf16 in) -> NCHW offsets, 8*tanh ----------------
__global__ __launch_bounds__(256)
void off6_nhwc(const ushortt* __restrict__ hi, const float* __restrict__ wgt,
               const float* __restrict__ bias, float* __restrict__ out) {
  __shared__ float Wl[18 * 64];
  for (int i = threadIdx.x; i < 18 * 64; i += 256) Wl[i] = wgt[i];
  __syncthreads();
  int px = blockIdx.x * 256 + threadIdx.x;
  int b = px >> 14, pim = px & 16383;
  float acc[18];
  #pragma unroll
  for (int j = 0; j < 18; j++) acc[j] = 0.f;
  const uint4* ph = (const uint4*)(hi + (size_t)px * 64);
  for (int g = 0; g < 8; g++) {
    uint4 H = ph[g];
    u32 hw[4] = {H.x, H.y, H.z, H.w};
    #pragma unroll
    for (int t = 0; t < 4; t++) {
      float v0 = b2f((ushortt)(hw[t] & 0xffff));
      float v1 = b2f((ushortt)(hw[t] >> 16));
      int ci = g * 8 + t * 2;
      #pragma unroll
      for (int j = 0; j < 18; j++)
        acc[j] += Wl[j * 64 + ci] * v0 + Wl[j * 64 + ci + 1] * v1;
    }
  }
  #pragma unroll
  for (int j = 0; j < 18; j++)
    out[((size_t)b * 18 + j) * HWp + pim] = 8.f * tanhf(acc[j] + bias[j]);
}

// ---------------- fused deform + dct (2 batches per dispatch) ----------------
// grid (HWp/4, 2); xn0/offs0 pre-offset to batch pair.
__global__ __launch_bounds__(256)
void deform_dct(const ushortt* __restrict__ xn0, const float* __restrict__ offs0,
                const float* __restrict__ w9, ushortt* __restrict__ xb,
                ushortt* __restrict__ dctb) {
  __shared__ float Wl[5184];
  for (int i = threadIdx.x; i < 5184; i += 256) Wl[i] = w9[i];
  __syncthreads();
  int bl = blockIdx.y;
  const ushortt* xn = xn0 + (size_t)bl * HWp * 64;
  const float* offs = offs0 + (size_t)bl * 18 * HWp;
  int wid = threadIdx.x >> 6, lane = threadIdx.x & 63;
  int p = blockIdx.x * 4 + wid;
  int yi = p >> 7, xi = p & 127;
  size_t pg = (size_t)bl * HWp + p;
  float v[9];
  #pragma unroll
  for (int k = 0; k < 9; k++) {
    float dy = offs[(size_t)(2 * k) * HWp + p];
    float dx = offs[(size_t)(2 * k + 1) * HWp + p];
    float py = (float)yi + (float)(k / 3 - 1) + dy;
    float px = (float)xi + (float)(k % 3 - 1) + dx;
    float y0f = floorf(py), x0f = floorf(px);
    float wy1 = py - y0f, wy0 = 1.f - wy1;
    float wx1 = px - x0f, wx0 = 1.f - wx1;
    int y0 = (int)y0f, x0 = (int)x0f;
    bool vy0 = (y0 >= 0 && y0 < Hp), vy1 = (y0 + 1 >= 0 && y0 + 1 < Hp);
    bool vx0 = (x0 >= 0 && x0 < Wp), vx1 = (x0 + 1 >= 0 && x0 + 1 < Wp);
    int yc0 = min(max(y0, 0), Hp - 1), yc1 = min(max(y0 + 1, 0), Hp - 1);
    int xc0 = min(max(x0, 0), Wp - 1), xc1 = min(max(x0 + 1, 0), Wp - 1);
    float w00 = wy0 * wx0 * ((vy0 && vx0) ? 1.f : 0.f);
    float w01 = wy0 * wx1 * ((vy0 && vx1) ? 1.f : 0.f);
    float w10 = wy1 * wx0 * ((vy1 && vx0) ? 1.f : 0.f);
    float w11 = wy1 * wx1 * ((vy1 && vx1) ? 1.f : 0.f);
    float v00 = b2f(xn[(size_t)(yc0 * Wp + xc0) * 64 + lane]);
    float v01 = b2f(xn[(size_t)(yc0 * Wp + xc1) * 64 + lane]);
    float v10 = b2f(xn[(size_t)(yc1 * Wp + xc0) * 64 + lane]);
    float v11 = b2f(xn[(size_t)(yc1 * Wp + xc1) * 64 + lane]);
    v[k] = v00 * w00 + v01 * w01 + v10 * w10 + v11 * w11;
    xb[pg * 576 + 64 * k + lane] = f2b(v[k]);
  }
  const float* wc = &Wl[lane * 81];
  #pragma unroll
  for (int j = 0; j < 9; j++) {
    float a = 0.f;
    #pragma unroll
    for (int kk = 0; kk < 9; kk++) a += wc[j * 9 + kk] * v[kk];
    dctb[pg * 576 + 64 * j + lane] = f2b(a);
  }
}

// ---------------- MFMA bf16 GEMM, 64-co tiles, 2-batch px range ----------------
// X [NPX][576] bf16; Wb [>=64*co-tiles][576]; grid (coTiles, NPX/128).
// OUT: 1 bf16 NHWC stride 576; 2 fp32 NCHW (b = px>>14).
template<int OUT>
__global__ __launch_bounds__(256)
void gemm_bf16(const ushortt* __restrict__ X, const ushortt* __restrict__ Wb,
               void* __restrict__ outv) {
  __shared__ ushortt Xs[128 * 32];
  __shared__ ushortt Wsh[64 * 32];
  int tid = threadIdx.x;
  int co0 = blockIdx.x * 64, px0 = blockIdx.y * 128;
  size_t gxo0 = (size_t)(px0 + (tid >> 2)) * 576 + (tid & 3) * 8;
  size_t gxo1 = gxo0 + (size_t)64 * 576;
  size_t gwo  = (size_t)(co0 + (tid >> 2)) * 576 + (tid & 3) * 8;
  int wid = tid >> 6, lane = tid & 63;
  int q = lane >> 4, m = lane & 15;
  int pxh = (wid & 1) * 64, coh = (wid >> 1) * 32;
  float4v acc[4][2];
  #pragma unroll
  for (int i = 0; i < 4; i++)
    #pragma unroll
    for (int j = 0; j < 2; j++) acc[i][j] = (float4v){0.f, 0.f, 0.f, 0.f};

  for (int k0 = 0; k0 < 576; k0 += 32) {
    __syncthreads();
    gll(X + gxo0 + k0,  &Xs[tid * 8]);
    gll(X + gxo1 + k0,  &Xs[2048 + tid * 8]);
    gll(Wb + gwo + k0,  &Wsh[tid * 8]);
    __syncthreads();
    short8 a[4], b[2];
    #pragma unroll
    for (int i = 0; i < 4; i++)
      a[i] = *(const short8*)&Xs[(pxh + i * 16 + m) * 32 + q * 8];
    #pragma unroll
    for (int j = 0; j < 2; j++)
      b[j] = *(const short8*)&Wsh[(coh + j * 16 + m) * 32 + q * 8];
    #pragma unroll
    for (int i = 0; i < 4; i++)
      #pragma unroll
      for (int j = 0; j < 2; j++)
        acc[i][j] = __builtin_amdgcn_mfma_f32_16x16x32_bf16(a[i], b[j], acc[i][j], 0, 0, 0);
  }

  #pragma unroll
  for (int j = 0; j < 2; j++) {
    int co = co0 + coh + j * 16 + m;
    #pragma unroll
    for (int i = 0; i < 4; i++) {
      int pxb = px0 + pxh + i * 16 + q * 4;
      if (OUT == 2) {
        int bl = pxb >> 14, pim = pxb & 16383;
        float4 r;
        r.x = acc[i][j][0]; r.y = acc[i][j][1];
        r.z = acc[i][j][2]; r.w = acc[i][j][3];
        *(float4*)&((float*)outv)[(size_t)(bl * 64 + co) * HWp + pim] = r;
      } else {
        #pragma unroll
        for (int r = 0; r < 4; r++)
          ((ushortt*)outv)[(size_t)(pxb + r) * 576 + co] = f2b(acc[i][j][r]);
      }
    }
  }
}

// ---------------- depthwise 3x3 NHWC bf16, 2 batches, 2 ch/thread ----------------
template<int ACT>
__global__ __launch_bounds__(256)
void dw3x3_nhwc(const ushortt* __restrict__ in, const float* __restrict__ wdw,
                ushortt* __restrict__ out) {
  int l = threadIdx.x & 31, pxl = threadIdx.x >> 5;
  int ch = blockIdx.y * 64 + l * 2;
  int px = blockIdx.x * 8 + pxl;            // [0, 2*HWp)
  int pim = px & 16383, bo = px - pim;
  int y = pim >> 7, xx = pim & 127;
  float w0[9], w1[9];
  #pragma unroll
  for (int k = 0; k < 9; k++) {
    w0[k] = wdw[ch * 9 + k];
    w1[k] = wdw[(ch + 1) * 9 + k];
  }
  float a0 = 0.f, a1 = 0.f;
  #pragma unroll
  for (int k = 0; k < 9; k++) {
    int yy = y + k / 3 - 1, xw = xx + k % 3 - 1;
    if (yy >= 0 && yy < Hp && xw >= 0 && xw < Wp) {
      u32 t = *(const u32*)&in[(size_t)(bo + yy * Wp + xw) * 576 + ch];
      a0 += b2f((ushortt)(t & 0xffff)) * w0[k];
      a1 += b2f((ushortt)(t >> 16)) * w1[k];
    }
  }
  float r0, r1;
  if (ACT == 1) { r0 = fmaxf(a0, 0.f); r1 = fmaxf(a1, 0.f); }
  else { r0 = 1.f / (1.f + __expf(-a0)); r1 = 1.f / (1.f + __expf(-a1)); }
  u32 o = (u32)f2b(r0) | (((u32)f2b(r1)) << 16);
  *(u32*)&out[(size_t)px * 576 + ch] = o;
}

// ---------------- group 9->9 inv1, fused wiener*dct (2 batches, bf16) ----------------
__global__ __launch_bounds__(256)
void g9inv(const ushortt* __restrict__ wien, const ushortt* __restrict__ dct,
           const float* __restrict__ w9, ushortt* __restrict__ outb) {
  __shared__ float Wl[5184];
  for (int i = threadIdx.x; i < 5184; i += 256) Wl[i] = w9[i];
  __syncthreads();
  int c = threadIdx.x & 63, pxl = threadIdx.x >> 6;
  size_t px = (size_t)blockIdx.x * 4 + pxl;   // [0, 2*HWp)
  float v[9];
  #pragma unroll
  for (int kk = 0; kk < 9; kk++)
    v[kk] = b2f(wien[px * 576 + 64 * kk + c]) * b2f(dct[px * 576 + 64 * kk + c]);
  const float* wc = &Wl[c * 81];
  #pragma unroll
  for (int j = 0; j < 9; j++) {
    float a = 0.f;
    #pragma unroll
    for (int kk = 0; kk < 9; kk++) a += wc[j * 9 + kk] * v[kk];
    outb[px * 576 + 64 * j + c] = f2b(a);
  }
}

// ---------------- launch ----------------
extern "C" void kernel_launch(void* const* d_in, const int* in_sizes, int n_in,
                              void* d_out, int out_size, void* d_ws, size_t ws_size,
                              hipStream_t stream) {
  const float* x       = (const float*)d_in[0];
  const float* enc_dw  = (const float*)d_in[1];
  const float* enc_pw1 = (const float*)d_in[2];
  const float* enc_pw2 = (const float*)d_in[3];
  const float* dec_dw  = (const float*)d_in[4];
  const float* dec_pw1 = (const float*)d_in[5];
  const float* dec_pw2 = (const float*)d_in[6];
  const float* off_w1  = (const float*)d_in[7];
  const float* off_b1  = (const float*)d_in[8];
  const float* off_w2  = (const float*)d_in[9];
  const float* off_b2  = (const float*)d_in[10];
  const float* off_w3  = (const float*)d_in[11];
  const float* off_b3  = (const float*)d_in[12];
  const float* off_w4  = (const float*)d_in[13];
  const float* off_b4  = (const float*)d_in[14];
  const float* off_w5  = (const float*)d_in[15];
  const float* off_b5  = (const float*)d_in[16];
  const float* off_w6  = (const float*)d_in[17];
  const float* off_b6  = (const float*)d_in[18];
  const float* dct_w   = (const float*)d_in[19];
  const float* wie_w1  = (const float*)d_in[20];
  const float* wie_w2  = (const float*)d_in[21];
  const float* wie_w3  = (const float*)d_in[22];
  const float* wie_w4  = (const float*)d_in[23];
  const float* wie_w5  = (const float*)d_in[24];
  const float* wie_w6  = (const float*)d_in[25];
  const float* inv_w1  = (const float*)d_in[26];
  const float* inv_w2  = (const float*)d_in[27];
  float* outp = (float*)d_out;

  const size_t NP = (size_t)Bp * HWp;
  const size_t REQ_FLOATS = NP * 64 + NP * 64 + NP * 128 +
                            2 * (size_t)HWp * CKp + (size_t)HWp * CKp;
  if (ws_size < REQ_FLOATS * sizeof(float)) return;

  float* ws  = (float*)d_ws;
  float* x1  = ws;                       // enc out fp32; later mid (dec input NCHW)
  float* t0  = x1 + NP * 64;             // dw7 tmp / offs + weights
  float* t1  = t0 + NP * 64;             // xnAll + offset ping-pong
  float* bigA = t1 + NP * 128;           // R1 region / fp32 pw tmp
  float* bigB = bigA + (size_t)HWp * CKp;  // R2 region
  float* bigC = bigB + (size_t)HWp * CKp;  // R3 region
  // 2-batch bf16 regions (each 2*HWp*576 ushorts = one HWp*CKp float region)
  ushortt* R1 = (ushortt*)bigA;
  ushortt* R2 = (ushortt*)bigB;
  ushortt* R3 = (ushortt*)bigC;

  // weight region in t0 after the offset maps
  float* wreg = t0 + NP * 18;
  ushortt* wb  = (ushortt*)wreg;            // 3 x [640][576]
  ushortt* wbi2 = wb + 3 * 640 * 576;       // [64][576]
  float* wdw = (float*)(wbi2 + 64 * 576);   // 3 x 5184
  ushortt* wc1 = (ushortt*)(wdw + 3 * 5184);  // [1][64][64]
  ushortt* wc2 = wc1 + 4096;                  // 4 x [9][64][64]

  // t1 region: xnAll (NP*64 ush) + oA/oB ping-pong
  ushortt* xnAll = (ushortt*)t1;
  ushortt* oA = xnAll + NP * 64;
  ushortt* oB = oA + NP * 64;

  float* offs = t0;
  float* mid  = x1;

  dim3 blk(256);

  // ---- enc ConvNeXt (full batch); pw1 tmp in bigA ----
  dwconv7_lds<<<dim3(Hp / 2, Bp * Cp), blk, 0, stream>>>(x, enc_dw, t0);
  conv1x1<1, false, false><<<dim3(HWp / 128, 2, Bp), blk, 0, stream>>>(
      t0, enc_pw1, nullptr, nullptr, bigA, 64, 128);
  conv1x1<0, true, false><<<dim3(HWp / 128, 1, Bp), blk, 0, stream>>>(
      bigA, enc_pw2, nullptr, x, x1, 128, 64);

  // ---- weight repacks (merged) ----
  rep576x3<<<dim3((640 * 576 + 255) / 256, 3), blk, 0, stream>>>(
      wie_w1, wie_w3, wie_w5, wb);
  repinv2<<<dim3((64 * 576 + 255) / 256), blk, 0, stream>>>(inv_w2, wbi2);
  repdw3<<<dim3((3 * 5184 + 255) / 256), blk, 0, stream>>>(wie_w2, wie_w4, wie_w6, wdw);
  repw1<<<dim3(16), blk, 0, stream>>>(off_w1, wc1);
  repw9x4<<<dim3((36864 + 255) / 256, 4), blk, 0, stream>>>(
      off_w2, off_w3, off_w4, off_w5, wc2);

  // ---- offset CNN (full batch, bf16 MFMA, NHWC) ----
  t64b<<<dim3(HWp / 64, Bp), blk, 0, stream>>>(x1, xnAll);
  conv_bf<1><<<dim3(HWp / 64, Bp), blk, 0, stream>>>(xnAll, wc1, off_b1, oA);
  conv_bf<9><<<dim3(HWp / 64, Bp), blk, 0, stream>>>(oA, wc2,             off_b2, oB);
  conv_bf<9><<<dim3(HWp / 64, Bp), blk, 0, stream>>>(oB, wc2 + 36864,     off_b3, oA);
  conv_bf<9><<<dim3(HWp / 64, Bp), blk, 0, stream>>>(oA, wc2 + 2 * 36864, off_b4, oB);
  conv_bf<9><<<dim3(HWp / 64, Bp), blk, 0, stream>>>(oB, wc2 + 3 * 36864, off_b5, oA);
  off6_nhwc<<<dim3(NP / 256), blk, 0, stream>>>(oA, off_w6, off_b6, offs);

  // ---- 576-channel middle: 2 batches per pass ----
  for (int bp = 0; bp < 2; bp++) {
    const ushortt* xn0 = xnAll + (size_t)(2 * bp) * HWp * 64;
    const float* off0 = offs + (size_t)(2 * bp) * 18 * HWp;
    float* mid0 = mid + (size_t)(2 * bp) * 64 * HWp;

    deform_dct<<<dim3(HWp / 4, 2), blk, 0, stream>>>(xn0, off0, dct_w, R1, R2);
    gemm_bf16<1><<<dim3(9, 256), blk, 0, stream>>>(R1, wb, R3);
    dw3x3_nhwc<1><<<dim3(2 * HWp / 8, 9), blk, 0, stream>>>(R3, wdw, R1);
    gemm_bf16<1><<<dim3(9, 256), blk, 0, stream>>>(R1, wb + 640 * 576, R3);
    dw3x3_nhwc<1><<<dim3(2 * HWp / 8, 9), blk, 0, stream>>>(R3, wdw + 5184, R1);
    gemm_bf16<1><<<dim3(9, 256), blk, 0, stream>>>(R1, wb + 2 * 640 * 576, R3);
    dw3x3_nhwc<2><<<dim3(2 * HWp / 8, 9), blk, 0, stream>>>(R3, wdw + 2 * 5184, R1);
    g9inv<<<dim3(2 * HWp / 4), blk, 0, stream>>>(R1, R2, inv_w1, R3);
    gemm_bf16<2><<<dim3(1, 256), blk, 0, stream>>>(R3, wbi2, mid0);
  }

  // ---- dec ConvNeXt (full batch); pw1 tmp in bigA ----
  dwconv7_lds<<<dim3(Hp / 2, Bp * Cp), blk, 0, stream>>>(mid, dec_dw, t0);
  conv1x1<1, false, false><<<dim3(HWp / 128, 2, Bp), blk, 0, stream>>>(
      t0, dec_pw1, nullptr, nullptr, bigA, 64, 128);
  conv1x1<0, true, false><<<dim3(HWp / 128, 1, Bp), blk, 0, stream>>>(
      bigA, dec_pw2, nullptr, mid, outp, 128, 64);
}

// Round 8
// 1062.926 us; speedup vs baseline: 3.7725x; 1.2340x over previous
//
#include <hip/hip_runtime.h>
#include <math.h>

#define HWp 16384
#define Wp 128
#define Hp 128
#define Bp 4
#define Cp 64
#define CKp 576

typedef unsigned int u32;
typedef unsigned short ushortt;
typedef __attribute__((ext_vector_type(8))) short short8;
typedef __attribute__((ext_vector_type(4))) float float4v;

__device__ __forceinline__ ushortt f2b(float f) {
  union { float f; u32 u; } x; x.f = f;
  u32 r = x.u + 0x7fff + ((x.u >> 16) & 1);
  return (ushortt)(r >> 16);
}
__device__ __forceinline__ float b2f(ushortt h) {
  union { u32 u; float f; } x; x.u = ((u32)h) << 16; return x.f;
}
__device__ __forceinline__ float blo(u32 t) {
  union { u32 u; float f; } x; x.u = t << 16; return x.f;
}
__device__ __forceinline__ float bhi(u32 t) {
  union { u32 u; float f; } x; x.u = t & 0xffff0000u; return x.f;
}
__device__ __forceinline__ void gll(const ushortt* g, ushortt* l) {
  __builtin_amdgcn_global_load_lds(
      (const __attribute__((address_space(1))) u32*)g,
      (__attribute__((address_space(3))) u32*)l, 16, 0, 0);
}

// ---------------- depthwise 7x7, pad 3, LDS-tiled (NCHW) ----------------
__global__ __launch_bounds__(256)
void dwconv7_lds(const float* __restrict__ in, const float* __restrict__ w,
                 float* __restrict__ out) {
  int bc = blockIdx.y;
  int tid = threadIdx.x;
  int y0 = blockIdx.x * 2;
  __shared__ float ws[49];
  __shared__ float tile[8][136];
  if (tid < 49) ws[tid] = w[(bc & 63) * 49 + tid];
  if (tid < 48) {
    int r = tid / 6, cc = tid % 6;
    tile[r][cc < 3 ? cc : 128 + cc] = 0.f;
  }
  const float* ip = in + (size_t)bc * HWp;
  #pragma unroll
  for (int i = 0; i < 4; i++) {
    int idx = tid + 256 * i;
    int r = idx >> 7, xx = idx & 127;
    int yy = y0 - 3 + r;
    tile[r][xx + 3] = (yy >= 0 && yy < Hp) ? ip[yy * Wp + xx] : 0.f;
  }
  __syncthreads();
  int ty = tid >> 7, x = tid & 127;
  float acc = 0.f;
  #pragma unroll
  for (int dy = 0; dy < 7; dy++)
    #pragma unroll
    for (int dx = 0; dx < 7; dx++)
      acc += tile[ty + dy][x + dx] * ws[dy * 7 + dx];
  out[(size_t)bc * HWp + (y0 + ty) * Wp + x] = acc;
}

// ---------------- bf16 MFMA pointwise conv (enc/dec ConvNeXt pw) ----------------
// in NHWC bf16 [NP][CIN]; wt [Cout][CIN] bf16.
// MODE 0: out bf16 NHWC (stride Cout), ACT relu optional.
// MODE 1: out bf16 NHWC stride 64 + resid fp32 NCHW added.
// MODE 2: out fp32 NCHW + resid fp32 NCHW added.
template<int CIN, int ACT, int MODE>
__global__ __launch_bounds__(256)
void pw_bf(const ushortt* __restrict__ in, const ushortt* __restrict__ wt,
           const float* __restrict__ resid, void* __restrict__ outv, int Cout) {
  int tid = threadIdx.x;
  int wid = tid >> 6, lane = tid & 63;
  int q = lane >> 4, m = lane & 15;
  int px0 = blockIdx.x * 128, co0 = blockIdx.y * 64;
  int pxh = (wid & 1) * 64, coh = (wid >> 1) * 32;
  float4v acc[4][2];
  #pragma unroll
  for (int i = 0; i < 4; i++)
    #pragma unroll
    for (int j = 0; j < 2; j++) acc[i][j] = (float4v){0.f, 0.f, 0.f, 0.f};

  #pragma unroll
  for (int k0 = 0; k0 < CIN; k0 += 32) {
    short8 a[4], b[2];
    #pragma unroll
    for (int j = 0; j < 2; j++)
      b[j] = *(const short8*)&wt[(size_t)(co0 + coh + j * 16 + m) * CIN + k0 + q * 8];
    #pragma unroll
    for (int i = 0; i < 4; i++)
      a[i] = *(const short8*)&in[(size_t)(px0 + pxh + i * 16 + m) * CIN + k0 + q * 8];
    #pragma unroll
    for (int i = 0; i < 4; i++)
      #pragma unroll
      for (int j = 0; j < 2; j++)
        acc[i][j] = __builtin_amdgcn_mfma_f32_16x16x32_bf16(a[i], b[j], acc[i][j], 0, 0, 0);
  }

  #pragma unroll
  for (int j = 0; j < 2; j++) {
    int co = co0 + coh + j * 16 + m;
    #pragma unroll
    for (int i = 0; i < 4; i++) {
      int pxb = px0 + pxh + i * 16 + q * 4;
      int bl = pxb >> 14, pim = pxb & 16383;
      if (MODE == 0) {
        #pragma unroll
        for (int r = 0; r < 4; r++) {
          float v = acc[i][j][r];
          if (ACT == 1) v = fmaxf(v, 0.f);
          ((ushortt*)outv)[(size_t)(pxb + r) * Cout + co] = f2b(v);
        }
      } else {
        float4 rr = *(const float4*)&resid[(size_t)(bl * 64 + co) * HWp + pim];
        float v0 = acc[i][j][0] + rr.x, v1 = acc[i][j][1] + rr.y;
        float v2 = acc[i][j][2] + rr.z, v3 = acc[i][j][3] + rr.w;
        if (MODE == 1) {
          ushortt* ob = (ushortt*)outv;
          ob[(size_t)(pxb + 0) * 64 + co] = f2b(v0);
          ob[(size_t)(pxb + 1) * 64 + co] = f2b(v1);
          ob[(size_t)(pxb + 2) * 64 + co] = f2b(v2);
          ob[(size_t)(pxb + 3) * 64 + co] = f2b(v3);
        } else {
          float4 w4; w4.x = v0; w4.y = v1; w4.z = v2; w4.w = v3;
          *(float4*)&((float*)outv)[(size_t)(bl * 64 + co) * HWp + pim] = w4;
        }
      }
    }
  }
}

// ---------------- plain-bf16 MFMA conv (1x1 or 3x3 pad1), NHWC 64ch ----------------
template<int TAPS>
__global__ __launch_bounds__(256)
void conv_bf(const ushortt* __restrict__ in, const ushortt* __restrict__ wt,
             const float* __restrict__ bias, ushortt* __restrict__ out) {
  int tid = threadIdx.x;
  int wid = tid >> 6, lane = tid & 63;
  int q = lane >> 4, m = lane & 15;
  int bx = blockIdx.x, b = blockIdx.y;
  int y = bx >> 1;
  int c0 = ((bx & 1) << 6) + ((wid & 1) << 5);
  int coW = (wid >> 1) << 5;
  size_t ibase = (size_t)b * HWp;

  float4v acc[2][2];
  #pragma unroll
  for (int i = 0; i < 2; i++)
    #pragma unroll
    for (int j = 0; j < 2; j++) acc[i][j] = (float4v){0.f, 0.f, 0.f, 0.f};
  short8 zz = {0, 0, 0, 0, 0, 0, 0, 0};

  #pragma unroll
  for (int k = 0; k < TAPS; k++) {
    int dy = (TAPS == 9) ? (k / 3 - 1) : 0;
    int dx = (TAPS == 9) ? (k % 3 - 1) : 0;
    int yy = y + dy;
    if (TAPS == 9 && (yy < 0 || yy >= Hp)) continue;
    #pragma unroll
    for (int ch = 0; ch < 2; ch++) {
      int ci0 = ch * 32 + q * 8;
      short8 bfr[2], afr[2];
      #pragma unroll
      for (int j = 0; j < 2; j++)
        bfr[j] = *(const short8*)&wt[(size_t)(k * 64 + coW + j * 16 + m) * 64 + ci0];
      #pragma unroll
      for (int i = 0; i < 2; i++) {
        int col = c0 + i * 16 + m + dx;
        bool vld = (TAPS == 1) || ((unsigned)col < (unsigned)Wp);
        int colc = min(max(col, 0), Wp - 1);
        short8 h = *(const short8*)&in[(ibase + (size_t)yy * Wp + colc) * 64 + ci0];
        afr[i] = vld ? h : zz;
      }
      #pragma unroll
      for (int i = 0; i < 2; i++)
        #pragma unroll
        for (int j = 0; j < 2; j++)
          acc[i][j] = __builtin_amdgcn_mfma_f32_16x16x32_bf16(afr[i], bfr[j], acc[i][j], 0, 0, 0);
    }
  }

  #pragma unroll
  for (int j = 0; j < 2; j++) {
    int co = coW + j * 16 + m;
    float bv = bias[co];
    #pragma unroll
    for (int i = 0; i < 2; i++) {
      #pragma unroll
      for (int r = 0; r < 4; r++) {
        size_t px = ibase + (size_t)y * Wp + c0 + i * 16 + q * 4 + r;
        float v = acc[i][j][r] + bv;
        v = v > 0.f ? v : 0.1f * v;
        out[px * 64 + co] = f2b(v);
      }
    }
  }
}

// ---------------- NCHW fp32 -> NHWC bf16 (full batch) ----------------
__global__ __launch_bounds__(256)
void t64b(const float* __restrict__ in, ushortt* __restrict__ out) {
  __shared__ float tl[64 * 65];
  int tid = threadIdx.x;
  int b = blockIdx.y;
  int px0 = blockIdx.x * 64;
  int lpx = tid & 63, c4 = tid >> 6;
  const float* ip = in + (size_t)b * 64 * HWp;
  #pragma unroll
  for (int i = 0; i < 16; i++) {
    int c = c4 + 4 * i;
    tl[lpx * 65 + c] = ip[(size_t)c * HWp + px0 + lpx];
  }
  __syncthreads();
  int ci = tid & 63, pr = tid >> 6;
  #pragma unroll
  for (int i = 0; i < 16; i++) {
    int r = pr + 4 * i;
    out[((size_t)b * HWp + px0 + r) * 64 + ci] = f2b(tl[r * 65 + ci]);
  }
}

// ---------------- weight repacks ----------------
__global__ __launch_bounds__(256)
void repw1(const float* __restrict__ in, ushortt* __restrict__ out) {
  int idx = blockIdx.x * 256 + threadIdx.x;
  if (idx >= 4096) return;
  out[idx] = f2b(in[idx]);   // [co][ci] taps=1 identical layout
}
__global__ __launch_bounds__(256)
void repw9x4(const float* __restrict__ s0, const float* __restrict__ s1,
             const float* __restrict__ s2, const float* __restrict__ s3,
             ushortt* __restrict__ dst) {
  int which = blockIdx.y;
  const float* in = which == 0 ? s0 : which == 1 ? s1 : which == 2 ? s2 : s3;
  int idx = blockIdx.x * 256 + threadIdx.x;
  if (idx >= 36864) return;
  int k = idx >> 12, r = idx & 4095;
  int co = r >> 6, ci = r & 63;
  dst[which * 36864 + idx] = f2b(in[(size_t)(co * 64 + ci) * 9 + k]);
}
__global__ __launch_bounds__(256)
void rep576x3(const float* __restrict__ s0, const float* __restrict__ s1,
              const float* __restrict__ s2, ushortt* __restrict__ dst) {
  int which = blockIdx.y;
  const float* in = which == 0 ? s0 : which == 1 ? s1 : s2;
  int idx = blockIdx.x * 256 + threadIdx.x;
  if (idx >= 640 * 576) return;
  int cop = idx / 576, cip = idx % 576;
  ushortt v = 0;
  if (cop < 576) {
    int co = (cop & 63) * 9 + (cop >> 6);
    int ci = (cip & 63) * 9 + (cip >> 6);
    v = f2b(in[(size_t)co * 576 + ci]);
  }
  dst[(size_t)which * 640 * 576 + idx] = v;
}
__global__ __launch_bounds__(256)
void repinv2(const float* __restrict__ in, ushortt* __restrict__ out) {
  int idx = blockIdx.x * 256 + threadIdx.x;
  if (idx >= 64 * 576) return;
  int co = idx / 576, cip = idx % 576;
  int ci = (cip & 63) * 9 + (cip >> 6);
  out[idx] = f2b(in[(size_t)co * 576 + ci]);
}
// 3x depthwise weights -> bf16 [which][tap][576 perm-ch]
__global__ __launch_bounds__(256)
void repdw3(const float* __restrict__ s0, const float* __restrict__ s1,
            const float* __restrict__ s2, ushortt* __restrict__ dst) {
  int idx = blockIdx.x * 256 + threadIdx.x;
  if (idx >= 3 * 5184) return;
  int which = idx / 5184, r = idx % 5184;
  const float* in = which == 0 ? s0 : which == 1 ? s1 : s2;
  int tap = r / 576, chp = r % 576;
  int ch = (chp & 63) * 9 + (chp >> 6);
  dst[idx] = f2b(in[ch * 9 + tap]);
}
// 4x pointwise weights (dense bf16 cast, layout preserved)
__global__ __launch_bounds__(256)
void reppw4(const float* __restrict__ s0, const float* __restrict__ s1,
            const float* __restrict__ s2, const float* __restrict__ s3,
            ushortt* __restrict__ dst) {
  int which = blockIdx.y;
  const float* in = which == 0 ? s0 : which == 1 ? s1 : which == 2 ? s2 : s3;
  int idx = blockIdx.x * 256 + threadIdx.x;
  if (idx >= 8192) return;
  dst[which * 8192 + idx] = f2b(in[idx]);
}

// ---------------- off_w6 -> NCHW offsets, 8*tanh ----------------
__global__ __launch_bounds__(256)
void off6_nhwc(const ushortt* __restrict__ hi, const float* __restrict__ wgt,
               const float* __restrict__ bias, float* __restrict__ out) {
  __shared__ float Wl[18 * 64];
  for (int i = threadIdx.x; i < 18 * 64; i += 256) Wl[i] = wgt[i];
  __syncthreads();
  int px = blockIdx.x * 256 + threadIdx.x;
  int b = px >> 14, pim = px & 16383;
  float acc[18];
  #pragma unroll
  for (int j = 0; j < 18; j++) acc[j] = 0.f;
  const uint4* ph = (const uint4*)(hi + (size_t)px * 64);
  for (int g = 0; g < 8; g++) {
    uint4 H = ph[g];
    u32 hw[4] = {H.x, H.y, H.z, H.w};
    #pragma unroll
    for (int t = 0; t < 4; t++) {
      float v0 = blo(hw[t]);
      float v1 = bhi(hw[t]);
      int ci = g * 8 + t * 2;
      #pragma unroll
      for (int j = 0; j < 18; j++)
        acc[j] += Wl[j * 64 + ci] * v0 + Wl[j * 64 + ci + 1] * v1;
    }
  }
  #pragma unroll
  for (int j = 0; j < 18; j++)
    out[((size_t)b * 18 + j) * HWp + pim] = 8.f * tanhf(acc[j] + bias[j]);
}

// ---------------- fused deform + dct (2 batches per dispatch) ----------------
__global__ __launch_bounds__(256)
void deform_dct(const ushortt* __restrict__ xn0, const float* __restrict__ offs0,
                const float* __restrict__ w9, ushortt* __restrict__ xb,
                ushortt* __restrict__ dctb) {
  __shared__ float Wl[5184];
  for (int i = threadIdx.x; i < 5184; i += 256) Wl[i] = w9[i];
  __syncthreads();
  int bl = blockIdx.y;
  const ushortt* xn = xn0 + (size_t)bl * HWp * 64;
  const float* offs = offs0 + (size_t)bl * 18 * HWp;
  int wid = threadIdx.x >> 6, lane = threadIdx.x & 63;
  int p = blockIdx.x * 4 + wid;
  int yi = p >> 7, xi = p & 127;
  size_t pg = (size_t)bl * HWp + p;
  float v[9];
  #pragma unroll
  for (int k = 0; k < 9; k++) {
    float dy = offs[(size_t)(2 * k) * HWp + p];
    float dx = offs[(size_t)(2 * k + 1) * HWp + p];
    float py = (float)yi + (float)(k / 3 - 1) + dy;
    float px = (float)xi + (float)(k % 3 - 1) + dx;
    float y0f = floorf(py), x0f = floorf(px);
    float wy1 = py - y0f, wy0 = 1.f - wy1;
    float wx1 = px - x0f, wx0 = 1.f - wx1;
    int y0 = (int)y0f, x0 = (int)x0f;
    bool vy0 = (y0 >= 0 && y0 < Hp), vy1 = (y0 + 1 >= 0 && y0 + 1 < Hp);
    bool vx0 = (x0 >= 0 && x0 < Wp), vx1 = (x0 + 1 >= 0 && x0 + 1 < Wp);
    int yc0 = min(max(y0, 0), Hp - 1), yc1 = min(max(y0 + 1, 0), Hp - 1);
    int xc0 = min(max(x0, 0), Wp - 1), xc1 = min(max(x0 + 1, 0), Wp - 1);
    float w00 = wy0 * wx0 * ((vy0 && vx0) ? 1.f : 0.f);
    float w01 = wy0 * wx1 * ((vy0 && vx1) ? 1.f : 0.f);
    float w10 = wy1 * wx0 * ((vy1 && vx0) ? 1.f : 0.f);
    float w11 = wy1 * wx1 * ((vy1 && vx1) ? 1.f : 0.f);
    float v00 = b2f(xn[(size_t)(yc0 * Wp + xc0) * 64 + lane]);
    float v01 = b2f(xn[(size_t)(yc0 * Wp + xc1) * 64 + lane]);
    float v10 = b2f(xn[(size_t)(yc1 * Wp + xc0) * 64 + lane]);
    float v11 = b2f(xn[(size_t)(yc1 * Wp + xc1) * 64 + lane]);
    v[k] = v00 * w00 + v01 * w01 + v10 * w10 + v11 * w11;
    xb[pg * 576 + 64 * k + lane] = f2b(v[k]);
  }
  const float* wc = &Wl[lane * 81];
  #pragma unroll
  for (int j = 0; j < 9; j++) {
    float a = 0.f;
    #pragma unroll
    for (int kk = 0; kk < 9; kk++) a += wc[j * 9 + kk] * v[kk];
    dctb[pg * 576 + 64 * j + lane] = f2b(a);
  }
}

// ---------------- MFMA bf16 GEMM, 64-co tiles, 2-batch px range ----------------
template<int OUT>   // 1 bf16 NHWC stride 576; 2 fp32 NCHW
__global__ __launch_bounds__(256)
void gemm_bf16(const ushortt* __restrict__ X, const ushortt* __restrict__ Wb,
               void* __restrict__ outv) {
  __shared__ ushortt Xs[128 * 32];
  __shared__ ushortt Wsh[64 * 32];
  int tid = threadIdx.x;
  int co0 = blockIdx.x * 64, px0 = blockIdx.y * 128;
  size_t gxo0 = (size_t)(px0 + (tid >> 2)) * 576 + (tid & 3) * 8;
  size_t gxo1 = gxo0 + (size_t)64 * 576;
  size_t gwo  = (size_t)(co0 + (tid >> 2)) * 576 + (tid & 3) * 8;
  int wid = tid >> 6, lane = tid & 63;
  int q = lane >> 4, m = lane & 15;
  int pxh = (wid & 1) * 64, coh = (wid >> 1) * 32;
  float4v acc[4][2];
  #pragma unroll
  for (int i = 0; i < 4; i++)
    #pragma unroll
    for (int j = 0; j < 2; j++) acc[i][j] = (float4v){0.f, 0.f, 0.f, 0.f};

  for (int k0 = 0; k0 < 576; k0 += 32) {
    __syncthreads();
    gll(X + gxo0 + k0,  &Xs[tid * 8]);
    gll(X + gxo1 + k0,  &Xs[2048 + tid * 8]);
    gll(Wb + gwo + k0,  &Wsh[tid * 8]);
    __syncthreads();
    short8 a[4], b[2];
    #pragma unroll
    for (int i = 0; i < 4; i++)
      a[i] = *(const short8*)&Xs[(pxh + i * 16 + m) * 32 + q * 8];
    #pragma unroll
    for (int j = 0; j < 2; j++)
      b[j] = *(const short8*)&Wsh[(coh + j * 16 + m) * 32 + q * 8];
    #pragma unroll
    for (int i = 0; i < 4; i++)
      #pragma unroll
      for (int j = 0; j < 2; j++)
        acc[i][j] = __builtin_amdgcn_mfma_f32_16x16x32_bf16(a[i], b[j], acc[i][j], 0, 0, 0);
  }

  #pragma unroll
  for (int j = 0; j < 2; j++) {
    int co = co0 + coh + j * 16 + m;
    #pragma unroll
    for (int i = 0; i < 4; i++) {
      int pxb = px0 + pxh + i * 16 + q * 4;
      if (OUT == 2) {
        int bl = pxb >> 14, pim = pxb & 16383;
        float4 r;
        r.x = acc[i][j][0]; r.y = acc[i][j][1];
        r.z = acc[i][j][2]; r.w = acc[i][j][3];
        *(float4*)&((float*)outv)[(size_t)(bl * 64 + co) * HWp + pim] = r;
      } else {
        #pragma unroll
        for (int r = 0; r < 4; r++)
          ((ushortt*)outv)[(size_t)(pxb + r) * 576 + co] = f2b(acc[i][j][r]);
      }
    }
  }
}

// ---------------- depthwise 3x3 NHWC bf16 v2: 8ch x 4-row column per thread ----------------
// grid (43, 32, 2): x-triple, y-tile(4 rows), batch. wt bf16 [9][576].
template<int ACT>
__global__ __launch_bounds__(256)
void dw3x3_v2(const ushortt* __restrict__ in, const ushortt* __restrict__ wt,
              ushortt* __restrict__ out) {
  int tid = threadIdx.x;
  int pxl = tid / 72;
  int g = tid - pxl * 72;
  if (pxl >= 3) return;
  int x = blockIdx.x * 3 + pxl;
  if (x >= Wp) return;
  int y0 = blockIdx.y * 4;
  size_t bbase = (size_t)blockIdx.z * HWp;

  float w[9][8];
  #pragma unroll
  for (int t = 0; t < 9; t++) {
    uint4 wv = *(const uint4*)&wt[t * 576 + g * 8];
    u32 wsw[4] = {wv.x, wv.y, wv.z, wv.w};
    #pragma unroll
    for (int p = 0; p < 4; p++) {
      w[t][2 * p]     = blo(wsw[p]);
      w[t][2 * p + 1] = bhi(wsw[p]);
    }
  }
  float acc[4][8];
  #pragma unroll
  for (int o = 0; o < 4; o++)
    #pragma unroll
    for (int c = 0; c < 8; c++) acc[o][c] = 0.f;

  #pragma unroll
  for (int ri = 0; ri < 6; ri++) {
    int yy = y0 - 1 + ri;
    bool vr = (yy >= 0 && yy < Hp);
    float v[3][8];
    #pragma unroll
    for (int dx = 0; dx < 3; dx++) {
      int xx = x + dx - 1;
      uint4 t4 = {0, 0, 0, 0};
      if (vr && xx >= 0 && xx < Wp)
        t4 = *(const uint4*)&in[(bbase + (size_t)yy * Wp + xx) * 576 + g * 8];
      u32 tw[4] = {t4.x, t4.y, t4.z, t4.w};
      #pragma unroll
      for (int p = 0; p < 4; p++) {
        v[dx][2 * p]     = blo(tw[p]);
        v[dx][2 * p + 1] = bhi(tw[p]);
      }
    }
    #pragma unroll
    for (int o = 0; o < 4; o++) {
      int dy = ri - o;
      if (dy < 0 || dy > 2) continue;
      #pragma unroll
      for (int dx = 0; dx < 3; dx++)
        #pragma unroll
        for (int c = 0; c < 8; c++)
          acc[o][c] += w[dy * 3 + dx][c] * v[dx][c];
    }
  }

  #pragma unroll
  for (int o = 0; o < 4; o++) {
    int yy = y0 + o;
    u32 pk[4];
    #pragma unroll
    for (int p = 0; p < 4; p++) {
      float r0 = acc[o][2 * p], r1 = acc[o][2 * p + 1];
      if (ACT == 1) { r0 = fmaxf(r0, 0.f); r1 = fmaxf(r1, 0.f); }
      else { r0 = 1.f / (1.f + __expf(-r0)); r1 = 1.f / (1.f + __expf(-r1)); }
      pk[p] = (u32)f2b(r0) | (((u32)f2b(r1)) << 16);
    }
    uint4 o4; o4.x = pk[0]; o4.y = pk[1]; o4.z = pk[2]; o4.w = pk[3];
    *(uint4*)&out[(bbase + (size_t)yy * Wp + x) * 576 + g * 8] = o4;
  }
}

// ---------------- group 9->9 inv1, fused wiener*dct (2 batches, bf16) ----------------
__global__ __launch_bounds__(256)
void g9inv(const ushortt* __restrict__ wien, const ushortt* __restrict__ dct,
           const float* __restrict__ w9, ushortt* __restrict__ outb) {
  __shared__ float Wl[5184];
  for (int i = threadIdx.x; i < 5184; i += 256) Wl[i] = w9[i];
  __syncthreads();
  int c = threadIdx.x & 63, pxl = threadIdx.x >> 6;
  size_t px = (size_t)blockIdx.x * 4 + pxl;
  float v[9];
  #pragma unroll
  for (int kk = 0; kk < 9; kk++)
    v[kk] = b2f(wien[px * 576 + 64 * kk + c]) * b2f(dct[px * 576 + 64 * kk + c]);
  const float* wc = &Wl[c * 81];
  #pragma unroll
  for (int j = 0; j < 9; j++) {
    float a = 0.f;
    #pragma unroll
    for (int kk = 0; kk < 9; kk++) a += wc[j * 9 + kk] * v[kk];
    outb[px * 576 + 64 * j + c] = f2b(a);
  }
}

// ---------------- launch ----------------
extern "C" void kernel_launch(void* const* d_in, const int* in_sizes, int n_in,
                              void* d_out, int out_size, void* d_ws, size_t ws_size,
                              hipStream_t stream) {
  const float* x       = (const float*)d_in[0];
  const float* enc_dw  = (const float*)d_in[1];
  const float* enc_pw1 = (const float*)d_in[2];
  const float* enc_pw2 = (const float*)d_in[3];
  const float* dec_dw  = (const float*)d_in[4];
  const float* dec_pw1 = (const float*)d_in[5];
  const float* dec_pw2 = (const float*)d_in[6];
  const float* off_w1  = (const float*)d_in[7];
  const float* off_b1  = (const float*)d_in[8];
  const float* off_w2  = (const float*)d_in[9];
  const float* off_b2  = (const float*)d_in[10];
  const float* off_w3  = (const float*)d_in[11];
  const float* off_b3  = (const float*)d_in[12];
  const float* off_w4  = (const float*)d_in[13];
  const float* off_b4  = (const float*)d_in[14];
  const float* off_w5  = (const float*)d_in[15];
  const float* off_b5  = (const float*)d_in[16];
  const float* off_w6  = (const float*)d_in[17];
  const float* off_b6  = (const float*)d_in[18];
  const float* dct_w   = (const float*)d_in[19];
  const float* wie_w1  = (const float*)d_in[20];
  const float* wie_w2  = (const float*)d_in[21];
  const float* wie_w3  = (const float*)d_in[22];
  const float* wie_w4  = (const float*)d_in[23];
  const float* wie_w5  = (const float*)d_in[24];
  const float* wie_w6  = (const float*)d_in[25];
  const float* inv_w1  = (const float*)d_in[26];
  const float* inv_w2  = (const float*)d_in[27];
  float* outp = (float*)d_out;

  const size_t NP = (size_t)Bp * HWp;
  const size_t REQ_FLOATS = NP * 64 + NP * 64 + NP * 128 +
                            2 * (size_t)HWp * CKp + (size_t)HWp * CKp;
  if (ws_size < REQ_FLOATS * sizeof(float)) return;

  float* ws  = (float*)d_ws;
  float* x1  = ws;                       // mid (dec input NCHW, via gemm OUT=2)
  float* t0  = x1 + NP * 64;             // enc/dec dw7 tmp / offs + weights
  float* t1  = t0 + NP * 64;             // xnAll + oA/oB
  float* bigA = t1 + NP * 128;           // R1 / e1 (pw intermediate)
  float* bigB = bigA + (size_t)HWp * CKp;  // R2 / dec dw7 tmp
  float* bigC = bigB + (size_t)HWp * CKp;  // R3
  ushortt* R1 = (ushortt*)bigA;
  ushortt* R2 = (ushortt*)bigB;
  ushortt* R3 = (ushortt*)bigC;
  ushortt* e1 = (ushortt*)bigA;          // NP*128 ushorts (pw1 output)

  // weight region in t0 after the offset maps (NP*18 floats)
  float* wreg = t0 + NP * 18;
  ushortt* wb  = (ushortt*)wreg;            // 3 x [640][576]
  ushortt* wbi2 = wb + 3 * 640 * 576;       // [64][576]
  ushortt* wdwb = wbi2 + 64 * 576;          // 3 x [9][576] bf16
  ushortt* wc1  = wdwb + 3 * 5184;          // [1][64][64]
  ushortt* wc2  = wc1 + 4096;               // 4 x [9][64][64]
  ushortt* wpw  = wc2 + 4 * 36864;          // 4 x 8192 (enc_pw1, enc_pw2, dec_pw1, dec_pw2)

  ushortt* xnAll = (ushortt*)t1;
  ushortt* oA = xnAll + NP * 64;
  ushortt* oB = oA + NP * 64;

  float* offs = t0;
  float* mid  = x1;

  dim3 blk(256);

  // ---- enc ConvNeXt: dw7 fp32, pw via bf16 MFMA ----
  dwconv7_lds<<<dim3(Hp / 2, Bp * Cp), blk, 0, stream>>>(x, enc_dw, t0);
  t64b<<<dim3(HWp / 64, Bp), blk, 0, stream>>>(t0, oA);   // dw7 out -> NHWC bf16

  // ---- weight repacks (t0 dw7-tmp consumed) ----
  rep576x3<<<dim3((640 * 576 + 255) / 256, 3), blk, 0, stream>>>(
      wie_w1, wie_w3, wie_w5, wb);
  repinv2<<<dim3((64 * 576 + 255) / 256), blk, 0, stream>>>(inv_w2, wbi2);
  repdw3<<<dim3((3 * 5184 + 255) / 256), blk, 0, stream>>>(wie_w2, wie_w4, wie_w6, wdwb);
  repw1<<<dim3(16), blk, 0, stream>>>(off_w1, wc1);
  repw9x4<<<dim3((36864 + 255) / 256, 4), blk, 0, stream>>>(
      off_w2, off_w3, off_w4, off_w5, wc2);
  reppw4<<<dim3(32, 4), blk, 0, stream>>>(enc_pw1, enc_pw2, dec_pw1, dec_pw2, wpw);

  pw_bf<64, 1, 0><<<dim3(NP / 128, 2), blk, 0, stream>>>(oA, wpw, nullptr, e1, 128);
  pw_bf<128, 0, 1><<<dim3(NP / 128, 1), blk, 0, stream>>>(e1, wpw + 8192, x, xnAll, 64);

  // ---- offset CNN (full batch, bf16 MFMA, NHWC) ----
  conv_bf<1><<<dim3(HWp / 64, Bp), blk, 0, stream>>>(xnAll, wc1, off_b1, oA);
  conv_bf<9><<<dim3(HWp / 64, Bp), blk, 0, stream>>>(oA, wc2,             off_b2, oB);
  conv_bf<9><<<dim3(HWp / 64, Bp), blk, 0, stream>>>(oB, wc2 + 36864,     off_b3, oA);
  conv_bf<9><<<dim3(HWp / 64, Bp), blk, 0, stream>>>(oA, wc2 + 2 * 36864, off_b4, oB);
  conv_bf<9><<<dim3(HWp / 64, Bp), blk, 0, stream>>>(oB, wc2 + 3 * 36864, off_b5, oA);
  off6_nhwc<<<dim3(NP / 256), blk, 0, stream>>>(oA, off_w6, off_b6, offs);

  // ---- 576-channel middle: 2 batches per pass ----
  for (int bp = 0; bp < 2; bp++) {
    const ushortt* xn0 = xnAll + (size_t)(2 * bp) * HWp * 64;
    const float* off0 = offs + (size_t)(2 * bp) * 18 * HWp;
    float* mid0 = mid + (size_t)(2 * bp) * 64 * HWp;

    deform_dct<<<dim3(HWp / 4, 2), blk, 0, stream>>>(xn0, off0, dct_w, R1, R2);
    gemm_bf16<1><<<dim3(9, 256), blk, 0, stream>>>(R1, wb, R3);
    dw3x3_v2<1><<<dim3(43, 32, 2), blk, 0, stream>>>(R3, wdwb, R1);
    gemm_bf16<1><<<dim3(9, 256), blk, 0, stream>>>(R1, wb + 640 * 576, R3);
    dw3x3_v2<1><<<dim3(43, 32, 2), blk, 0, stream>>>(R3, wdwb + 5184, R1);
    gemm_bf16<1><<<dim3(9, 256), blk, 0, stream>>>(R1, wb + 2 * 640 * 576, R3);
    dw3x3_v2<2><<<dim3(43, 32, 2), blk, 0, stream>>>(R3, wdwb + 2 * 5184, R1);
    g9inv<<<dim3(2 * HWp / 4), blk, 0, stream>>>(R1, R2, inv_w1, R3);
    gemm_bf16<2><<<dim3(1, 256), blk, 0, stream>>>(R3, wbi2, mid0);
  }

  // ---- dec ConvNeXt: dw7 fp32 (tmp in bigB), pw via bf16 MFMA ----
  dwconv7_lds<<<dim3(Hp / 2, Bp * Cp), blk, 0, stream>>>(mid, dec_dw, bigB);
  t64b<<<dim3(HWp / 64, Bp), blk, 0, stream>>>(bigB, oA);
  pw_bf<64, 1, 0><<<dim3(NP / 128, 2), blk, 0, stream>>>(oA, wpw + 2 * 8192, nullptr, e1, 128);
  pw_bf<128, 0, 2><<<dim3(NP / 128, 1), blk, 0, stream>>>(e1, wpw + 3 * 8192, mid, outp, 64);
}

// Round 9
// 931.037 us; speedup vs baseline: 4.3069x; 1.1417x over previous
//
#include <hip/hip_runtime.h>
#include <math.h>

#define HWp 16384
#define Wp 128
#define Hp 128
#define Bp 4
#define Cp 64
#define CKp 576

typedef unsigned int u32;
typedef unsigned short ushortt;
typedef __attribute__((ext_vector_type(8))) short short8;
typedef __attribute__((ext_vector_type(4))) float float4v;

__device__ __forceinline__ ushortt f2b(float f) {
  union { float f; u32 u; } x; x.f = f;
  u32 r = x.u + 0x7fff + ((x.u >> 16) & 1);
  return (ushortt)(r >> 16);
}
__device__ __forceinline__ float b2f(ushortt h) {
  union { u32 u; float f; } x; x.u = ((u32)h) << 16; return x.f;
}
__device__ __forceinline__ float blo(u32 t) {
  union { u32 u; float f; } x; x.u = t << 16; return x.f;
}
__device__ __forceinline__ float bhi(u32 t) {
  union { u32 u; float f; } x; x.u = t & 0xffff0000u; return x.f;
}
__device__ __forceinline__ void gll(const ushortt* g, ushortt* l) {
  __builtin_amdgcn_global_load_lds(
      (const __attribute__((address_space(1))) u32*)g,
      (__attribute__((address_space(3))) u32*)l, 16, 0, 0);
}

// ---------------- depthwise 7x7, pad 3, LDS-tiled (NCHW) ----------------
__global__ __launch_bounds__(256)
void dwconv7_lds(const float* __restrict__ in, const float* __restrict__ w,
                 float* __restrict__ out) {
  int bc = blockIdx.y;
  int tid = threadIdx.x;
  int y0 = blockIdx.x * 2;
  __shared__ float ws[49];
  __shared__ float tile[8][136];
  if (tid < 49) ws[tid] = w[(bc & 63) * 49 + tid];
  if (tid < 48) {
    int r = tid / 6, cc = tid % 6;
    tile[r][cc < 3 ? cc : 128 + cc] = 0.f;
  }
  const float* ip = in + (size_t)bc * HWp;
  #pragma unroll
  for (int i = 0; i < 4; i++) {
    int idx = tid + 256 * i;
    int r = idx >> 7, xx = idx & 127;
    int yy = y0 - 3 + r;
    tile[r][xx + 3] = (yy >= 0 && yy < Hp) ? ip[yy * Wp + xx] : 0.f;
  }
  __syncthreads();
  int ty = tid >> 7, x = tid & 127;
  float acc = 0.f;
  #pragma unroll
  for (int dy = 0; dy < 7; dy++)
    #pragma unroll
    for (int dx = 0; dx < 7; dx++)
      acc += tile[ty + dy][x + dx] * ws[dy * 7 + dx];
  out[(size_t)bc * HWp + (y0 + ty) * Wp + x] = acc;
}

// ---------------- bf16 MFMA pointwise conv (enc/dec ConvNeXt pw) ----------------
template<int CIN, int ACT, int MODE>
__global__ __launch_bounds__(256)
void pw_bf(const ushortt* __restrict__ in, const ushortt* __restrict__ wt,
           const float* __restrict__ resid, void* __restrict__ outv, int Cout) {
  int tid = threadIdx.x;
  int wid = tid >> 6, lane = tid & 63;
  int q = lane >> 4, m = lane & 15;
  int px0 = blockIdx.x * 128, co0 = blockIdx.y * 64;
  int pxh = (wid & 1) * 64, coh = (wid >> 1) * 32;
  float4v acc[4][2];
  #pragma unroll
  for (int i = 0; i < 4; i++)
    #pragma unroll
    for (int j = 0; j < 2; j++) acc[i][j] = (float4v){0.f, 0.f, 0.f, 0.f};

  #pragma unroll
  for (int k0 = 0; k0 < CIN; k0 += 32) {
    short8 a[4], b[2];
    #pragma unroll
    for (int j = 0; j < 2; j++)
      b[j] = *(const short8*)&wt[(size_t)(co0 + coh + j * 16 + m) * CIN + k0 + q * 8];
    #pragma unroll
    for (int i = 0; i < 4; i++)
      a[i] = *(const short8*)&in[(size_t)(px0 + pxh + i * 16 + m) * CIN + k0 + q * 8];
    #pragma unroll
    for (int i = 0; i < 4; i++)
      #pragma unroll
      for (int j = 0; j < 2; j++)
        acc[i][j] = __builtin_amdgcn_mfma_f32_16x16x32_bf16(a[i], b[j], acc[i][j], 0, 0, 0);
  }

  #pragma unroll
  for (int j = 0; j < 2; j++) {
    int co = co0 + coh + j * 16 + m;
    #pragma unroll
    for (int i = 0; i < 4; i++) {
      int pxb = px0 + pxh + i * 16 + q * 4;
      int bl = pxb >> 14, pim = pxb & 16383;
      if (MODE == 0) {
        #pragma unroll
        for (int r = 0; r < 4; r++) {
          float v = acc[i][j][r];
          if (ACT == 1) v = fmaxf(v, 0.f);
          ((ushortt*)outv)[(size_t)(pxb + r) * Cout + co] = f2b(v);
        }
      } else {
        float4 rr = *(const float4*)&resid[(size_t)(bl * 64 + co) * HWp + pim];
        float v0 = acc[i][j][0] + rr.x, v1 = acc[i][j][1] + rr.y;
        float v2 = acc[i][j][2] + rr.z, v3 = acc[i][j][3] + rr.w;
        if (MODE == 1) {
          ushortt* ob = (ushortt*)outv;
          ob[(size_t)(pxb + 0) * 64 + co] = f2b(v0);
          ob[(size_t)(pxb + 1) * 64 + co] = f2b(v1);
          ob[(size_t)(pxb + 2) * 64 + co] = f2b(v2);
          ob[(size_t)(pxb + 3) * 64 + co] = f2b(v3);
        } else {
          float4 w4; w4.x = v0; w4.y = v1; w4.z = v2; w4.w = v3;
          *(float4*)&((float*)outv)[(size_t)(bl * 64 + co) * HWp + pim] = w4;
        }
      }
    }
  }
}

// ---------------- plain-bf16 MFMA conv (1x1 or 3x3 pad1), NHWC 64ch ----------------
template<int TAPS>
__global__ __launch_bounds__(256)
void conv_bf(const ushortt* __restrict__ in, const ushortt* __restrict__ wt,
             const float* __restrict__ bias, ushortt* __restrict__ out) {
  int tid = threadIdx.x;
  int wid = tid >> 6, lane = tid & 63;
  int q = lane >> 4, m = lane & 15;
  int bx = blockIdx.x, b = blockIdx.y;
  int y = bx >> 1;
  int c0 = ((bx & 1) << 6) + ((wid & 1) << 5);
  int coW = (wid >> 1) << 5;
  size_t ibase = (size_t)b * HWp;

  float4v acc[2][2];
  #pragma unroll
  for (int i = 0; i < 2; i++)
    #pragma unroll
    for (int j = 0; j < 2; j++) acc[i][j] = (float4v){0.f, 0.f, 0.f, 0.f};
  short8 zz = {0, 0, 0, 0, 0, 0, 0, 0};

  #pragma unroll
  for (int k = 0; k < TAPS; k++) {
    int dy = (TAPS == 9) ? (k / 3 - 1) : 0;
    int dx = (TAPS == 9) ? (k % 3 - 1) : 0;
    int yy = y + dy;
    if (TAPS == 9 && (yy < 0 || yy >= Hp)) continue;
    #pragma unroll
    for (int ch = 0; ch < 2; ch++) {
      int ci0 = ch * 32 + q * 8;
      short8 bfr[2], afr[2];
      #pragma unroll
      for (int j = 0; j < 2; j++)
        bfr[j] = *(const short8*)&wt[(size_t)(k * 64 + coW + j * 16 + m) * 64 + ci0];
      #pragma unroll
      for (int i = 0; i < 2; i++) {
        int col = c0 + i * 16 + m + dx;
        bool vld = (TAPS == 1) || ((unsigned)col < (unsigned)Wp);
        int colc = min(max(col, 0), Wp - 1);
        short8 h = *(const short8*)&in[(ibase + (size_t)yy * Wp + colc) * 64 + ci0];
        afr[i] = vld ? h : zz;
      }
      #pragma unroll
      for (int i = 0; i < 2; i++)
        #pragma unroll
        for (int j = 0; j < 2; j++)
          acc[i][j] = __builtin_amdgcn_mfma_f32_16x16x32_bf16(afr[i], bfr[j], acc[i][j], 0, 0, 0);
    }
  }

  #pragma unroll
  for (int j = 0; j < 2; j++) {
    int co = coW + j * 16 + m;
    float bv = bias[co];
    #pragma unroll
    for (int i = 0; i < 2; i++) {
      #pragma unroll
      for (int r = 0; r < 4; r++) {
        size_t px = ibase + (size_t)y * Wp + c0 + i * 16 + q * 4 + r;
        float v = acc[i][j][r] + bv;
        v = v > 0.f ? v : 0.1f * v;
        out[px * 64 + co] = f2b(v);
      }
    }
  }
}

// ---------------- NCHW fp32 -> NHWC bf16 (full batch) ----------------
__global__ __launch_bounds__(256)
void t64b(const float* __restrict__ in, ushortt* __restrict__ out) {
  __shared__ float tl[64 * 65];
  int tid = threadIdx.x;
  int b = blockIdx.y;
  int px0 = blockIdx.x * 64;
  int lpx = tid & 63, c4 = tid >> 6;
  const float* ip = in + (size_t)b * 64 * HWp;
  #pragma unroll
  for (int i = 0; i < 16; i++) {
    int c = c4 + 4 * i;
    tl[lpx * 65 + c] = ip[(size_t)c * HWp + px0 + lpx];
  }
  __syncthreads();
  int ci = tid & 63, pr = tid >> 6;
  #pragma unroll
  for (int i = 0; i < 16; i++) {
    int r = pr + 4 * i;
    out[((size_t)b * HWp + px0 + r) * 64 + ci] = f2b(tl[r * 65 + ci]);
  }
}

// ---------------- weight repacks ----------------
__global__ __launch_bounds__(256)
void repw1(const float* __restrict__ in, ushortt* __restrict__ out) {
  int idx = blockIdx.x * 256 + threadIdx.x;
  if (idx >= 4096) return;
  out[idx] = f2b(in[idx]);
}
__global__ __launch_bounds__(256)
void repw9x4(const float* __restrict__ s0, const float* __restrict__ s1,
             const float* __restrict__ s2, const float* __restrict__ s3,
             ushortt* __restrict__ dst) {
  int which = blockIdx.y;
  const float* in = which == 0 ? s0 : which == 1 ? s1 : which == 2 ? s2 : s3;
  int idx = blockIdx.x * 256 + threadIdx.x;
  if (idx >= 36864) return;
  int k = idx >> 12, r = idx & 4095;
  int co = r >> 6, ci = r & 63;
  dst[which * 36864 + idx] = f2b(in[(size_t)(co * 64 + ci) * 9 + k]);
}
__global__ __launch_bounds__(256)
void rep576x3(const float* __restrict__ s0, const float* __restrict__ s1,
              const float* __restrict__ s2, ushortt* __restrict__ dst) {
  int which = blockIdx.y;
  const float* in = which == 0 ? s0 : which == 1 ? s1 : s2;
  int idx = blockIdx.x * 256 + threadIdx.x;
  if (idx >= 640 * 576) return;
  int cop = idx / 576, cip = idx % 576;
  ushortt v = 0;
  if (cop < 576) {
    int co = (cop & 63) * 9 + (cop >> 6);
    int ci = (cip & 63) * 9 + (cip >> 6);
    v = f2b(in[(size_t)co * 576 + ci]);
  }
  dst[(size_t)which * 640 * 576 + idx] = v;
}
__global__ __launch_bounds__(256)
void repinv2(const float* __restrict__ in, ushortt* __restrict__ out) {
  int idx = blockIdx.x * 256 + threadIdx.x;
  if (idx >= 64 * 576) return;
  int co = idx / 576, cip = idx % 576;
  int ci = (cip & 63) * 9 + (cip >> 6);
  out[idx] = f2b(in[(size_t)co * 576 + ci]);
}
__global__ __launch_bounds__(256)
void repdw3(const float* __restrict__ s0, const float* __restrict__ s1,
            const float* __restrict__ s2, ushortt* __restrict__ dst) {
  int idx = blockIdx.x * 256 + threadIdx.x;
  if (idx >= 3 * 5184) return;
  int which = idx / 5184, r = idx % 5184;
  const float* in = which == 0 ? s0 : which == 1 ? s1 : s2;
  int tap = r / 576, chp = r % 576;
  int ch = (chp & 63) * 9 + (chp >> 6);
  dst[idx] = f2b(in[ch * 9 + tap]);
}
__global__ __launch_bounds__(256)
void reppw4(const float* __restrict__ s0, const float* __restrict__ s1,
            const float* __restrict__ s2, const float* __restrict__ s3,
            ushortt* __restrict__ dst) {
  int which = blockIdx.y;
  const float* in = which == 0 ? s0 : which == 1 ? s1 : which == 2 ? s2 : s3;
  int idx = blockIdx.x * 256 + threadIdx.x;
  if (idx >= 8192) return;
  dst[which * 8192 + idx] = f2b(in[idx]);
}

// ---------------- off_w6 -> NCHW offsets, 8*tanh ----------------
__global__ __launch_bounds__(256)
void off6_nhwc(const ushortt* __restrict__ hi, const float* __restrict__ wgt,
               const float* __restrict__ bias, float* __restrict__ out) {
  __shared__ float Wl[18 * 64];
  for (int i = threadIdx.x; i < 18 * 64; i += 256) Wl[i] = wgt[i];
  __syncthreads();
  int px = blockIdx.x * 256 + threadIdx.x;
  int b = px >> 14, pim = px & 16383;
  float acc[18];
  #pragma unroll
  for (int j = 0; j < 18; j++) acc[j] = 0.f;
  const uint4* ph = (const uint4*)(hi + (size_t)px * 64);
  for (int g = 0; g < 8; g++) {
    uint4 H = ph[g];
    u32 hw[4] = {H.x, H.y, H.z, H.w};
    #pragma unroll
    for (int t = 0; t < 4; t++) {
      float v0 = blo(hw[t]);
      float v1 = bhi(hw[t]);
      int ci = g * 8 + t * 2;
      #pragma unroll
      for (int j = 0; j < 18; j++)
        acc[j] += Wl[j * 64 + ci] * v0 + Wl[j * 64 + ci + 1] * v1;
    }
  }
  #pragma unroll
  for (int j = 0; j < 18; j++)
    out[((size_t)b * 18 + j) * HWp + pim] = 8.f * tanhf(acc[j] + bias[j]);
}

// ---------------- fused deform + dct (2 batches per dispatch) ----------------
__global__ __launch_bounds__(256)
void deform_dct(const ushortt* __restrict__ xn0, const float* __restrict__ offs0,
                const float* __restrict__ w9, ushortt* __restrict__ xb,
                ushortt* __restrict__ dctb) {
  __shared__ float Wl[5184];
  for (int i = threadIdx.x; i < 5184; i += 256) Wl[i] = w9[i];
  __syncthreads();
  int bl = blockIdx.y;
  const ushortt* xn = xn0 + (size_t)bl * HWp * 64;
  const float* offs = offs0 + (size_t)bl * 18 * HWp;
  int wid = threadIdx.x >> 6, lane = threadIdx.x & 63;
  int p = blockIdx.x * 4 + wid;
  int yi = p >> 7, xi = p & 127;
  size_t pg = (size_t)bl * HWp + p;
  float v[9];
  #pragma unroll
  for (int k = 0; k < 9; k++) {
    float dy = offs[(size_t)(2 * k) * HWp + p];
    float dx = offs[(size_t)(2 * k + 1) * HWp + p];
    float py = (float)yi + (float)(k / 3 - 1) + dy;
    float px = (float)xi + (float)(k % 3 - 1) + dx;
    float y0f = floorf(py), x0f = floorf(px);
    float wy1 = py - y0f, wy0 = 1.f - wy1;
    float wx1 = px - x0f, wx0 = 1.f - wx1;
    int y0 = (int)y0f, x0 = (int)x0f;
    bool vy0 = (y0 >= 0 && y0 < Hp), vy1 = (y0 + 1 >= 0 && y0 + 1 < Hp);
    bool vx0 = (x0 >= 0 && x0 < Wp), vx1 = (x0 + 1 >= 0 && x0 + 1 < Wp);
    int yc0 = min(max(y0, 0), Hp - 1), yc1 = min(max(y0 + 1, 0), Hp - 1);
    int xc0 = min(max(x0, 0), Wp - 1), xc1 = min(max(x0 + 1, 0), Wp - 1);
    float w00 = wy0 * wx0 * ((vy0 && vx0) ? 1.f : 0.f);
    float w01 = wy0 * wx1 * ((vy0 && vx1) ? 1.f : 0.f);
    float w10 = wy1 * wx0 * ((vy1 && vx0) ? 1.f : 0.f);
    float w11 = wy1 * wx1 * ((vy1 && vx1) ? 1.f : 0.f);
    float v00 = b2f(xn[(size_t)(yc0 * Wp + xc0) * 64 + lane]);
    float v01 = b2f(xn[(size_t)(yc0 * Wp + xc1) * 64 + lane]);
    float v10 = b2f(xn[(size_t)(yc1 * Wp + xc0) * 64 + lane]);
    float v11 = b2f(xn[(size_t)(yc1 * Wp + xc1) * 64 + lane]);
    v[k] = v00 * w00 + v01 * w01 + v10 * w10 + v11 * w11;
    xb[pg * 576 + 64 * k + lane] = f2b(v[k]);
  }
  const float* wc = &Wl[lane * 81];
  #pragma unroll
  for (int j = 0; j < 9; j++) {
    float a = 0.f;
    #pragma unroll
    for (int kk = 0; kk < 9; kk++) a += wc[j * 9 + kk] * v[kk];
    dctb[pg * 576 + 64 * j + lane] = f2b(a);
  }
}

// ---------------- MFMA bf16 GEMM, 64-co tiles, 2-batch px range ----------------
// OUT 1: grid (9, 256), XCD-partitioned px slices; OUT 2: grid (1, 256).
// XOR LDS swizzle: stage k-chunk (tid&3)^((tid>>3)&3); read chunk q^((m>>1)&3).
template<int OUT>
__global__ __launch_bounds__(256)
void gemm_bf16(const ushortt* __restrict__ X, const ushortt* __restrict__ Wb,
               void* __restrict__ outv) {
  __shared__ ushortt Xs[128 * 32];
  __shared__ ushortt Wsh[64 * 32];
  int tid = threadIdx.x;
  int lin = blockIdx.x + blockIdx.y * gridDim.x;
  int px_t, co_t;
  if (OUT == 1) {
    // 2304 blocks; XCD lin&7 owns px-tiles [xcd*32, xcd*32+32), co fastest
    int xcd = lin & 7, loc = lin >> 3;
    co_t = loc % 9;
    px_t = xcd * 32 + loc / 9;
  } else {
    co_t = 0;
    px_t = lin;
  }
  int co0 = co_t * 64, px0 = px_t * 128;
  int srow = tid >> 2;
  int sch = (tid & 3) ^ ((tid >> 3) & 3);      // swizzled k-chunk for staging
  size_t gxo0 = (size_t)(px0 + srow) * 576 + sch * 8;
  size_t gxo1 = gxo0 + (size_t)64 * 576;
  size_t gwo  = (size_t)(co0 + srow) * 576 + sch * 8;
  int wid = tid >> 6, lane = tid & 63;
  int q = lane >> 4, m = lane & 15;
  int qx = (q ^ ((m >> 1) & 3)) * 8;           // swizzled read column
  int pxh = (wid & 1) * 64, coh = (wid >> 1) * 32;
  float4v acc[4][2];
  #pragma unroll
  for (int i = 0; i < 4; i++)
    #pragma unroll
    for (int j = 0; j < 2; j++) acc[i][j] = (float4v){0.f, 0.f, 0.f, 0.f};

  for (int k0 = 0; k0 < 576; k0 += 32) {
    __syncthreads();
    gll(X + gxo0 + k0,  &Xs[tid * 8]);
    gll(X + gxo1 + k0,  &Xs[2048 + tid * 8]);
    gll(Wb + gwo + k0,  &Wsh[tid * 8]);
    __syncthreads();
    short8 a[4], b[2];
    #pragma unroll
    for (int i = 0; i < 4; i++)
      a[i] = *(const short8*)&Xs[(pxh + i * 16 + m) * 32 + qx];
    #pragma unroll
    for (int j = 0; j < 2; j++)
      b[j] = *(const short8*)&Wsh[(coh + j * 16 + m) * 32 + qx];
    #pragma unroll
    for (int i = 0; i < 4; i++)
      #pragma unroll
      for (int j = 0; j < 2; j++)
        acc[i][j] = __builtin_amdgcn_mfma_f32_16x16x32_bf16(a[i], b[j], acc[i][j], 0, 0, 0);
  }

  #pragma unroll
  for (int j = 0; j < 2; j++) {
    int co = co0 + coh + j * 16 + m;
    #pragma unroll
    for (int i = 0; i < 4; i++) {
      int pxb = px0 + pxh + i * 16 + q * 4;
      if (OUT == 2) {
        int bl = pxb >> 14, pim = pxb & 16383;
        float4 r;
        r.x = acc[i][j][0]; r.y = acc[i][j][1];
        r.z = acc[i][j][2]; r.w = acc[i][j][3];
        *(float4*)&((float*)outv)[(size_t)(bl * 64 + co) * HWp + pim] = r;
      } else {
        #pragma unroll
        for (int r = 0; r < 4; r++)
          ((ushortt*)outv)[(size_t)(pxb + r) * 576 + co] = f2b(acc[i][j][r]);
      }
    }
  }
}

// ---------------- depthwise 3x3 NHWC bf16 v2: 8ch x 4-row column per thread ----------------
template<int ACT>
__global__ __launch_bounds__(256)
void dw3x3_v2(const ushortt* __restrict__ in, const ushortt* __restrict__ wt,
              ushortt* __restrict__ out) {
  int tid = threadIdx.x;
  int pxl = tid / 72;
  int g = tid - pxl * 72;
  if (pxl >= 3) return;
  int x = blockIdx.x * 3 + pxl;
  if (x >= Wp) return;
  int y0 = blockIdx.y * 4;
  size_t bbase = (size_t)blockIdx.z * HWp;

  float w[9][8];
  #pragma unroll
  for (int t = 0; t < 9; t++) {
    uint4 wv = *(const uint4*)&wt[t * 576 + g * 8];
    u32 wsw[4] = {wv.x, wv.y, wv.z, wv.w};
    #pragma unroll
    for (int p = 0; p < 4; p++) {
      w[t][2 * p]     = blo(wsw[p]);
      w[t][2 * p + 1] = bhi(wsw[p]);
    }
  }
  float acc[4][8];
  #pragma unroll
  for (int o = 0; o < 4; o++)
    #pragma unroll
    for (int c = 0; c < 8; c++) acc[o][c] = 0.f;

  #pragma unroll
  for (int ri = 0; ri < 6; ri++) {
    int yy = y0 - 1 + ri;
    bool vr = (yy >= 0 && yy < Hp);
    float v[3][8];
    #pragma unroll
    for (int dx = 0; dx < 3; dx++) {
      int xx = x + dx - 1;
      uint4 t4 = {0, 0, 0, 0};
      if (vr && xx >= 0 && xx < Wp)
        t4 = *(const uint4*)&in[(bbase + (size_t)yy * Wp + xx) * 576 + g * 8];
      u32 tw[4] = {t4.x, t4.y, t4.z, t4.w};
      #pragma unroll
      for (int p = 0; p < 4; p++) {
        v[dx][2 * p]     = blo(tw[p]);
        v[dx][2 * p + 1] = bhi(tw[p]);
      }
    }
    #pragma unroll
    for (int o = 0; o < 4; o++) {
      int dy = ri - o;
      if (dy < 0 || dy > 2) continue;
      #pragma unroll
      for (int dx = 0; dx < 3; dx++)
        #pragma unroll
        for (int c = 0; c < 8; c++)
          acc[o][c] += w[dy * 3 + dx][c] * v[dx][c];
    }
  }

  #pragma unroll
  for (int o = 0; o < 4; o++) {
    int yy = y0 + o;
    u32 pk[4];
    #pragma unroll
    for (int p = 0; p < 4; p++) {
      float r0 = acc[o][2 * p], r1 = acc[o][2 * p + 1];
      if (ACT == 1) { r0 = fmaxf(r0, 0.f); r1 = fmaxf(r1, 0.f); }
      else { r0 = 1.f / (1.f + __expf(-r0)); r1 = 1.f / (1.f + __expf(-r1)); }
      pk[p] = (u32)f2b(r0) | (((u32)f2b(r1)) << 16);
    }
    uint4 o4; o4.x = pk[0]; o4.y = pk[1]; o4.z = pk[2]; o4.w = pk[3];
    *(uint4*)&out[(bbase + (size_t)yy * Wp + x) * 576 + g * 8] = o4;
  }
}

// ---------------- group 9->9 inv1, fused wiener*dct (2 batches, bf16) ----------------
__global__ __launch_bounds__(256)
void g9inv(const ushortt* __restrict__ wien, const ushortt* __restrict__ dct,
           const float* __restrict__ w9, ushortt* __restrict__ outb) {
  __shared__ float Wl[5184];
  for (int i = threadIdx.x; i < 5184; i += 256) Wl[i] = w9[i];
  __syncthreads();
  int c = threadIdx.x & 63, pxl = threadIdx.x >> 6;
  size_t px = (size_t)blockIdx.x * 4 + pxl;
  float v[9];
  #pragma unroll
  for (int kk = 0; kk < 9; kk++)
    v[kk] = b2f(wien[px * 576 + 64 * kk + c]) * b2f(dct[px * 576 + 64 * kk + c]);
  const float* wc = &Wl[c * 81];
  #pragma unroll
  for (int j = 0; j < 9; j++) {
    float a = 0.f;
    #pragma unroll
    for (int kk = 0; kk < 9; kk++) a += wc[j * 9 + kk] * v[kk];
    outb[px * 576 + 64 * j + c] = f2b(a);
  }
}

// ---------------- launch ----------------
extern "C" void kernel_launch(void* const* d_in, const int* in_sizes, int n_in,
                              void* d_out, int out_size, void* d_ws, size_t ws_size,
                              hipStream_t stream) {
  const float* x       = (const float*)d_in[0];
  const float* enc_dw  = (const float*)d_in[1];
  const float* enc_pw1 = (const float*)d_in[2];
  const float* enc_pw2 = (const float*)d_in[3];
  const float* dec_dw  = (const float*)d_in[4];
  const float* dec_pw1 = (const float*)d_in[5];
  const float* dec_pw2 = (const float*)d_in[6];
  const float* off_w1  = (const float*)d_in[7];
  const float* off_b1  = (const float*)d_in[8];
  const float* off_w2  = (const float*)d_in[9];
  const float* off_b2  = (const float*)d_in[10];
  const float* off_w3  = (const float*)d_in[11];
  const float* off_b3  = (const float*)d_in[12];
  const float* off_w4  = (const float*)d_in[13];
  const float* off_b4  = (const float*)d_in[14];
  const float* off_w5  = (const float*)d_in[15];
  const float* off_b5  = (const float*)d_in[16];
  const float* off_w6  = (const float*)d_in[17];
  const float* off_b6  = (const float*)d_in[18];
  const float* dct_w   = (const float*)d_in[19];
  const float* wie_w1  = (const float*)d_in[20];
  const float* wie_w2  = (const float*)d_in[21];
  const float* wie_w3  = (const float*)d_in[22];
  const float* wie_w4  = (const float*)d_in[23];
  const float* wie_w5  = (const float*)d_in[24];
  const float* wie_w6  = (const float*)d_in[25];
  const float* inv_w1  = (const float*)d_in[26];
  const float* inv_w2  = (const float*)d_in[27];
  float* outp = (float*)d_out;

  const size_t NP = (size_t)Bp * HWp;
  const size_t REQ_FLOATS = NP * 64 + NP * 64 + NP * 128 +
                            2 * (size_t)HWp * CKp + (size_t)HWp * CKp;
  if (ws_size < REQ_FLOATS * sizeof(float)) return;

  float* ws  = (float*)d_ws;
  float* x1  = ws;
  float* t0  = x1 + NP * 64;
  float* t1  = t0 + NP * 64;
  float* bigA = t1 + NP * 128;
  float* bigB = bigA + (size_t)HWp * CKp;
  float* bigC = bigB + (size_t)HWp * CKp;
  ushortt* R1 = (ushortt*)bigA;
  ushortt* R2 = (ushortt*)bigB;
  ushortt* R3 = (ushortt*)bigC;
  ushortt* e1 = (ushortt*)bigA;

  float* wreg = t0 + NP * 18;
  ushortt* wb  = (ushortt*)wreg;
  ushortt* wbi2 = wb + 3 * 640 * 576;
  ushortt* wdwb = wbi2 + 64 * 576;
  ushortt* wc1  = wdwb + 3 * 5184;
  ushortt* wc2  = wc1 + 4096;
  ushortt* wpw  = wc2 + 4 * 36864;

  ushortt* xnAll = (ushortt*)t1;
  ushortt* oA = xnAll + NP * 64;
  ushortt* oB = oA + NP * 64;

  float* offs = t0;
  float* mid  = x1;

  dim3 blk(256);

  // ---- enc ConvNeXt: dw7 fp32, pw via bf16 MFMA ----
  dwconv7_lds<<<dim3(Hp / 2, Bp * Cp), blk, 0, stream>>>(x, enc_dw, t0);
  t64b<<<dim3(HWp / 64, Bp), blk, 0, stream>>>(t0, oA);

  // ---- weight repacks ----
  rep576x3<<<dim3((640 * 576 + 255) / 256, 3), blk, 0, stream>>>(
      wie_w1, wie_w3, wie_w5, wb);
  repinv2<<<dim3((64 * 576 + 255) / 256), blk, 0, stream>>>(inv_w2, wbi2);
  repdw3<<<dim3((3 * 5184 + 255) / 256), blk, 0, stream>>>(wie_w2, wie_w4, wie_w6, wdwb);
  repw1<<<dim3(16), blk, 0, stream>>>(off_w1, wc1);
  repw9x4<<<dim3((36864 + 255) / 256, 4), blk, 0, stream>>>(
      off_w2, off_w3, off_w4, off_w5, wc2);
  reppw4<<<dim3(32, 4), blk, 0, stream>>>(enc_pw1, enc_pw2, dec_pw1, dec_pw2, wpw);

  pw_bf<64, 1, 0><<<dim3(NP / 128, 2), blk, 0, stream>>>(oA, wpw, nullptr, e1, 128);
  pw_bf<128, 0, 1><<<dim3(NP / 128, 1), blk, 0, stream>>>(e1, wpw + 8192, x, xnAll, 64);

  // ---- offset CNN (full batch, bf16 MFMA, NHWC) ----
  conv_bf<1><<<dim3(HWp / 64, Bp), blk, 0, stream>>>(xnAll, wc1, off_b1, oA);
  conv_bf<9><<<dim3(HWp / 64, Bp), blk, 0, stream>>>(oA, wc2,             off_b2, oB);
  conv_bf<9><<<dim3(HWp / 64, Bp), blk, 0, stream>>>(oB, wc2 + 36864,     off_b3, oA);
  conv_bf<9><<<dim3(HWp / 64, Bp), blk, 0, stream>>>(oA, wc2 + 2 * 36864, off_b4, oB);
  conv_bf<9><<<dim3(HWp / 64, Bp), blk, 0, stream>>>(oB, wc2 + 3 * 36864, off_b5, oA);
  off6_nhwc<<<dim3(NP / 256), blk, 0, stream>>>(oA, off_w6, off_b6, offs);

  // ---- 576-channel middle: 2 batches per pass ----
  for (int bp = 0; bp < 2; bp++) {
    const ushortt* xn0 = xnAll + (size_t)(2 * bp) * HWp * 64;
    const float* off0 = offs + (size_t)(2 * bp) * 18 * HWp;
    float* mid0 = mid + (size_t)(2 * bp) * 64 * HWp;

    deform_dct<<<dim3(HWp / 4, 2), blk, 0, stream>>>(xn0, off0, dct_w, R1, R2);
    gemm_bf16<1><<<dim3(9, 256), blk, 0, stream>>>(R1, wb, R3);
    dw3x3_v2<1><<<dim3(43, 32, 2), blk, 0, stream>>>(R3, wdwb, R1);
    gemm_bf16<1><<<dim3(9, 256), blk, 0, stream>>>(R1, wb + 640 * 576, R3);
    dw3x3_v2<1><<<dim3(43, 32, 2), blk, 0, stream>>>(R3, wdwb + 5184, R1);
    gemm_bf16<1><<<dim3(9, 256), blk, 0, stream>>>(R1, wb + 2 * 640 * 576, R3);
    dw3x3_v2<2><<<dim3(43, 32, 2), blk, 0, stream>>>(R3, wdwb + 2 * 5184, R1);
    g9inv<<<dim3(2 * HWp / 4), blk, 0, stream>>>(R1, R2, inv_w1, R3);
    gemm_bf16<2><<<dim3(1, 256), blk, 0, stream>>>(R3, wbi2, mid0);
  }

  // ---- dec ConvNeXt: dw7 fp32 (tmp in bigB), pw via bf16 MFMA ----
  dwconv7_lds<<<dim3(Hp / 2, Bp * Cp), blk, 0, stream>>>(mid, dec_dw, bigB);
  t64b<<<dim3(HWp / 64, Bp), blk, 0, stream>>>(bigB, oA);
  pw_bf<64, 1, 0><<<dim3(NP / 128, 2), blk, 0, stream>>>(oA, wpw + 2 * 8192, nullptr, e1, 128);
  pw_bf<128, 0, 2><<<dim3(NP / 128, 1), blk, 0, stream>>>(e1, wpw + 3 * 8192, mid, outp, 64);
}

// Round 11
// 928.200 us; speedup vs baseline: 4.3201x; 1.0031x over previous
//
#include <hip/hip_runtime.h>
#include <math.h>

#define HWp 16384
#define Wp 128
#define Hp 128
#define Bp 4
#define Cp 64
#define CKp 576

typedef unsigned int u32;
typedef unsigned short ushortt;
typedef __attribute__((ext_vector_type(8))) short short8;
typedef __attribute__((ext_vector_type(4))) float float4v;

__device__ __forceinline__ ushortt f2b(float f) {
  union { float f; u32 u; } x; x.f = f;
  u32 r = x.u + 0x7fff + ((x.u >> 16) & 1);
  return (ushortt)(r >> 16);
}
__device__ __forceinline__ float b2f(ushortt h) {
  union { u32 u; float f; } x; x.u = ((u32)h) << 16; return x.f;
}
__device__ __forceinline__ float blo(u32 t) {
  union { u32 u; float f; } x; x.u = t << 16; return x.f;
}
__device__ __forceinline__ float bhi(u32 t) {
  union { u32 u; float f; } x; x.u = t & 0xffff0000u; return x.f;
}
__device__ __forceinline__ void gll(const ushortt* g, ushortt* l) {
  __builtin_amdgcn_global_load_lds(
      (const __attribute__((address_space(1))) u32*)g,
      (__attribute__((address_space(3))) u32*)l, 16, 0, 0);
}

// ---------------- depthwise 7x7, pad 3, LDS-tiled (NCHW) ----------------
__global__ __launch_bounds__(256)
void dwconv7_lds(const float* __restrict__ in, const float* __restrict__ w,
                 float* __restrict__ out) {
  int bc = blockIdx.y;
  int tid = threadIdx.x;
  int y0 = blockIdx.x * 2;
  __shared__ float ws[49];
  __shared__ float tile[8][136];
  if (tid < 49) ws[tid] = w[(bc & 63) * 49 + tid];
  if (tid < 48) {
    int r = tid / 6, cc = tid % 6;
    tile[r][cc < 3 ? cc : 128 + cc] = 0.f;
  }
  const float* ip = in + (size_t)bc * HWp;
  #pragma unroll
  for (int i = 0; i < 4; i++) {
    int idx = tid + 256 * i;
    int r = idx >> 7, xx = idx & 127;
    int yy = y0 - 3 + r;
    tile[r][xx + 3] = (yy >= 0 && yy < Hp) ? ip[yy * Wp + xx] : 0.f;
  }
  __syncthreads();
  int ty = tid >> 7, x = tid & 127;
  float acc = 0.f;
  #pragma unroll
  for (int dy = 0; dy < 7; dy++)
    #pragma unroll
    for (int dx = 0; dx < 7; dx++)
      acc += tile[ty + dy][x + dx] * ws[dy * 7 + dx];
  out[(size_t)bc * HWp + (y0 + ty) * Wp + x] = acc;
}

// ---------------- bf16 MFMA pointwise conv (enc/dec ConvNeXt pw) ----------------
template<int CIN, int ACT, int MODE>
__global__ __launch_bounds__(256)
void pw_bf(const ushortt* __restrict__ in, const ushortt* __restrict__ wt,
           const float* __restrict__ resid, void* __restrict__ outv, int Cout) {
  int tid = threadIdx.x;
  int wid = tid >> 6, lane = tid & 63;
  int q = lane >> 4, m = lane & 15;
  int px0 = blockIdx.x * 128, co0 = blockIdx.y * 64;
  int pxh = (wid & 1) * 64, coh = (wid >> 1) * 32;
  float4v acc[4][2];
  #pragma unroll
  for (int i = 0; i < 4; i++)
    #pragma unroll
    for (int j = 0; j < 2; j++) acc[i][j] = (float4v){0.f, 0.f, 0.f, 0.f};

  #pragma unroll
  for (int k0 = 0; k0 < CIN; k0 += 32) {
    short8 a[4], b[2];
    #pragma unroll
    for (int j = 0; j < 2; j++)
      b[j] = *(const short8*)&wt[(size_t)(co0 + coh + j * 16 + m) * CIN + k0 + q * 8];
    #pragma unroll
    for (int i = 0; i < 4; i++)
      a[i] = *(const short8*)&in[(size_t)(px0 + pxh + i * 16 + m) * CIN + k0 + q * 8];
    #pragma unroll
    for (int i = 0; i < 4; i++)
      #pragma unroll
      for (int j = 0; j < 2; j++)
        acc[i][j] = __builtin_amdgcn_mfma_f32_16x16x32_bf16(a[i], b[j], acc[i][j], 0, 0, 0);
  }

  #pragma unroll
  for (int j = 0; j < 2; j++) {
    int co = co0 + coh + j * 16 + m;
    #pragma unroll
    for (int i = 0; i < 4; i++) {
      int pxb = px0 + pxh + i * 16 + q * 4;
      int bl = pxb >> 14, pim = pxb & 16383;
      if (MODE == 0) {
        #pragma unroll
        for (int r = 0; r < 4; r++) {
          float v = acc[i][j][r];
          if (ACT == 1) v = fmaxf(v, 0.f);
          ((ushortt*)outv)[(size_t)(pxb + r) * Cout + co] = f2b(v);
        }
      } else {
        float4 rr = *(const float4*)&resid[(size_t)(bl * 64 + co) * HWp + pim];
        float v0 = acc[i][j][0] + rr.x, v1 = acc[i][j][1] + rr.y;
        float v2 = acc[i][j][2] + rr.z, v3 = acc[i][j][3] + rr.w;
        if (MODE == 1) {
          ushortt* ob = (ushortt*)outv;
          ob[(size_t)(pxb + 0) * 64 + co] = f2b(v0);
          ob[(size_t)(pxb + 1) * 64 + co] = f2b(v1);
          ob[(size_t)(pxb + 2) * 64 + co] = f2b(v2);
          ob[(size_t)(pxb + 3) * 64 + co] = f2b(v3);
        } else {
          float4 w4; w4.x = v0; w4.y = v1; w4.z = v2; w4.w = v3;
          *(float4*)&((float*)outv)[(size_t)(bl * 64 + co) * HWp + pim] = w4;
        }
      }
    }
  }
}

// ---------------- plain-bf16 MFMA conv (1x1 or 3x3 pad1), NHWC 64ch ----------------
template<int TAPS>
__global__ __launch_bounds__(256)
void conv_bf(const ushortt* __restrict__ in, const ushortt* __restrict__ wt,
             const float* __restrict__ bias, ushortt* __restrict__ out) {
  int tid = threadIdx.x;
  int wid = tid >> 6, lane = tid & 63;
  int q = lane >> 4, m = lane & 15;
  int bx = blockIdx.x, b = blockIdx.y;
  int y = bx >> 1;
  int c0 = ((bx & 1) << 6) + ((wid & 1) << 5);
  int coW = (wid >> 1) << 5;
  size_t ibase = (size_t)b * HWp;

  float4v acc[2][2];
  #pragma unroll
  for (int i = 0; i < 2; i++)
    #pragma unroll
    for (int j = 0; j < 2; j++) acc[i][j] = (float4v){0.f, 0.f, 0.f, 0.f};
  short8 zz = {0, 0, 0, 0, 0, 0, 0, 0};

  #pragma unroll
  for (int k = 0; k < TAPS; k++) {
    int dy = (TAPS == 9) ? (k / 3 - 1) : 0;
    int dx = (TAPS == 9) ? (k % 3 - 1) : 0;
    int yy = y + dy;
    if (TAPS == 9 && (yy < 0 || yy >= Hp)) continue;
    #pragma unroll
    for (int ch = 0; ch < 2; ch++) {
      int ci0 = ch * 32 + q * 8;
      short8 bfr[2], afr[2];
      #pragma unroll
      for (int j = 0; j < 2; j++)
        bfr[j] = *(const short8*)&wt[(size_t)(k * 64 + coW + j * 16 + m) * 64 + ci0];
      #pragma unroll
      for (int i = 0; i < 2; i++) {
        int col = c0 + i * 16 + m + dx;
        bool vld = (TAPS == 1) || ((unsigned)col < (unsigned)Wp);
        int colc = min(max(col, 0), Wp - 1);
        short8 h = *(const short8*)&in[(ibase + (size_t)yy * Wp + colc) * 64 + ci0];
        afr[i] = vld ? h : zz;
      }
      #pragma unroll
      for (int i = 0; i < 2; i++)
        #pragma unroll
        for (int j = 0; j < 2; j++)
          acc[i][j] = __builtin_amdgcn_mfma_f32_16x16x32_bf16(afr[i], bfr[j], acc[i][j], 0, 0, 0);
    }
  }

  #pragma unroll
  for (int j = 0; j < 2; j++) {
    int co = coW + j * 16 + m;
    float bv = bias[co];
    #pragma unroll
    for (int i = 0; i < 2; i++) {
      #pragma unroll
      for (int r = 0; r < 4; r++) {
        size_t px = ibase + (size_t)y * Wp + c0 + i * 16 + q * 4 + r;
        float v = acc[i][j][r] + bv;
        v = v > 0.f ? v : 0.1f * v;
        out[px * 64 + co] = f2b(v);
      }
    }
  }
}

// ---------------- NCHW fp32 -> NHWC bf16 (full batch) ----------------
__global__ __launch_bounds__(256)
void t64b(const float* __restrict__ in, ushortt* __restrict__ out) {
  __shared__ float tl[64 * 65];
  int tid = threadIdx.x;
  int b = blockIdx.y;
  int px0 = blockIdx.x * 64;
  int lpx = tid & 63, c4 = tid >> 6;
  const float* ip = in + (size_t)b * 64 * HWp;
  #pragma unroll
  for (int i = 0; i < 16; i++) {
    int c = c4 + 4 * i;
    tl[lpx * 65 + c] = ip[(size_t)c * HWp + px0 + lpx];
  }
  __syncthreads();
  int ci = tid & 63, pr = tid >> 6;
  #pragma unroll
  for (int i = 0; i < 16; i++) {
    int r = pr + 4 * i;
    out[((size_t)b * HWp + px0 + r) * 64 + ci] = f2b(tl[r * 65 + ci]);
  }
}

// ---------------- weight repacks ----------------
__global__ __launch_bounds__(256)
void repw1(const float* __restrict__ in, ushortt* __restrict__ out) {
  int idx = blockIdx.x * 256 + threadIdx.x;
  if (idx >= 4096) return;
  out[idx] = f2b(in[idx]);
}
__global__ __launch_bounds__(256)
void repw9x4(const float* __restrict__ s0, const float* __restrict__ s1,
             const float* __restrict__ s2, const float* __restrict__ s3,
             ushortt* __restrict__ dst) {
  int which = blockIdx.y;
  const float* in = which == 0 ? s0 : which == 1 ? s1 : which == 2 ? s2 : s3;
  int idx = blockIdx.x * 256 + threadIdx.x;
  if (idx >= 36864) return;
  int k = idx >> 12, r = idx & 4095;
  int co = r >> 6, ci = r & 63;
  dst[which * 36864 + idx] = f2b(in[(size_t)(co * 64 + ci) * 9 + k]);
}
__global__ __launch_bounds__(256)
void rep576x3(const float* __restrict__ s0, const float* __restrict__ s1,
              const float* __restrict__ s2, ushortt* __restrict__ dst) {
  int which = blockIdx.y;
  const float* in = which == 0 ? s0 : which == 1 ? s1 : s2;
  int idx = blockIdx.x * 256 + threadIdx.x;
  if (idx >= 640 * 576) return;
  int cop = idx / 576, cip = idx % 576;
  ushortt v = 0;
  if (cop < 576) {
    int co = (cop & 63) * 9 + (cop >> 6);
    int ci = (cip & 63) * 9 + (cip >> 6);
    v = f2b(in[(size_t)co * 576 + ci]);
  }
  dst[(size_t)which * 640 * 576 + idx] = v;
}
__global__ __launch_bounds__(256)
void repinv2(const float* __restrict__ in, ushortt* __restrict__ out) {
  int idx = blockIdx.x * 256 + threadIdx.x;
  if (idx >= 64 * 576) return;
  int co = idx / 576, cip = idx % 576;
  int ci = (cip & 63) * 9 + (cip >> 6);
  out[idx] = f2b(in[(size_t)co * 576 + ci]);
}
__global__ __launch_bounds__(256)
void repdw3(const float* __restrict__ s0, const float* __restrict__ s1,
            const float* __restrict__ s2, ushortt* __restrict__ dst) {
  int idx = blockIdx.x * 256 + threadIdx.x;
  if (idx >= 3 * 5184) return;
  int which = idx / 5184, r = idx % 5184;
  const float* in = which == 0 ? s0 : which == 1 ? s1 : s2;
  int tap = r / 576, chp = r % 576;
  int ch = (chp & 63) * 9 + (chp >> 6);
  dst[idx] = f2b(in[ch * 9 + tap]);
}
__global__ __launch_bounds__(256)
void reppw4(const float* __restrict__ s0, const float* __restrict__ s1,
            const float* __restrict__ s2, const float* __restrict__ s3,
            ushortt* __restrict__ dst) {
  int which = blockIdx.y;
  const float* in = which == 0 ? s0 : which == 1 ? s1 : which == 2 ? s2 : s3;
  int idx = blockIdx.x * 256 + threadIdx.x;
  if (idx >= 8192) return;
  dst[which * 8192 + idx] = f2b(in[idx]);
}

// ---------------- off_w6 -> NCHW offsets, 8*tanh ----------------
__global__ __launch_bounds__(256)
void off6_nhwc(const ushortt* __restrict__ hi, const float* __restrict__ wgt,
               const float* __restrict__ bias, float* __restrict__ out) {
  __shared__ float Wl[18 * 64];
  for (int i = threadIdx.x; i < 18 * 64; i += 256) Wl[i] = wgt[i];
  __syncthreads();
  int px = blockIdx.x * 256 + threadIdx.x;
  int b = px >> 14, pim = px & 16383;
  float acc[18];
  #pragma unroll
  for (int j = 0; j < 18; j++) acc[j] = 0.f;
  const uint4* ph = (const uint4*)(hi + (size_t)px * 64);
  for (int g = 0; g < 8; g++) {
    uint4 H = ph[g];
    u32 hw[4] = {H.x, H.y, H.z, H.w};
    #pragma unroll
    for (int t = 0; t < 4; t++) {
      float v0 = blo(hw[t]);
      float v1 = bhi(hw[t]);
      int ci = g * 8 + t * 2;
      #pragma unroll
      for (int j = 0; j < 18; j++)
        acc[j] += Wl[j * 64 + ci] * v0 + Wl[j * 64 + ci + 1] * v1;
    }
  }
  #pragma unroll
  for (int j = 0; j < 18; j++)
    out[((size_t)b * 18 + j) * HWp + pim] = 8.f * tanhf(acc[j] + bias[j]);
}

// ---------------- fused deform + dct (2 batches per dispatch) ----------------
__global__ __launch_bounds__(256)
void deform_dct(const ushortt* __restrict__ xn0, const float* __restrict__ offs0,
                const float* __restrict__ w9, ushortt* __restrict__ xb,
                ushortt* __restrict__ dctb) {
  __shared__ float Wl[5184];
  for (int i = threadIdx.x; i < 5184; i += 256) Wl[i] = w9[i];
  __syncthreads();
  int bl = blockIdx.y;
  const ushortt* xn = xn0 + (size_t)bl * HWp * 64;
  const float* offs = offs0 + (size_t)bl * 18 * HWp;
  int wid = threadIdx.x >> 6, lane = threadIdx.x & 63;
  int p = blockIdx.x * 4 + wid;
  int yi = p >> 7, xi = p & 127;
  size_t pg = (size_t)bl * HWp + p;
  float v[9];
  #pragma unroll
  for (int k = 0; k < 9; k++) {
    float dy = offs[(size_t)(2 * k) * HWp + p];
    float dx = offs[(size_t)(2 * k + 1) * HWp + p];
    float py = (float)yi + (float)(k / 3 - 1) + dy;
    float px = (float)xi + (float)(k % 3 - 1) + dx;
    float y0f = floorf(py), x0f = floorf(px);
    float wy1 = py - y0f, wy0 = 1.f - wy1;
    float wx1 = px - x0f, wx0 = 1.f - wx1;
    int y0 = (int)y0f, x0 = (int)x0f;
    bool vy0 = (y0 >= 0 && y0 < Hp), vy1 = (y0 + 1 >= 0 && y0 + 1 < Hp);
    bool vx0 = (x0 >= 0 && x0 < Wp), vx1 = (x0 + 1 >= 0 && x0 + 1 < Wp);
    int yc0 = min(max(y0, 0), Hp - 1), yc1 = min(max(y0 + 1, 0), Hp - 1);
    int xc0 = min(max(x0, 0), Wp - 1), xc1 = min(max(x0 + 1, 0), Wp - 1);
    float w00 = wy0 * wx0 * ((vy0 && vx0) ? 1.f : 0.f);
    float w01 = wy0 * wx1 * ((vy0 && vx1) ? 1.f : 0.f);
    float w10 = wy1 * wx0 * ((vy1 && vx0) ? 1.f : 0.f);
    float w11 = wy1 * wx1 * ((vy1 && vx1) ? 1.f : 0.f);
    float v00 = b2f(xn[(size_t)(yc0 * Wp + xc0) * 64 + lane]);
    float v01 = b2f(xn[(size_t)(yc0 * Wp + xc1) * 64 + lane]);
    float v10 = b2f(xn[(size_t)(yc1 * Wp + xc0) * 64 + lane]);
    float v11 = b2f(xn[(size_t)(yc1 * Wp + xc1) * 64 + lane]);
    v[k] = v00 * w00 + v01 * w01 + v10 * w10 + v11 * w11;
    xb[pg * 576 + 64 * k + lane] = f2b(v[k]);
  }
  const float* wc = &Wl[lane * 81];
  #pragma unroll
  for (int j = 0; j < 9; j++) {
    float a = 0.f;
    #pragma unroll
    for (int kk = 0; kk < 9; kk++) a += wc[j * 9 + kk] * v[kk];
    dctb[pg * 576 + 64 * j + lane] = f2b(a);
  }
}

// ---------------- MFMA bf16 GEMM, 128x128 tile, XCD-partitioned ----------------
// grid (5, 256) = 1280 blocks; xcd=lin&7 owns px-tiles [xcd*32, xcd*32+32), co fastest.
// Wb padded to 640 rows. SWIZZLE: global SOURCE chunk XOR'd per lane; LDS dest
// stays lane-linear (global_load_lds writes base+lane*16B — per-lane dest
// addresses are NOT honored; round-10 bug). Read column qx matches.
__global__ __launch_bounds__(256)
void gemm128(const ushortt* __restrict__ X, const ushortt* __restrict__ Wb,
             ushortt* __restrict__ out) {
  __shared__ ushortt Xs[128 * 32];
  __shared__ ushortt Wsh[128 * 32];
  int tid = threadIdx.x;
  int lin = blockIdx.x + blockIdx.y * 5;
  int xcd = lin & 7, loc = lin >> 3;        // loc in [0,160)
  int co_t = loc % 5;
  int px_t = xcd * 32 + loc / 5;
  int co0 = co_t * 128, px0 = px_t * 128;
  int r0 = tid >> 2;
  int sch = (tid & 3) ^ ((tid >> 3) & 3);   // source-chunk swizzle (slot s1 identical)
  size_t gx0 = (size_t)(px0 + r0) * 576 + sch * 8;
  size_t gx1 = gx0 + (size_t)64 * 576;
  size_t gw0 = (size_t)(co0 + r0) * 576 + sch * 8;
  size_t gw1 = gw0 + (size_t)64 * 576;
  int wid = tid >> 6, lane = tid & 63;
  int q = lane >> 4, m = lane & 15;
  int qx = (q ^ ((m >> 1) & 3)) * 8;
  int pxh = (wid & 1) * 64, coh = (wid >> 1) * 64;
  float4v acc[4][4];
  #pragma unroll
  for (int i = 0; i < 4; i++)
    #pragma unroll
    for (int j = 0; j < 4; j++) acc[i][j] = (float4v){0.f, 0.f, 0.f, 0.f};

  for (int k0 = 0; k0 < 576; k0 += 32) {
    __syncthreads();
    gll(X + gx0 + k0,  &Xs[tid * 8]);
    gll(X + gx1 + k0,  &Xs[2048 + tid * 8]);
    gll(Wb + gw0 + k0, &Wsh[tid * 8]);
    gll(Wb + gw1 + k0, &Wsh[2048 + tid * 8]);
    __syncthreads();
    short8 a[4], b[4];
    #pragma unroll
    for (int i = 0; i < 4; i++)
      a[i] = *(const short8*)&Xs[(pxh + i * 16 + m) * 32 + qx];
    #pragma unroll
    for (int j = 0; j < 4; j++)
      b[j] = *(const short8*)&Wsh[(coh + j * 16 + m) * 32 + qx];
    #pragma unroll
    for (int i = 0; i < 4; i++)
      #pragma unroll
      for (int j = 0; j < 4; j++)
        acc[i][j] = __builtin_amdgcn_mfma_f32_16x16x32_bf16(a[i], b[j], acc[i][j], 0, 0, 0);
  }

  #pragma unroll
  for (int j = 0; j < 4; j++) {
    int co = co0 + coh + j * 16 + m;
    if (co >= 576) continue;
    #pragma unroll
    for (int i = 0; i < 4; i++) {
      int pxb = px0 + pxh + i * 16 + q * 4;
      #pragma unroll
      for (int r = 0; r < 4; r++)
        out[(size_t)(pxb + r) * 576 + co] = f2b(acc[i][j][r]);
    }
  }
}

// ---------------- MFMA bf16 GEMM 576->64 (inv2), out fp32 NCHW ----------------
__global__ __launch_bounds__(256)
void gemm64o2(const ushortt* __restrict__ X, const ushortt* __restrict__ Wb,
              float* __restrict__ outv) {
  __shared__ ushortt Xs[128 * 32];
  __shared__ ushortt Wsh[64 * 32];
  int tid = threadIdx.x;
  int px0 = (blockIdx.x + blockIdx.y * gridDim.x) * 128;
  int srow = tid >> 2;
  int sch = (tid & 3) ^ ((tid >> 3) & 3);
  size_t gxo0 = (size_t)(px0 + srow) * 576 + sch * 8;
  size_t gxo1 = gxo0 + (size_t)64 * 576;
  size_t gwo  = (size_t)srow * 576 + sch * 8;
  int wid = tid >> 6, lane = tid & 63;
  int q = lane >> 4, m = lane & 15;
  int qx = (q ^ ((m >> 1) & 3)) * 8;
  int pxh = (wid & 1) * 64, coh = (wid >> 1) * 32;
  float4v acc[4][2];
  #pragma unroll
  for (int i = 0; i < 4; i++)
    #pragma unroll
    for (int j = 0; j < 2; j++) acc[i][j] = (float4v){0.f, 0.f, 0.f, 0.f};

  for (int k0 = 0; k0 < 576; k0 += 32) {
    __syncthreads();
    gll(X + gxo0 + k0,  &Xs[tid * 8]);
    gll(X + gxo1 + k0,  &Xs[2048 + tid * 8]);
    gll(Wb + gwo + k0,  &Wsh[tid * 8]);
    __syncthreads();
    short8 a[4], b[2];
    #pragma unroll
    for (int i = 0; i < 4; i++)
      a[i] = *(const short8*)&Xs[(pxh + i * 16 + m) * 32 + qx];
    #pragma unroll
    for (int j = 0; j < 2; j++)
      b[j] = *(const short8*)&Wsh[(coh + j * 16 + m) * 32 + qx];
    #pragma unroll
    for (int i = 0; i < 4; i++)
      #pragma unroll
      for (int j = 0; j < 2; j++)
        acc[i][j] = __builtin_amdgcn_mfma_f32_16x16x32_bf16(a[i], b[j], acc[i][j], 0, 0, 0);
  }

  #pragma unroll
  for (int j = 0; j < 2; j++) {
    int co = coh + j * 16 + m;
    #pragma unroll
    for (int i = 0; i < 4; i++) {
      int pxb = px0 + pxh + i * 16 + q * 4;
      int bl = pxb >> 14, pim = pxb & 16383;
      float4 r;
      r.x = acc[i][j][0]; r.y = acc[i][j][1];
      r.z = acc[i][j][2]; r.w = acc[i][j][3];
      *(float4*)&outv[(size_t)(bl * 64 + co) * HWp + pim] = r;
    }
  }
}

// ---------------- depthwise 3x3 NHWC bf16 v2: 8ch x 4-row column per thread ----------------
template<int ACT>
__global__ __launch_bounds__(256)
void dw3x3_v2(const ushortt* __restrict__ in, const ushortt* __restrict__ wt,
              ushortt* __restrict__ out) {
  int tid = threadIdx.x;
  int pxl = tid / 72;
  int g = tid - pxl * 72;
  if (pxl >= 3) return;
  int x = blockIdx.x * 3 + pxl;
  if (x >= Wp) return;
  int y0 = blockIdx.y * 4;
  size_t bbase = (size_t)blockIdx.z * HWp;

  float w[9][8];
  #pragma unroll
  for (int t = 0; t < 9; t++) {
    uint4 wv = *(const uint4*)&wt[t * 576 + g * 8];
    u32 wsw[4] = {wv.x, wv.y, wv.z, wv.w};
    #pragma unroll
    for (int p = 0; p < 4; p++) {
      w[t][2 * p]     = blo(wsw[p]);
      w[t][2 * p + 1] = bhi(wsw[p]);
    }
  }
  float acc[4][8];
  #pragma unroll
  for (int o = 0; o < 4; o++)
    #pragma unroll
    for (int c = 0; c < 8; c++) acc[o][c] = 0.f;

  #pragma unroll
  for (int ri = 0; ri < 6; ri++) {
    int yy = y0 - 1 + ri;
    bool vr = (yy >= 0 && yy < Hp);
    float v[3][8];
    #pragma unroll
    for (int dx = 0; dx < 3; dx++) {
      int xx = x + dx - 1;
      uint4 t4 = {0, 0, 0, 0};
      if (vr && xx >= 0 && xx < Wp)
        t4 = *(const uint4*)&in[(bbase + (size_t)yy * Wp + xx) * 576 + g * 8];
      u32 tw[4] = {t4.x, t4.y, t4.z, t4.w};
      #pragma unroll
      for (int p = 0; p < 4; p++) {
        v[dx][2 * p]     = blo(tw[p]);
        v[dx][2 * p + 1] = bhi(tw[p]);
      }
    }
    #pragma unroll
    for (int o = 0; o < 4; o++) {
      int dy = ri - o;
      if (dy < 0 || dy > 2) continue;
      #pragma unroll
      for (int dx = 0; dx < 3; dx++)
        #pragma unroll
        for (int c = 0; c < 8; c++)
          acc[o][c] += w[dy * 3 + dx][c] * v[dx][c];
    }
  }

  #pragma unroll
  for (int o = 0; o < 4; o++) {
    int yy = y0 + o;
    u32 pk[4];
    #pragma unroll
    for (int p = 0; p < 4; p++) {
      float r0 = acc[o][2 * p], r1 = acc[o][2 * p + 1];
      if (ACT == 1) { r0 = fmaxf(r0, 0.f); r1 = fmaxf(r1, 0.f); }
      else { r0 = 1.f / (1.f + __expf(-r0)); r1 = 1.f / (1.f + __expf(-r1)); }
      pk[p] = (u32)f2b(r0) | (((u32)f2b(r1)) << 16);
    }
    uint4 o4; o4.x = pk[0]; o4.y = pk[1]; o4.z = pk[2]; o4.w = pk[3];
    *(uint4*)&out[(bbase + (size_t)yy * Wp + x) * 576 + g * 8] = o4;
  }
}

// ---------------- group 9->9 inv1, fused wiener*dct (2 batches, bf16) ----------------
__global__ __launch_bounds__(256)
void g9inv(const ushortt* __restrict__ wien, const ushortt* __restrict__ dct,
           const float* __restrict__ w9, ushortt* __restrict__ outb) {
  __shared__ float Wl[5184];
  for (int i = threadIdx.x; i < 5184; i += 256) Wl[i] = w9[i];
  __syncthreads();
  int c = threadIdx.x & 63, pxl = threadIdx.x >> 6;
  size_t px = (size_t)blockIdx.x * 4 + pxl;
  float v[9];
  #pragma unroll
  for (int kk = 0; kk < 9; kk++)
    v[kk] = b2f(wien[px * 576 + 64 * kk + c]) * b2f(dct[px * 576 + 64 * kk + c]);
  const float* wc = &Wl[c * 81];
  #pragma unroll
  for (int j = 0; j < 9; j++) {
    float a = 0.f;
    #pragma unroll
    for (int kk = 0; kk < 9; kk++) a += wc[j * 9 + kk] * v[kk];
    outb[px * 576 + 64 * j + c] = f2b(a);
  }
}

// ---------------- launch ----------------
extern "C" void kernel_launch(void* const* d_in, const int* in_sizes, int n_in,
                              void* d_out, int out_size, void* d_ws, size_t ws_size,
                              hipStream_t stream) {
  const float* x       = (const float*)d_in[0];
  const float* enc_dw  = (const float*)d_in[1];
  const float* enc_pw1 = (const float*)d_in[2];
  const float* enc_pw2 = (const float*)d_in[3];
  const float* dec_dw  = (const float*)d_in[4];
  const float* dec_pw1 = (const float*)d_in[5];
  const float* dec_pw2 = (const float*)d_in[6];
  const float* off_w1  = (const float*)d_in[7];
  const float* off_b1  = (const float*)d_in[8];
  const float* off_w2  = (const float*)d_in[9];
  const float* off_b2  = (const float*)d_in[10];
  const float* off_w3  = (const float*)d_in[11];
  const float* off_b3  = (const float*)d_in[12];
  const float* off_w4  = (const float*)d_in[13];
  const float* off_b4  = (const float*)d_in[14];
  const float* off_w5  = (const float*)d_in[15];
  const float* off_b5  = (const float*)d_in[16];
  const float* off_w6  = (const float*)d_in[17];
  const float* off_b6  = (const float*)d_in[18];
  const float* dct_w   = (const float*)d_in[19];
  const float* wie_w1  = (const float*)d_in[20];
  const float* wie_w2  = (const float*)d_in[21];
  const float* wie_w3  = (const float*)d_in[22];
  const float* wie_w4  = (const float*)d_in[23];
  const float* wie_w5  = (const float*)d_in[24];
  const float* wie_w6  = (const float*)d_in[25];
  const float* inv_w1  = (const float*)d_in[26];
  const float* inv_w2  = (const float*)d_in[27];
  float* outp = (float*)d_out;

  const size_t NP = (size_t)Bp * HWp;
  const size_t REQ_FLOATS = NP * 64 + NP * 64 + NP * 128 +
                            2 * (size_t)HWp * CKp + (size_t)HWp * CKp;
  if (ws_size < REQ_FLOATS * sizeof(float)) return;

  float* ws  = (float*)d_ws;
  float* x1  = ws;
  float* t0  = x1 + NP * 64;
  float* t1  = t0 + NP * 64;
  float* bigA = t1 + NP * 128;
  float* bigB = bigA + (size_t)HWp * CKp;
  float* bigC = bigB + (size_t)HWp * CKp;
  ushortt* R1 = (ushortt*)bigA;
  ushortt* R2 = (ushortt*)bigB;
  ushortt* R3 = (ushortt*)bigC;
  ushortt* e1 = (ushortt*)bigA;

  float* wreg = t0 + NP * 18;
  ushortt* wb  = (ushortt*)wreg;
  ushortt* wbi2 = wb + 3 * 640 * 576;
  ushortt* wdwb = wbi2 + 64 * 576;
  ushortt* wc1  = wdwb + 3 * 5184;
  ushortt* wc2  = wc1 + 4096;
  ushortt* wpw  = wc2 + 4 * 36864;

  ushortt* xnAll = (ushortt*)t1;
  ushortt* oA = xnAll + NP * 64;
  ushortt* oB = oA + NP * 64;

  float* offs = t0;
  float* mid  = x1;

  dim3 blk(256);

  // ---- enc ConvNeXt: dw7 fp32, pw via bf16 MFMA ----
  dwconv7_lds<<<dim3(Hp / 2, Bp * Cp), blk, 0, stream>>>(x, enc_dw, t0);
  t64b<<<dim3(HWp / 64, Bp), blk, 0, stream>>>(t0, oA);

  // ---- weight repacks ----
  rep576x3<<<dim3((640 * 576 + 255) / 256, 3), blk, 0, stream>>>(
      wie_w1, wie_w3, wie_w5, wb);
  repinv2<<<dim3((64 * 576 + 255) / 256), blk, 0, stream>>>(inv_w2, wbi2);
  repdw3<<<dim3((3 * 5184 + 255) / 256), blk, 0, stream>>>(wie_w2, wie_w4, wie_w6, wdwb);
  repw1<<<dim3(16), blk, 0, stream>>>(off_w1, wc1);
  repw9x4<<<dim3((36864 + 255) / 256, 4), blk, 0, stream>>>(
      off_w2, off_w3, off_w4, off_w5, wc2);
  reppw4<<<dim3(32, 4), blk, 0, stream>>>(enc_pw1, enc_pw2, dec_pw1, dec_pw2, wpw);

  pw_bf<64, 1, 0><<<dim3(NP / 128, 2), blk, 0, stream>>>(oA, wpw, nullptr, e1, 128);
  pw_bf<128, 0, 1><<<dim3(NP / 128, 1), blk, 0, stream>>>(e1, wpw + 8192, x, xnAll, 64);

  // ---- offset CNN (full batch, bf16 MFMA, NHWC) ----
  conv_bf<1><<<dim3(HWp / 64, Bp), blk, 0, stream>>>(xnAll, wc1, off_b1, oA);
  conv_bf<9><<<dim3(HWp / 64, Bp), blk, 0, stream>>>(oA, wc2,             off_b2, oB);
  conv_bf<9><<<dim3(HWp / 64, Bp), blk, 0, stream>>>(oB, wc2 + 36864,     off_b3, oA);
  conv_bf<9><<<dim3(HWp / 64, Bp), blk, 0, stream>>>(oA, wc2 + 2 * 36864, off_b4, oB);
  conv_bf<9><<<dim3(HWp / 64, Bp), blk, 0, stream>>>(oB, wc2 + 3 * 36864, off_b5, oA);
  off6_nhwc<<<dim3(NP / 256), blk, 0, stream>>>(oA, off_w6, off_b6, offs);

  // ---- 576-channel middle: 2 batches per pass ----
  for (int bp = 0; bp < 2; bp++) {
    const ushortt* xn0 = xnAll + (size_t)(2 * bp) * HWp * 64;
    const float* off0 = offs + (size_t)(2 * bp) * 18 * HWp;
    float* mid0 = mid + (size_t)(2 * bp) * 64 * HWp;

    deform_dct<<<dim3(HWp / 4, 2), blk, 0, stream>>>(xn0, off0, dct_w, R1, R2);
    gemm128<<<dim3(5, 256), blk, 0, stream>>>(R1, wb, R3);
    dw3x3_v2<1><<<dim3(43, 32, 2), blk, 0, stream>>>(R3, wdwb, R1);
    gemm128<<<dim3(5, 256), blk, 0, stream>>>(R1, wb + 640 * 576, R3);
    dw3x3_v2<1><<<dim3(43, 32, 2), blk, 0, stream>>>(R3, wdwb + 5184, R1);
    gemm128<<<dim3(5, 256), blk, 0, stream>>>(R1, wb + 2 * 640 * 576, R3);
    dw3x3_v2<2><<<dim3(43, 32, 2), blk, 0, stream>>>(R3, wdwb + 2 * 5184, R1);
    g9inv<<<dim3(2 * HWp / 4), blk, 0, stream>>>(R1, R2, inv_w1, R3);
    gemm64o2<<<dim3(1, 256), blk, 0, stream>>>(R3, wbi2, mid0);
  }

  // ---- dec ConvNeXt: dw7 fp32 (tmp in bigB), pw via bf16 MFMA ----
  dwconv7_lds<<<dim3(Hp / 2, Bp * Cp), blk, 0, stream>>>(mid, dec_dw, bigB);
  t64b<<<dim3(HWp / 64, Bp), blk, 0, stream>>>(bigB, oA);
  pw_bf<64, 1, 0><<<dim3(NP / 128, 2), blk, 0, stream>>>(oA, wpw + 2 * 8192, nullptr, e1, 128);
  pw_bf<128, 0, 2><<<dim3(NP / 128, 1), blk, 0, stream>>>(e1, wpw + 3 * 8192, mid, outp, 64);
}

// Round 12
// 898.881 us; speedup vs baseline: 4.4610x; 1.0326x over previous
//
#include <hip/hip_runtime.h>
#include <math.h>

#define HWp 16384
#define Wp 128
#define Hp 128
#define Bp 4
#define Cp 64
#define CKp 576

typedef unsigned int u32;
typedef unsigned short ushortt;
typedef __attribute__((ext_vector_type(8))) short short8;
typedef __attribute__((ext_vector_type(4))) float float4v;

__device__ __forceinline__ ushortt f2b(float f) {
  union { float f; u32 u; } x; x.f = f;
  u32 r = x.u + 0x7fff + ((x.u >> 16) & 1);
  return (ushortt)(r >> 16);
}
__device__ __forceinline__ float b2f(ushortt h) {
  union { u32 u; float f; } x; x.u = ((u32)h) << 16; return x.f;
}
__device__ __forceinline__ float blo(u32 t) {
  union { u32 u; float f; } x; x.u = t << 16; return x.f;
}
__device__ __forceinline__ float bhi(u32 t) {
  union { u32 u; float f; } x; x.u = t & 0xffff0000u; return x.f;
}
__device__ __forceinline__ void gll(const ushortt* g, ushortt* l) {
  __builtin_amdgcn_global_load_lds(
      (const __attribute__((address_space(1))) u32*)g,
      (__attribute__((address_space(3))) u32*)l, 16, 0, 0);
}

// ---------------- depthwise 7x7, pad 3, LDS-tiled (NCHW) ----------------
__global__ __launch_bounds__(256)
void dwconv7_lds(const float* __restrict__ in, const float* __restrict__ w,
                 float* __restrict__ out) {
  int bc = blockIdx.y;
  int tid = threadIdx.x;
  int y0 = blockIdx.x * 2;
  __shared__ float ws[49];
  __shared__ float tile[8][136];
  if (tid < 49) ws[tid] = w[(bc & 63) * 49 + tid];
  if (tid < 48) {
    int r = tid / 6, cc = tid % 6;
    tile[r][cc < 3 ? cc : 128 + cc] = 0.f;
  }
  const float* ip = in + (size_t)bc * HWp;
  #pragma unroll
  for (int i = 0; i < 4; i++) {
    int idx = tid + 256 * i;
    int r = idx >> 7, xx = idx & 127;
    int yy = y0 - 3 + r;
    tile[r][xx + 3] = (yy >= 0 && yy < Hp) ? ip[yy * Wp + xx] : 0.f;
  }
  __syncthreads();
  int ty = tid >> 7, x = tid & 127;
  float acc = 0.f;
  #pragma unroll
  for (int dy = 0; dy < 7; dy++)
    #pragma unroll
    for (int dx = 0; dx < 7; dx++)
      acc += tile[ty + dy][x + dx] * ws[dy * 7 + dx];
  out[(size_t)bc * HWp + (y0 + ty) * Wp + x] = acc;
}

// ---------------- bf16 MFMA pointwise conv (enc/dec ConvNeXt pw) ----------------
template<int CIN, int ACT, int MODE>
__global__ __launch_bounds__(256)
void pw_bf(const ushortt* __restrict__ in, const ushortt* __restrict__ wt,
           const float* __restrict__ resid, void* __restrict__ outv, int Cout) {
  int tid = threadIdx.x;
  int wid = tid >> 6, lane = tid & 63;
  int q = lane >> 4, m = lane & 15;
  int px0 = blockIdx.x * 128, co0 = blockIdx.y * 64;
  int pxh = (wid & 1) * 64, coh = (wid >> 1) * 32;
  float4v acc[4][2];
  #pragma unroll
  for (int i = 0; i < 4; i++)
    #pragma unroll
    for (int j = 0; j < 2; j++) acc[i][j] = (float4v){0.f, 0.f, 0.f, 0.f};

  #pragma unroll
  for (int k0 = 0; k0 < CIN; k0 += 32) {
    short8 a[4], b[2];
    #pragma unroll
    for (int j = 0; j < 2; j++)
      b[j] = *(const short8*)&wt[(size_t)(co0 + coh + j * 16 + m) * CIN + k0 + q * 8];
    #pragma unroll
    for (int i = 0; i < 4; i++)
      a[i] = *(const short8*)&in[(size_t)(px0 + pxh + i * 16 + m) * CIN + k0 + q * 8];
    #pragma unroll
    for (int i = 0; i < 4; i++)
      #pragma unroll
      for (int j = 0; j < 2; j++)
        acc[i][j] = __builtin_amdgcn_mfma_f32_16x16x32_bf16(a[i], b[j], acc[i][j], 0, 0, 0);
  }

  #pragma unroll
  for (int j = 0; j < 2; j++) {
    int co = co0 + coh + j * 16 + m;
    #pragma unroll
    for (int i = 0; i < 4; i++) {
      int pxb = px0 + pxh + i * 16 + q * 4;
      int bl = pxb >> 14, pim = pxb & 16383;
      if (MODE == 0) {
        #pragma unroll
        for (int r = 0; r < 4; r++) {
          float v = acc[i][j][r];
          if (ACT == 1) v = fmaxf(v, 0.f);
          ((ushortt*)outv)[(size_t)(pxb + r) * Cout + co] = f2b(v);
        }
      } else {
        float4 rr = *(const float4*)&resid[(size_t)(bl * 64 + co) * HWp + pim];
        float v0 = acc[i][j][0] + rr.x, v1 = acc[i][j][1] + rr.y;
        float v2 = acc[i][j][2] + rr.z, v3 = acc[i][j][3] + rr.w;
        if (MODE == 1) {
          ushortt* ob = (ushortt*)outv;
          ob[(size_t)(pxb + 0) * 64 + co] = f2b(v0);
          ob[(size_t)(pxb + 1) * 64 + co] = f2b(v1);
          ob[(size_t)(pxb + 2) * 64 + co] = f2b(v2);
          ob[(size_t)(pxb + 3) * 64 + co] = f2b(v3);
        } else {
          float4 w4; w4.x = v0; w4.y = v1; w4.z = v2; w4.w = v3;
          *(float4*)&((float*)outv)[(size_t)(bl * 64 + co) * HWp + pim] = w4;
        }
      }
    }
  }
}

// ---------------- plain-bf16 MFMA conv (1x1 or 3x3 pad1), NHWC 64ch ----------------
template<int TAPS>
__global__ __launch_bounds__(256)
void conv_bf(const ushortt* __restrict__ in, const ushortt* __restrict__ wt,
             const float* __restrict__ bias, ushortt* __restrict__ out) {
  int tid = threadIdx.x;
  int wid = tid >> 6, lane = tid & 63;
  int q = lane >> 4, m = lane & 15;
  int bx = blockIdx.x, b = blockIdx.y;
  int y = bx >> 1;
  int c0 = ((bx & 1) << 6) + ((wid & 1) << 5);
  int coW = (wid >> 1) << 5;
  size_t ibase = (size_t)b * HWp;

  float4v acc[2][2];
  #pragma unroll
  for (int i = 0; i < 2; i++)
    #pragma unroll
    for (int j = 0; j < 2; j++) acc[i][j] = (float4v){0.f, 0.f, 0.f, 0.f};
  short8 zz = {0, 0, 0, 0, 0, 0, 0, 0};

  #pragma unroll
  for (int k = 0; k < TAPS; k++) {
    int dy = (TAPS == 9) ? (k / 3 - 1) : 0;
    int dx = (TAPS == 9) ? (k % 3 - 1) : 0;
    int yy = y + dy;
    if (TAPS == 9 && (yy < 0 || yy >= Hp)) continue;
    #pragma unroll
    for (int ch = 0; ch < 2; ch++) {
      int ci0 = ch * 32 + q * 8;
      short8 bfr[2], afr[2];
      #pragma unroll
      for (int j = 0; j < 2; j++)
        bfr[j] = *(const short8*)&wt[(size_t)(k * 64 + coW + j * 16 + m) * 64 + ci0];
      #pragma unroll
      for (int i = 0; i < 2; i++) {
        int col = c0 + i * 16 + m + dx;
        bool vld = (TAPS == 1) || ((unsigned)col < (unsigned)Wp);
        int colc = min(max(col, 0), Wp - 1);
        short8 h = *(const short8*)&in[(ibase + (size_t)yy * Wp + colc) * 64 + ci0];
        afr[i] = vld ? h : zz;
      }
      #pragma unroll
      for (int i = 0; i < 2; i++)
        #pragma unroll
        for (int j = 0; j < 2; j++)
          acc[i][j] = __builtin_amdgcn_mfma_f32_16x16x32_bf16(afr[i], bfr[j], acc[i][j], 0, 0, 0);
    }
  }

  #pragma unroll
  for (int j = 0; j < 2; j++) {
    int co = coW + j * 16 + m;
    float bv = bias[co];
    #pragma unroll
    for (int i = 0; i < 2; i++) {
      #pragma unroll
      for (int r = 0; r < 4; r++) {
        size_t px = ibase + (size_t)y * Wp + c0 + i * 16 + q * 4 + r;
        float v = acc[i][j][r] + bv;
        v = v > 0.f ? v : 0.1f * v;
        out[px * 64 + co] = f2b(v);
      }
    }
  }
}

// ---------------- NCHW fp32 -> NHWC bf16 (full batch) ----------------
__global__ __launch_bounds__(256)
void t64b(const float* __restrict__ in, ushortt* __restrict__ out) {
  __shared__ float tl[64 * 65];
  int tid = threadIdx.x;
  int b = blockIdx.y;
  int px0 = blockIdx.x * 64;
  int lpx = tid & 63, c4 = tid >> 6;
  const float* ip = in + (size_t)b * 64 * HWp;
  #pragma unroll
  for (int i = 0; i < 16; i++) {
    int c = c4 + 4 * i;
    tl[lpx * 65 + c] = ip[(size_t)c * HWp + px0 + lpx];
  }
  __syncthreads();
  int ci = tid & 63, pr = tid >> 6;
  #pragma unroll
  for (int i = 0; i < 16; i++) {
    int r = pr + 4 * i;
    out[((size_t)b * HWp + px0 + r) * 64 + ci] = f2b(tl[r * 65 + ci]);
  }
}

// ---------------- merged weight repack (all segments, 5245 blocks) ----------------
__global__ __launch_bounds__(256)
void repack_all(const float* __restrict__ w1a, const float* __restrict__ w3a,
                const float* __restrict__ w5a, const float* __restrict__ inv2,
                const float* __restrict__ d2, const float* __restrict__ d4,
                const float* __restrict__ d6, const float* __restrict__ ow1,
                const float* __restrict__ ow2, const float* __restrict__ ow3,
                const float* __restrict__ ow4, const float* __restrict__ ow5,
                const float* __restrict__ p1, const float* __restrict__ p2,
                const float* __restrict__ p3, const float* __restrict__ p4,
                ushortt* __restrict__ wb, ushortt* __restrict__ wbi2,
                ushortt* __restrict__ wdwb, ushortt* __restrict__ wc1,
                ushortt* __restrict__ wc2, ushortt* __restrict__ wpw) {
  int b = blockIdx.x;
  int tid = threadIdx.x;
  if (b < 4320) {                       // wie_w1/3/5 -> wb (640-padded, perm)
    int which = b / 1440;
    int idx = (b - which * 1440) * 256 + tid;
    const float* in = which == 0 ? w1a : which == 1 ? w3a : w5a;
    int cop = idx / 576, cip = idx % 576;
    ushortt v = 0;
    if (cop < 576) {
      int co = (cop & 63) * 9 + (cop >> 6);
      int ci = (cip & 63) * 9 + (cip >> 6);
      v = f2b(in[(size_t)co * 576 + ci]);
    }
    wb[(size_t)which * 640 * 576 + idx] = v;
  } else if (b < 4464) {                // inv_w2 -> wbi2
    int idx = (b - 4320) * 256 + tid;
    if (idx < 64 * 576) {
      int co = idx / 576, cip = idx % 576;
      int ci = (cip & 63) * 9 + (cip >> 6);
      wbi2[idx] = f2b(inv2[(size_t)co * 576 + ci]);
    }
  } else if (b < 4525) {                // wie_w2/4/6 dw -> wdwb
    int idx = (b - 4464) * 256 + tid;
    if (idx < 3 * 5184) {
      int which = idx / 5184, r = idx % 5184;
      const float* in = which == 0 ? d2 : which == 1 ? d4 : d6;
      int tap = r / 576, chp = r % 576;
      int ch = (chp & 63) * 9 + (chp >> 6);
      wdwb[idx] = f2b(in[ch * 9 + tap]);
    }
  } else if (b < 4541) {                // off_w1 -> wc1
    int idx = (b - 4525) * 256 + tid;
    if (idx < 4096) wc1[idx] = f2b(ow1[idx]);
  } else if (b < 5117) {                // off_w2..5 -> wc2
    int bb = b - 4541;
    int which = bb / 144;
    int idx = (bb - which * 144) * 256 + tid;
    if (idx < 36864) {
      const float* in = which == 0 ? ow2 : which == 1 ? ow3 : which == 2 ? ow4 : ow5;
      int k = idx >> 12, r = idx & 4095;
      int co = r >> 6, ci = r & 63;
      wc2[which * 36864 + idx] = f2b(in[(size_t)(co * 64 + ci) * 9 + k]);
    }
  } else {                              // enc/dec pw -> wpw
    int bb = b - 5117;
    int which = bb / 32;
    int idx = (bb - which * 32) * 256 + tid;
    if (idx < 8192) {
      const float* in = which == 0 ? p1 : which == 1 ? p2 : which == 2 ? p3 : p4;
      wpw[which * 8192 + idx] = f2b(in[idx]);
    }
  }
}

// ---------------- off_w6 -> NCHW offsets, 8*tanh ----------------
__global__ __launch_bounds__(256)
void off6_nhwc(const ushortt* __restrict__ hi, const float* __restrict__ wgt,
               const float* __restrict__ bias, float* __restrict__ out) {
  __shared__ float Wl[18 * 64];
  for (int i = threadIdx.x; i < 18 * 64; i += 256) Wl[i] = wgt[i];
  __syncthreads();
  int px = blockIdx.x * 256 + threadIdx.x;
  int b = px >> 14, pim = px & 16383;
  float acc[18];
  #pragma unroll
  for (int j = 0; j < 18; j++) acc[j] = 0.f;
  const uint4* ph = (const uint4*)(hi + (size_t)px * 64);
  for (int g = 0; g < 8; g++) {
    uint4 H = ph[g];
    u32 hw[4] = {H.x, H.y, H.z, H.w};
    #pragma unroll
    for (int t = 0; t < 4; t++) {
      float v0 = blo(hw[t]);
      float v1 = bhi(hw[t]);
      int ci = g * 8 + t * 2;
      #pragma unroll
      for (int j = 0; j < 18; j++)
        acc[j] += Wl[j * 64 + ci] * v0 + Wl[j * 64 + ci + 1] * v1;
    }
  }
  #pragma unroll
  for (int j = 0; j < 18; j++)
    out[((size_t)b * 18 + j) * HWp + pim] = 8.f * tanhf(acc[j] + bias[j]);
}

// ---------------- deform only (xb), 2ch/lane, 2px/wave, XCD row-aligned ----------------
// grid 4096 1-D; xcd=lin&7 owns combined rows [xcd*32, xcd*32+32).
__global__ __launch_bounds__(256)
void deform_x(const ushortt* __restrict__ xn0, const float* __restrict__ offs0,
              ushortt* __restrict__ xb) {
  int lin = blockIdx.x;
  int xcd = lin & 7, local = lin >> 3;    // [0,512)
  int rowi = local >> 4, bx = local & 15;
  int tid = threadIdx.x;
  int wid = tid >> 6, lane = tid & 63;
  int c2 = lane & 31, ps = lane >> 5;
  int pg = (xcd * 32 + rowi) * 128 + bx * 8 + wid * 2 + ps;
  int bl = pg >> 14, p = pg & 16383;
  const ushortt* xn = xn0 + (size_t)bl * HWp * 64;
  const float* offs = offs0 + (size_t)bl * 18 * HWp;
  int yi = p >> 7, xi = p & 127;
  #pragma unroll
  for (int k = 0; k < 9; k++) {
    float dy = offs[(size_t)(2 * k) * HWp + p];
    float dx = offs[(size_t)(2 * k + 1) * HWp + p];
    float py = (float)yi + (float)(k / 3 - 1) + dy;
    float px = (float)xi + (float)(k % 3 - 1) + dx;
    float y0f = floorf(py), x0f = floorf(px);
    float wy1 = py - y0f, wy0 = 1.f - wy1;
    float wx1 = px - x0f, wx0 = 1.f - wx1;
    int y0 = (int)y0f, x0 = (int)x0f;
    bool vy0 = (y0 >= 0 && y0 < Hp), vy1 = (y0 + 1 >= 0 && y0 + 1 < Hp);
    bool vx0 = (x0 >= 0 && x0 < Wp), vx1 = (x0 + 1 >= 0 && x0 + 1 < Wp);
    int yc0 = min(max(y0, 0), Hp - 1), yc1 = min(max(y0 + 1, 0), Hp - 1);
    int xc0 = min(max(x0, 0), Wp - 1), xc1 = min(max(x0 + 1, 0), Wp - 1);
    float w00 = wy0 * wx0 * ((vy0 && vx0) ? 1.f : 0.f);
    float w01 = wy0 * wx1 * ((vy0 && vx1) ? 1.f : 0.f);
    float w10 = wy1 * wx0 * ((vy1 && vx0) ? 1.f : 0.f);
    float w11 = wy1 * wx1 * ((vy1 && vx1) ? 1.f : 0.f);
    u32 t00 = *(const u32*)&xn[(size_t)(yc0 * Wp + xc0) * 64 + c2 * 2];
    u32 t01 = *(const u32*)&xn[(size_t)(yc0 * Wp + xc1) * 64 + c2 * 2];
    u32 t10 = *(const u32*)&xn[(size_t)(yc1 * Wp + xc0) * 64 + c2 * 2];
    u32 t11 = *(const u32*)&xn[(size_t)(yc1 * Wp + xc1) * 64 + c2 * 2];
    float a = blo(t00) * w00 + blo(t01) * w01 + blo(t10) * w10 + blo(t11) * w11;
    float bv = bhi(t00) * w00 + bhi(t01) * w01 + bhi(t10) * w10 + bhi(t11) * w11;
    u32 pk = (u32)f2b(a) | (((u32)f2b(bv)) << 16);
    *(u32*)&xb[(size_t)pg * 576 + 64 * k + c2 * 2] = pk;
  }
}

// ---------------- MFMA bf16 GEMM, 128x128 tile, XCD-partitioned ----------------
__global__ __launch_bounds__(256)
void gemm128(const ushortt* __restrict__ X, const ushortt* __restrict__ Wb,
             ushortt* __restrict__ out) {
  __shared__ ushortt Xs[128 * 32];
  __shared__ ushortt Wsh[128 * 32];
  int tid = threadIdx.x;
  int lin = blockIdx.x + blockIdx.y * 5;
  int xcd = lin & 7, loc = lin >> 3;
  int co_t = loc % 5;
  int px_t = xcd * 32 + loc / 5;
  int co0 = co_t * 128, px0 = px_t * 128;
  int r0 = tid >> 2;
  int sch = (tid & 3) ^ ((tid >> 3) & 3);
  size_t gx0 = (size_t)(px0 + r0) * 576 + sch * 8;
  size_t gx1 = gx0 + (size_t)64 * 576;
  size_t gw0 = (size_t)(co0 + r0) * 576 + sch * 8;
  size_t gw1 = gw0 + (size_t)64 * 576;
  int wid = tid >> 6, lane = tid & 63;
  int q = lane >> 4, m = lane & 15;
  int qx = (q ^ ((m >> 1) & 3)) * 8;
  int pxh = (wid & 1) * 64, coh = (wid >> 1) * 64;
  float4v acc[4][4];
  #pragma unroll
  for (int i = 0; i < 4; i++)
    #pragma unroll
    for (int j = 0; j < 4; j++) acc[i][j] = (float4v){0.f, 0.f, 0.f, 0.f};

  for (int k0 = 0; k0 < 576; k0 += 32) {
    __syncthreads();
    gll(X + gx0 + k0,  &Xs[tid * 8]);
    gll(X + gx1 + k0,  &Xs[2048 + tid * 8]);
    gll(Wb + gw0 + k0, &Wsh[tid * 8]);
    gll(Wb + gw1 + k0, &Wsh[2048 + tid * 8]);
    __syncthreads();
    short8 a[4], b[4];
    #pragma unroll
    for (int i = 0; i < 4; i++)
      a[i] = *(const short8*)&Xs[(pxh + i * 16 + m) * 32 + qx];
    #pragma unroll
    for (int j = 0; j < 4; j++)
      b[j] = *(const short8*)&Wsh[(coh + j * 16 + m) * 32 + qx];
    #pragma unroll
    for (int i = 0; i < 4; i++)
      #pragma unroll
      for (int j = 0; j < 4; j++)
        acc[i][j] = __builtin_amdgcn_mfma_f32_16x16x32_bf16(a[i], b[j], acc[i][j], 0, 0, 0);
  }

  #pragma unroll
  for (int j = 0; j < 4; j++) {
    int co = co0 + coh + j * 16 + m;
    if (co >= 576) continue;
    #pragma unroll
    for (int i = 0; i < 4; i++) {
      int pxb = px0 + pxh + i * 16 + q * 4;
      #pragma unroll
      for (int r = 0; r < 4; r++)
        out[(size_t)(pxb + r) * 576 + co] = f2b(acc[i][j][r]);
    }
  }
}

// ---------------- MFMA bf16 GEMM 576->64 (inv2), out fp32 NCHW, XCD row-aligned ----------------
__global__ __launch_bounds__(256)
void gemm64o2(const ushortt* __restrict__ X, const ushortt* __restrict__ Wb,
              float* __restrict__ outv) {
  __shared__ ushortt Xs[128 * 32];
  __shared__ ushortt Wsh[64 * 32];
  int tid = threadIdx.x;
  int lin = blockIdx.x;
  int xcd = lin & 7, local = lin >> 3;      // [0,32)
  int px0 = (xcd * 32 + local) * 128;
  int srow = tid >> 2;
  int sch = (tid & 3) ^ ((tid >> 3) & 3);
  size_t gxo0 = (size_t)(px0 + srow) * 576 + sch * 8;
  size_t gxo1 = gxo0 + (size_t)64 * 576;
  size_t gwo  = (size_t)srow * 576 + sch * 8;
  int wid = tid >> 6, lane = tid & 63;
  int q = lane >> 4, m = lane & 15;
  int qx = (q ^ ((m >> 1) & 3)) * 8;
  int pxh = (wid & 1) * 64, coh = (wid >> 1) * 32;
  float4v acc[4][2];
  #pragma unroll
  for (int i = 0; i < 4; i++)
    #pragma unroll
    for (int j = 0; j < 2; j++) acc[i][j] = (float4v){0.f, 0.f, 0.f, 0.f};

  for (int k0 = 0; k0 < 576; k0 += 32) {
    __syncthreads();
    gll(X + gxo0 + k0,  &Xs[tid * 8]);
    gll(X + gxo1 + k0,  &Xs[2048 + tid * 8]);
    gll(Wb + gwo + k0,  &Wsh[tid * 8]);
    __syncthreads();
    short8 a[4], b[2];
    #pragma unroll
    for (int i = 0; i < 4; i++)
      a[i] = *(const short8*)&Xs[(pxh + i * 16 + m) * 32 + qx];
    #pragma unroll
    for (int j = 0; j < 2; j++)
      b[j] = *(const short8*)&Wsh[(coh + j * 16 + m) * 32 + qx];
    #pragma unroll
    for (int i = 0; i < 4; i++)
      #pragma unroll
      for (int j = 0; j < 2; j++)
        acc[i][j] = __builtin_amdgcn_mfma_f32_16x16x32_bf16(a[i], b[j], acc[i][j], 0, 0, 0);
  }

  #pragma unroll
  for (int j = 0; j < 2; j++) {
    int co = coh + j * 16 + m;
    #pragma unroll
    for (int i = 0; i < 4; i++) {
      int pxb = px0 + pxh + i * 16 + q * 4;
      int bl = pxb >> 14, pim = pxb & 16383;
      float4 r;
      r.x = acc[i][j][0]; r.y = acc[i][j][1];
      r.z = acc[i][j][2]; r.w = acc[i][j][3];
      *(float4*)&outv[(size_t)(bl * 64 + co) * HWp + pim] = r;
    }
  }
}

// ---------------- depthwise 3x3 NHWC bf16 v3: XCD row-aligned, 8ch x 4 rows ----------------
// grid 2752 1-D = 8 xcd x 8 row-groups x 43 x-triples
template<int ACT>
__global__ __launch_bounds__(256)
void dw3x3_v3(const ushortt* __restrict__ in, const ushortt* __restrict__ wt,
              ushortt* __restrict__ out) {
  int lin = blockIdx.x;
  int xcd = lin & 7, local = lin >> 3;     // [0,344)
  int g = local / 43, bxq = local - g * 43;
  int rg = xcd * 8 + g;                    // combined row-group [0,64)
  int bz = rg >> 5, by = rg & 31;
  int tid = threadIdx.x;
  int pxl = tid / 72;
  int gg = tid - pxl * 72;
  if (pxl >= 3) return;
  int x = bxq * 3 + pxl;
  if (x >= Wp) return;
  int y0 = by * 4;
  size_t bbase = (size_t)bz * HWp;

  float w[9][8];
  #pragma unroll
  for (int t = 0; t < 9; t++) {
    uint4 wv = *(const uint4*)&wt[t * 576 + gg * 8];
    u32 wsw[4] = {wv.x, wv.y, wv.z, wv.w};
    #pragma unroll
    for (int p = 0; p < 4; p++) {
      w[t][2 * p]     = blo(wsw[p]);
      w[t][2 * p + 1] = bhi(wsw[p]);
    }
  }
  float acc[4][8];
  #pragma unroll
  for (int o = 0; o < 4; o++)
    #pragma unroll
    for (int c = 0; c < 8; c++) acc[o][c] = 0.f;

  #pragma unroll
  for (int ri = 0; ri < 6; ri++) {
    int yy = y0 - 1 + ri;
    bool vr = (yy >= 0 && yy < Hp);
    float v[3][8];
    #pragma unroll
    for (int dx = 0; dx < 3; dx++) {
      int xx = x + dx - 1;
      uint4 t4 = {0, 0, 0, 0};
      if (vr && xx >= 0 && xx < Wp)
        t4 = *(const uint4*)&in[(bbase + (size_t)yy * Wp + xx) * 576 + gg * 8];
      u32 tw[4] = {t4.x, t4.y, t4.z, t4.w};
      #pragma unroll
      for (int p = 0; p < 4; p++) {
        v[dx][2 * p]     = blo(tw[p]);
        v[dx][2 * p + 1] = bhi(tw[p]);
      }
    }
    #pragma unroll
    for (int o = 0; o < 4; o++) {
      int dy = ri - o;
      if (dy < 0 || dy > 2) continue;
      #pragma unroll
      for (int dx = 0; dx < 3; dx++)
        #pragma unroll
        for (int c = 0; c < 8; c++)
          acc[o][c] += w[dy * 3 + dx][c] * v[dx][c];
    }
  }

  #pragma unroll
  for (int o = 0; o < 4; o++) {
    int yy = y0 + o;
    u32 pk[4];
    #pragma unroll
    for (int p = 0; p < 4; p++) {
      float r0 = acc[o][2 * p], r1 = acc[o][2 * p + 1];
      if (ACT == 1) { r0 = fmaxf(r0, 0.f); r1 = fmaxf(r1, 0.f); }
      else { r0 = 1.f / (1.f + __expf(-r0)); r1 = 1.f / (1.f + __expf(-r1)); }
      pk[p] = (u32)f2b(r0) | (((u32)f2b(r1)) << 16);
    }
    uint4 o4; o4.x = pk[0]; o4.y = pk[1]; o4.z = pk[2]; o4.w = pk[3];
    *(uint4*)&out[(bbase + (size_t)yy * Wp + x) * 576 + gg * 8] = o4;
  }
}

// ---------------- g9inv2: dct-from-xb + wiener mul + inv1 (2 batches, bf16) ----------------
// grid 8192 1-D, XCD row-aligned. LDS: dct + inv1 weight tables (41.5 KB).
__global__ __launch_bounds__(256)
void g9inv2(const ushortt* __restrict__ wien, const ushortt* __restrict__ xb,
            const float* __restrict__ wdct, const float* __restrict__ winv,
            ushortt* __restrict__ outb) {
  __shared__ float Wd[5184];
  __shared__ float Wi[5184];
  for (int i = threadIdx.x; i < 5184; i += 256) {
    Wd[i] = wdct[i];
    Wi[i] = winv[i];
  }
  __syncthreads();
  int lin = blockIdx.x;
  int xcd = lin & 7, local = lin >> 3;     // [0,1024)
  int rowi = local >> 5, bx = local & 31;
  size_t px = (size_t)((xcd * 32 + rowi) * 128 + bx * 4) + (threadIdx.x >> 6);
  int c = threadIdx.x & 63;
  float xr[9], v[9];
  #pragma unroll
  for (int t = 0; t < 9; t++) xr[t] = b2f(xb[px * 576 + 64 * t + c]);
  const float* wd = &Wd[c * 81];
  const float* wi = &Wi[c * 81];
  #pragma unroll
  for (int o = 0; o < 9; o++) {
    float d = 0.f;
    #pragma unroll
    for (int t = 0; t < 9; t++) d += wd[o * 9 + t] * xr[t];
    v[o] = b2f(wien[px * 576 + 64 * o + c]) * d;
  }
  #pragma unroll
  for (int j = 0; j < 9; j++) {
    float a = 0.f;
    #pragma unroll
    for (int o = 0; o < 9; o++) a += wi[j * 9 + o] * v[o];
    outb[px * 576 + 64 * j + c] = f2b(a);
  }
}

// ---------------- launch ----------------
extern "C" void kernel_launch(void* const* d_in, const int* in_sizes, int n_in,
                              void* d_out, int out_size, void* d_ws, size_t ws_size,
                              hipStream_t stream) {
  const float* x       = (const float*)d_in[0];
  const float* enc_dw  = (const float*)d_in[1];
  const float* enc_pw1 = (const float*)d_in[2];
  const float* enc_pw2 = (const float*)d_in[3];
  const float* dec_dw  = (const float*)d_in[4];
  const float* dec_pw1 = (const float*)d_in[5];
  const float* dec_pw2 = (const float*)d_in[6];
  const float* off_w1  = (const float*)d_in[7];
  const float* off_b1  = (const float*)d_in[8];
  const float* off_w2  = (const float*)d_in[9];
  const float* off_b2  = (const float*)d_in[10];
  const float* off_w3  = (const float*)d_in[11];
  const float* off_b3  = (const float*)d_in[12];
  const float* off_w4  = (const float*)d_in[13];
  const float* off_b4  = (const float*)d_in[14];
  const float* off_w5  = (const float*)d_in[15];
  const float* off_b5  = (const float*)d_in[16];
  const float* off_w6  = (const float*)d_in[17];
  const float* off_b6  = (const float*)d_in[18];
  const float* dct_w   = (const float*)d_in[19];
  const float* wie_w1  = (const float*)d_in[20];
  const float* wie_w2  = (const float*)d_in[21];
  const float* wie_w3  = (const float*)d_in[22];
  const float* wie_w4  = (const float*)d_in[23];
  const float* wie_w5  = (const float*)d_in[24];
  const float* wie_w6  = (const float*)d_in[25];
  const float* inv_w1  = (const float*)d_in[26];
  const float* inv_w2  = (const float*)d_in[27];
  float* outp = (float*)d_out;

  const size_t NP = (size_t)Bp * HWp;
  const size_t REQ_FLOATS = NP * 64 + NP * 64 + NP * 128 +
                            2 * (size_t)HWp * CKp + (size_t)HWp * CKp;
  if (ws_size < REQ_FLOATS * sizeof(float)) return;

  float* ws  = (float*)d_ws;
  float* x1  = ws;
  float* t0  = x1 + NP * 64;
  float* t1  = t0 + NP * 64;
  float* bigA = t1 + NP * 128;
  float* bigB = bigA + (size_t)HWp * CKp;
  float* bigC = bigB + (size_t)HWp * CKp;
  ushortt* R1 = (ushortt*)bigA;
  ushortt* R2 = (ushortt*)bigB;
  ushortt* R3 = (ushortt*)bigC;
  ushortt* e1 = (ushortt*)bigA;

  float* wreg = t0 + NP * 18;
  ushortt* wb  = (ushortt*)wreg;
  ushortt* wbi2 = wb + 3 * 640 * 576;
  ushortt* wdwb = wbi2 + 64 * 576;
  ushortt* wc1  = wdwb + 3 * 5184;
  ushortt* wc2  = wc1 + 4096;
  ushortt* wpw  = wc2 + 4 * 36864;

  ushortt* xnAll = (ushortt*)t1;
  ushortt* oA = xnAll + NP * 64;
  ushortt* oB = oA + NP * 64;

  float* offs = t0;
  float* mid  = x1;

  dim3 blk(256);

  // ---- enc ConvNeXt: dw7 fp32, pw via bf16 MFMA ----
  dwconv7_lds<<<dim3(Hp / 2, Bp * Cp), blk, 0, stream>>>(x, enc_dw, t0);
  t64b<<<dim3(HWp / 64, Bp), blk, 0, stream>>>(t0, oA);

  // ---- merged weight repack ----
  repack_all<<<dim3(5245), blk, 0, stream>>>(
      wie_w1, wie_w3, wie_w5, inv_w2, wie_w2, wie_w4, wie_w6, off_w1,
      off_w2, off_w3, off_w4, off_w5, enc_pw1, enc_pw2, dec_pw1, dec_pw2,
      wb, wbi2, wdwb, wc1, wc2, wpw);

  pw_bf<64, 1, 0><<<dim3(NP / 128, 2), blk, 0, stream>>>(oA, wpw, nullptr, e1, 128);
  pw_bf<128, 0, 1><<<dim3(NP / 128, 1), blk, 0, stream>>>(e1, wpw + 8192, x, xnAll, 64);

  // ---- offset CNN (full batch, bf16 MFMA, NHWC) ----
  conv_bf<1><<<dim3(HWp / 64, Bp), blk, 0, stream>>>(xnAll, wc1, off_b1, oA);
  conv_bf<9><<<dim3(HWp / 64, Bp), blk, 0, stream>>>(oA, wc2,             off_b2, oB);
  conv_bf<9><<<dim3(HWp / 64, Bp), blk, 0, stream>>>(oB, wc2 + 36864,     off_b3, oA);
  conv_bf<9><<<dim3(HWp / 64, Bp), blk, 0, stream>>>(oA, wc2 + 2 * 36864, off_b4, oB);
  conv_bf<9><<<dim3(HWp / 64, Bp), blk, 0, stream>>>(oB, wc2 + 3 * 36864, off_b5, oA);
  off6_nhwc<<<dim3(NP / 256), blk, 0, stream>>>(oA, off_w6, off_b6, offs);

  // ---- 576-channel middle: 2 batches per pass; xb persists in R2 ----
  for (int bp = 0; bp < 2; bp++) {
    const ushortt* xn0 = xnAll + (size_t)(2 * bp) * HWp * 64;
    const float* off0 = offs + (size_t)(2 * bp) * 18 * HWp;
    float* mid0 = mid + (size_t)(2 * bp) * 64 * HWp;

    deform_x<<<dim3(4096), blk, 0, stream>>>(xn0, off0, R2);
    gemm128<<<dim3(5, 256), blk, 0, stream>>>(R2, wb, R3);
    dw3x3_v3<1><<<dim3(2752), blk, 0, stream>>>(R3, wdwb, R1);
    gemm128<<<dim3(5, 256), blk, 0, stream>>>(R1, wb + 640 * 576, R3);
    dw3x3_v3<1><<<dim3(2752), blk, 0, stream>>>(R3, wdwb + 5184, R1);
    gemm128<<<dim3(5, 256), blk, 0, stream>>>(R1, wb + 2 * 640 * 576, R3);
    dw3x3_v3<2><<<dim3(2752), blk, 0, stream>>>(R3, wdwb + 2 * 5184, R1);  // wiener
    g9inv2<<<dim3(8192), blk, 0, stream>>>(R1, R2, dct_w, inv_w1, R3);
    gemm64o2<<<dim3(256), blk, 0, stream>>>(R3, wbi2, mid0);
  }

  // ---- dec ConvNeXt: dw7 fp32 (tmp in bigB), pw via bf16 MFMA ----
  dwconv7_lds<<<dim3(Hp / 2, Bp * Cp), blk, 0, stream>>>(mid, dec_dw, bigB);
  t64b<<<dim3(HWp / 64, Bp), blk, 0, stream>>>(bigB, oA);
  pw_bf<64, 1, 0><<<dim3(NP / 128, 2), blk, 0, stream>>>(oA, wpw + 2 * 8192, nullptr, e1, 128);
  pw_bf<128, 0, 2><<<dim3(NP / 128, 1), blk, 0, stream>>>(e1, wpw + 3 * 8192, mid, outp, 64);
}